// Round 1
// baseline (482.559 us; speedup 1.0000x reference)
//
#include <hip/hip_runtime.h>
#include <hip/hip_bf16.h>

// Problem constants
#define Bc   4
#define Tc   1024
#define Cc   768
#define Hc   12
#define HSc  64
#define VDc  128
#define NQKV 4608   // gemm N for qkv (4*768 Q/K + 1536 V)
#define YLD  3072   // Y row stride: Q/K only (V goes to Vt)
#define NROWS 4096  // B*T
#define HVD  1536   // H*VD

// Y (qk) column offsets
#define Q1OFF 0
#define K1OFF 768
#define Q2OFF 1536
#define K2OFF 2304

typedef __bf16 bf16x8 __attribute__((ext_vector_type(8)));
typedef float f32x4 __attribute__((ext_vector_type(4)));

#define PW_S 36   // P row stride in dwords: 144B rows, 16B aligned, <=2-way banks
// exp(s*0.125) == exp2(s * 0.125*log2(e))
#define EXP2SCALE 0.18033688011112042f

static __device__ __forceinline__ float bf2f(unsigned short s) {
    return __uint_as_float(((unsigned int)s) << 16);
}
static __device__ __forceinline__ unsigned short f2bf(float f) {
    unsigned int u = __float_as_uint(f);
    unsigned int r = (u + 0x7FFFu + ((u >> 16) & 1u)) >> 16;  // round-nearest-even
    return (unsigned short)r;
}
static __device__ __forceinline__ unsigned int pack2bf(float lo, float hi) {
    // bf16(lo) | bf16(hi)<<16, half-up rounding (values >= 0)
    unsigned int a = (__float_as_uint(lo) + 0x8000u) >> 16;
    unsigned int b = (__float_as_uint(hi) + 0x8000u) & 0xFFFF0000u;
    return a | b;
}

// async global->LDS 16B per lane; lds base must be wave-uniform
static __device__ __forceinline__ void load16_lds(const void* g, void* l) {
    __builtin_amdgcn_global_load_lds(
        (const __attribute__((address_space(1))) void*)g,
        (__attribute__((address_space(3))) void*)l, 16, 0, 0);
}

// ---------------------------------------------------------------------------
// cast fp32 -> bf16, 4 elts/thread
// ---------------------------------------------------------------------------
__global__ __launch_bounds__(256) void cast_bf16(
    const float* __restrict__ src, unsigned short* __restrict__ dst)
{
    int i = blockIdx.x * 256 + threadIdx.x;
    float4 v = *(const float4*)(src + (size_t)i * 4);
    ushort4 u;
    u.x = f2bf(v.x); u.y = f2bf(v.y); u.z = f2bf(v.z); u.w = f2bf(v.w);
    *(ushort4*)(dst + (size_t)i * 4) = u;
}

// ---------------------------------------------------------------------------
// Transpose-repack the 5 projection weights into WcatT[n][k] bf16, k-contig.
// ---------------------------------------------------------------------------
__global__ __launch_bounds__(256) void trans_w(
    const float* __restrict__ Wq1, const float* __restrict__ Wk1,
    const float* __restrict__ Wq2, const float* __restrict__ Wk2,
    const float* __restrict__ Wv, unsigned short* __restrict__ WcatT)
{
    __shared__ float tile[64][65];
    int tid = threadIdx.x;
    int t = blockIdx.x;
    int kt = t % 12, nt = t / 12;
    int k0 = kt * 64, n0 = nt * 64;
    const float* src;
    int stride;
    if (n0 < 3072) {
        int which = n0 / 768, m = n0 - which * 768, h = m >> 6;
        const float* W = (which == 0) ? Wq1 : (which == 1) ? Wk1 : (which == 2) ? Wq2 : Wk2;
        src = W + ((size_t)h * 768 + k0) * 64;
        stride = 64;
    } else {
        int rel = n0 - 3072, h = rel >> 7, e0 = rel & 127;
        src = Wv + ((size_t)h * 768 + k0) * 128 + e0;
        stride = 128;
    }
    for (int i = tid; i < 4096; i += 256) {
        int kl = i >> 6, dl = i & 63;
        tile[dl][kl] = src[(size_t)kl * stride + dl];
    }
    __syncthreads();
    for (int i = tid; i < 4096; i += 256) {
        int nl = i >> 6, kl = i & 63;
        WcatT[(size_t)(n0 + nl) * 768 + k0 + kl] = f2bf(tile[nl][kl]);
    }
}

// ---------------------------------------------------------------------------
// lambda per head
// ---------------------------------------------------------------------------
__global__ __launch_bounds__(64) void lambda_kernel(
    const float* __restrict__ lq1, const float* __restrict__ lk1,
    const float* __restrict__ lq2, const float* __restrict__ lk2,
    const int* __restrict__ layer_idx, float* __restrict__ lam)
{
    int h = blockIdx.x, l = threadIdx.x;
    float li = (float)layer_idx[0];
    float dyn = 0.8f - 0.6f * expf(-0.3f * (li - 1.0f));
    int i = h * HSc + l;
    float v = expf(lq1[i] * lk1[i]) - expf(lq2[i] * lk2[i]) + dyn;
    #pragma unroll
    for (int off = 32; off; off >>= 1) v += __shfl_xor(v, off);
    if (l == 0) lam[h] = v * (1.0f / 64.0f);
}

// ---------------------------------------------------------------------------
// MFMA GEMM (m97 structure): C[M][LDC] = A[M][KD] * Bt[N][KD]^T, bf16 inputs.
// SPLITV: cols >= 3072 (V projection) -> written transposed to VtOut[bh][e][t].
// ---------------------------------------------------------------------------
template<int TN, int KD, int LDC, bool OUT_BIAS, bool SPLITV>
__global__ __launch_bounds__(256) void gemm_mfma(
    const unsigned short* __restrict__ A, const unsigned short* __restrict__ Bt,
    unsigned short* __restrict__ Cb, float* __restrict__ Cf,
    const float* __restrict__ bias, unsigned short* __restrict__ VtOut)
{
    constexpr int BN = TN * 32;
    constexpr int JB = TN / 2;
    __shared__ unsigned short As[128 * 32];
    __shared__ unsigned short Bs[BN * 32];
    int tid = threadIdx.x, lane = tid & 63, w = tid >> 6;
    int wm = w >> 1, wn = w & 1;
    int m0 = blockIdx.y * 128, n0 = blockIdx.x * BN;

    int lr = lane >> 2, lq = lane & 3;
    const unsigned short* gA[2];
    const unsigned short* gB[JB];
    #pragma unroll
    for (int j = 0; j < 2; ++j) {
        int row = w * 32 + j * 16 + lr;
        int qg = lq ^ ((row >> 1) & 3);
        gA[j] = A + (size_t)(m0 + row) * KD + qg * 8;
    }
    #pragma unroll
    for (int j = 0; j < JB; ++j) {
        int row = w * (JB * 16) + j * 16 + lr;
        int qg = lq ^ ((row >> 1) & 3);
        gB[j] = Bt + (size_t)(n0 + row) * KD + qg * 8;
    }

    int rr = lane & 15, qd = lane >> 4;
    const unsigned short* aAddr[4];
    const unsigned short* bAddr[TN];
    #pragma unroll
    for (int i = 0; i < 4; ++i) {
        int row = wm * 64 + i * 16 + rr;
        int qs = qd ^ ((row >> 1) & 3);
        aAddr[i] = As + row * 32 + qs * 8;
    }
    #pragma unroll
    for (int t = 0; t < TN; ++t) {
        int row = wn * (TN * 16) + t * 16 + rr;
        int qs = qd ^ ((row >> 1) & 3);
        bAddr[t] = Bs + row * 32 + qs * 8;
    }

    f32x4 acc[4][TN];
    #pragma unroll
    for (int i = 0; i < 4; ++i)
        #pragma unroll
        for (int t = 0; t < TN; ++t) acc[i][t] = {0.f, 0.f, 0.f, 0.f};

    for (int k = 0; k < KD / 32; ++k) {
        __syncthreads();
        load16_lds(gA[0], As + (w * 2 + 0) * 512);
        load16_lds(gA[1], As + (w * 2 + 1) * 512);
        #pragma unroll
        for (int j = 0; j < JB; ++j)
            load16_lds(gB[j], Bs + (w * JB + j) * 512);
        gA[0] += 32; gA[1] += 32;
        #pragma unroll
        for (int j = 0; j < JB; ++j) gB[j] += 32;
        __syncthreads();

        bf16x8 af[4], bfr[TN];
        #pragma unroll
        for (int i = 0; i < 4; ++i) af[i] = *(const bf16x8*)aAddr[i];
        #pragma unroll
        for (int t = 0; t < TN; ++t) bfr[t] = *(const bf16x8*)bAddr[t];
        #pragma unroll
        for (int i = 0; i < 4; ++i)
            #pragma unroll
            for (int t = 0; t < TN; ++t)
                acc[i][t] = __builtin_amdgcn_mfma_f32_16x16x32_bf16(af[i], bfr[t], acc[i][t], 0, 0, 0);
    }

    #pragma unroll
    for (int t = 0; t < TN; ++t) {
        int col = n0 + wn * (TN * 16) + t * 16 + rr;
        if (SPLITV && col >= 3072) {
            int rel = col - 3072, hh = rel >> 7, e = rel & 127;
            #pragma unroll
            for (int i = 0; i < 4; ++i) {
                int row0 = m0 + wm * 64 + i * 16 + qd * 4;
                int b = row0 >> 10, tt = row0 & 1023;
                ushort4 pk;
                pk.x = f2bf(acc[i][t][0]); pk.y = f2bf(acc[i][t][1]);
                pk.z = f2bf(acc[i][t][2]); pk.w = f2bf(acc[i][t][3]);
                *(ushort4*)&VtOut[(size_t)((b * Hc + hh) * 128 + e) * 1024 + tt] = pk;
            }
        } else {
            float bv = OUT_BIAS ? bias[col] : 0.f;
            #pragma unroll
            for (int i = 0; i < 4; ++i) {
                #pragma unroll
                for (int r = 0; r < 4; ++r) {
                    int row = m0 + wm * 64 + i * 16 + qd * 4 + r;
                    if (OUT_BIAS)
                        Cf[(size_t)row * LDC + col] = acc[i][t][r] + bv;
                    else
                        Cb[(size_t)row * LDC + col] = f2bf(acc[i][t][r]);
                }
            }
        }
    }
}

// ---------------------------------------------------------------------------
// MFMA differential flash attention — R9: intra-block split-KV.
// grid (48, 32): x = bh (XCD-pinned KV), y -> QT = 31 - y (longest first).
// block 256 = 4 waves: wave (rg, s) with rg = wv&1 (16-row group, same as
// before), s = wv>>1 (KV half). s=0 takes K-tiles [0, ceil(n/2)),
// s=1 takes [ceil(n/2), n) (n = QT+1; s can own the diag tile).
// Rationale (rocprof): MfmaUtil 7%, VALUBusy 20%, HBM 4%, Occupancy 18.7%
// -> latency-bound, grid-drain-limited (block duration was prop. to QT+1,
// 1..32). Split halves the critical path of long blocks and doubles wave
// parallelism per (bh,QT) at ZERO extra HBM traffic (partials are additive:
// no online max in this exp formulation; combine through 20 KB LDS in f32).
// LDS ~30 KB/block, VGPR <=128 (launch_bounds(256,4)) -> 4 blocks/CU
// resident, 6 blocks/CU of queued work keeps CUs fed through the tail.
// ---------------------------------------------------------------------------
__global__ __launch_bounds__(256, 4) void diff_attn_mfma(
    const unsigned short* __restrict__ Y, const unsigned short* __restrict__ Vt,
    const float* __restrict__ lam_buf, unsigned short* __restrict__ attn)
{
    __shared__ __align__(16) unsigned int PL32[4][16 * PW_S]; // per-wave packed P
    __shared__ __align__(16) float Oex[2][128][20];           // [rg][e][row(16)+pad4]
    __shared__ float lex[2][16][2];                           // [rg][row][l1,l2]

    int bh = blockIdx.x;                          // fastest dim -> XCD-pinned
    int b = bh / Hc, h = bh - b * Hc;
    int QT = 31 - (int)blockIdx.y;                // longest first
    int tid = threadIdx.x, lane = tid & 63, wv = tid >> 6;
    int rg = wv & 1;                              // row-group: rows rg*16..rg*16+15
    int sh = wv >> 1;                             // KV half
    int cl = lane & 15, qd = lane >> 4;
    float lamv = lam_buf[h];
    size_t rowbase = (size_t)(b * Tc) * YLD;
    const int hq = h * HSc;
    unsigned int* Pw = PL32[wv];
    const unsigned short* VtB = Vt + ((size_t)bh << 17);   // bh*128*1024
    const f32x4 zero4 = {0.f, 0.f, 0.f, 0.f};

    bf16x8 ka[2][4], kb[2][4], va[8], vb2[8];

    auto loadK = [&](int kt, bf16x8 kf[2][4]) {
        #pragma unroll
        for (int c = 0; c < 2; ++c) {
            size_t koff = rowbase + (size_t)(kt * 32 + c * 16 + cl) * YLD;
            kf[c][0] = *(const bf16x8*)(Y + koff + K1OFF + hq + qd * 8);
            kf[c][1] = *(const bf16x8*)(Y + koff + K1OFF + hq + 32 + qd * 8);
            kf[c][2] = *(const bf16x8*)(Y + koff + K2OFF + hq + qd * 8);
            kf[c][3] = *(const bf16x8*)(Y + koff + K2OFF + hq + 32 + qd * 8);
        }
    };
    auto loadV = [&](int kt, bf16x8 vf[8]) {
        #pragma unroll
        for (int ec = 0; ec < 8; ++ec)
            vf[ec] = *(const bf16x8*)(VtB + (((ec * 16 + cl) << 10) + kt * 32 + qd * 8));
    };

    int qrow = QT * 32 + rg * 16;

    size_t qoff = rowbase + (size_t)(qrow + cl) * YLD;
    bf16x8 q1a = *(const bf16x8*)(Y + qoff + Q1OFF + hq + qd * 8);
    bf16x8 q1b = *(const bf16x8*)(Y + qoff + Q1OFF + hq + 32 + qd * 8);
    bf16x8 q2a = *(const bf16x8*)(Y + qoff + Q2OFF + hq + qd * 8);
    bf16x8 q2b = *(const bf16x8*)(Y + qoff + Q2OFF + hq + 32 + qd * 8);

    f32x4 O1[8], O2[8];
    #pragma unroll
    for (int ec = 0; ec < 8; ++ec) { O1[ec] = zero4; O2[ec] = zero4; }
    float l1[4] = {0.f, 0.f, 0.f, 0.f}, l2[4] = {0.f, 0.f, 0.f, 0.f};

    auto tile = [&](int kt, bf16x8 kf[2][4], bf16x8 vf[8], bool diag) {
        f32x4 S1[2], S2[2];
        #pragma unroll
        for (int c = 0; c < 2; ++c) { S1[c] = zero4; S2[c] = zero4; }
        #pragma unroll
        for (int c = 0; c < 2; ++c) {
            S1[c] = __builtin_amdgcn_mfma_f32_16x16x32_bf16(q1a, kf[c][0], S1[c], 0, 0, 0);
            S1[c] = __builtin_amdgcn_mfma_f32_16x16x32_bf16(q1b, kf[c][1], S1[c], 0, 0, 0);
            S2[c] = __builtin_amdgcn_mfma_f32_16x16x32_bf16(q2a, kf[c][2], S2[c], 0, 0, 0);
            S2[c] = __builtin_amdgcn_mfma_f32_16x16x32_bf16(q2b, kf[c][3], S2[c], 0, 0, 0);
        }
        if (diag) {
            #pragma unroll
            for (int c = 0; c < 2; ++c) {
                int key_local = c * 16 + cl;
                #pragma unroll
                for (int r = 0; r < 4; ++r) {
                    int row_local = rg * 16 + qd * 4 + r;
                    if (key_local > row_local) { S1[c][r] = -1e30f; S2[c][r] = -1e30f; }
                }
            }
        }
        // p = exp(s/8) = exp2(s * 0.125*log2e): one v_mul + one v_exp each
        #pragma unroll
        for (int r = 0; r < 4; ++r) {
            float p10 = exp2f(S1[0][r] * EXP2SCALE);
            float p11 = exp2f(S1[1][r] * EXP2SCALE);
            float p20 = exp2f(S2[0][r] * EXP2SCALE);
            float p21 = exp2f(S2[1][r] * EXP2SCALE);
            l1[r] += p10 + p11;
            l2[r] += p20 + p21;
            int row = (qd << 2) + r;
            Pw[row * PW_S + cl]      = pack2bf(p10, p20);   // key = cl
            Pw[row * PW_S + cl + 16] = pack2bf(p11, p21);   // key = cl+16
        }
        // read back as A-operand fragments: row = cl, keys qd*8..qd*8+7
        const unsigned int* rp = Pw + cl * PW_S + qd * 8;
        uint4 L0 = *(const uint4*)(rp);
        uint4 L1 = *(const uint4*)(rp + 4);
        uint4 u1, u2;
        u1.x = __builtin_amdgcn_perm(L0.y, L0.x, 0x05040100u);
        u1.y = __builtin_amdgcn_perm(L0.w, L0.z, 0x05040100u);
        u1.z = __builtin_amdgcn_perm(L1.y, L1.x, 0x05040100u);
        u1.w = __builtin_amdgcn_perm(L1.w, L1.z, 0x05040100u);
        u2.x = __builtin_amdgcn_perm(L0.y, L0.x, 0x07060302u);
        u2.y = __builtin_amdgcn_perm(L0.w, L0.z, 0x07060302u);
        u2.z = __builtin_amdgcn_perm(L1.y, L1.x, 0x07060302u);
        u2.w = __builtin_amdgcn_perm(L1.w, L1.z, 0x07060302u);
        bf16x8 pa1 = __builtin_bit_cast(bf16x8, u1);
        bf16x8 pa2 = __builtin_bit_cast(bf16x8, u2);
        #pragma unroll
        for (int ec = 0; ec < 8; ++ec) {
            O1[ec] = __builtin_amdgcn_mfma_f32_16x16x32_bf16(pa1, vf[ec], O1[ec], 0, 0, 0);
            O2[ec] = __builtin_amdgcn_mfma_f32_16x16x32_bf16(pa2, vf[ec], O2[ec], 0, 0, 0);
        }
    };

    // KV range for this wave: s=0 -> [0, nh), s=1 -> [nh, n)
    int n = QT + 1;
    int nh = (n + 1) >> 1;
    int lo = sh ? nh : 0;
    int hi = sh ? n : nh;

    if (lo < hi) { loadK(lo, ka); loadV(lo, va); }
    for (int kt = lo; kt < hi; kt += 2) {
        if (kt + 1 < hi) { loadK(kt + 1, kb); loadV(kt + 1, vb2); }
        tile(kt, ka, va, kt == QT);
        if (kt + 1 < hi) {
            if (kt + 2 < hi) { loadK(kt + 2, ka); loadV(kt + 2, va); }
            tile(kt + 1, kb, vb2, kt + 1 == QT);
        }
    }

    // reduce partial l across the 16 column-lanes
    float la1[4], la2[4];
    #pragma unroll
    for (int r = 0; r < 4; ++r) {
        float a = l1[r], c = l2[r];
        a += __shfl_xor(a, 1); a += __shfl_xor(a, 2);
        a += __shfl_xor(a, 4); a += __shfl_xor(a, 8);
        c += __shfl_xor(c, 1); c += __shfl_xor(c, 2);
        c += __shfl_xor(c, 4); c += __shfl_xor(c, 8);
        la1[r] = a; la2[r] = c;
    }

    // --- combine the two KV halves through LDS (f32, 2 phases) ---
    if (sh == 1) {
        #pragma unroll
        for (int ec = 0; ec < 8; ++ec)
            *(f32x4*)&Oex[rg][ec * 16 + cl][qd * 4] = O1[ec];
        if (cl == 0) {
            #pragma unroll
            for (int r = 0; r < 4; ++r) {
                lex[rg][qd * 4 + r][0] = la1[r];
                lex[rg][qd * 4 + r][1] = la2[r];
            }
        }
    }
    __syncthreads();
    if (sh == 0) {
        #pragma unroll
        for (int ec = 0; ec < 8; ++ec)
            O1[ec] += *(const f32x4*)&Oex[rg][ec * 16 + cl][qd * 4];
        #pragma unroll
        for (int r = 0; r < 4; ++r) {
            la1[r] += lex[rg][qd * 4 + r][0];
            la2[r] += lex[rg][qd * 4 + r][1];
        }
    }
    __syncthreads();
    if (sh == 1) {
        #pragma unroll
        for (int ec = 0; ec < 8; ++ec)
            *(f32x4*)&Oex[rg][ec * 16 + cl][qd * 4] = O2[ec];
    }
    __syncthreads();
    if (sh == 0) {
        #pragma unroll
        for (int ec = 0; ec < 8; ++ec)
            O2[ec] += *(const f32x4*)&Oex[rg][ec * 16 + cl][qd * 4];

        float w1[4], w2[4];
        #pragma unroll
        for (int r = 0; r < 4; ++r) {
            w1[r] = 1.0f / la1[r];
            w2[r] = lamv / la2[r];
        }
        #pragma unroll
        for (int ec = 0; ec < 8; ++ec) {
            #pragma unroll
            for (int r = 0; r < 4; ++r) {
                size_t row = (size_t)(b * Tc + qrow + qd * 4 + r);
                attn[row * HVD + h * VDc + ec * 16 + cl] =
                    f2bf(O1[ec][r] * w1[r] - O2[ec][r] * w2[r]);
            }
        }
    }
}

// ---------------------------------------------------------------------------
// Fused row-stats + LayerNorm*0.2, in-place on bf16 attn. 128 thr/row.
// ---------------------------------------------------------------------------
__global__ __launch_bounds__(128) void ln_inplace(
    unsigned short* __restrict__ attn,
    const float* __restrict__ gnw, const float* __restrict__ gnb)
{
    int row = blockIdx.x, tid = threadIdx.x;
    unsigned short* p = attn + (size_t)row * HVD;
    float v[12];
    float s = 0.f, sq = 0.f;
    #pragma unroll
    for (int j = 0; j < 3; ++j) {
        int g = tid + j * 128;
        ushort4 u = *(const ushort4*)(p + g * 4);
        float x0 = bf2f(u.x), x1 = bf2f(u.y), x2 = bf2f(u.z), x3 = bf2f(u.w);
        v[j * 4 + 0] = x0; v[j * 4 + 1] = x1; v[j * 4 + 2] = x2; v[j * 4 + 3] = x3;
        s += x0 + x1 + x2 + x3;
        sq = fmaf(x0, x0, sq); sq = fmaf(x1, x1, sq);
        sq = fmaf(x2, x2, sq); sq = fmaf(x3, x3, sq);
    }
    #pragma unroll
    for (int off = 32; off; off >>= 1) { s += __shfl_xor(s, off); sq += __shfl_xor(sq, off); }
    __shared__ float ss[2], sqs[2];
    if ((tid & 63) == 0) { ss[tid >> 6] = s; sqs[tid >> 6] = sq; }
    __syncthreads();
    float S = ss[0] + ss[1], Q = sqs[0] + sqs[1];
    float mu = S * (1.0f / HVD);
    float rstd = rsqrtf(Q * (1.0f / HVD) - mu * mu + 1e-5f);
    #pragma unroll
    for (int j = 0; j < 3; ++j) {
        int g = tid + j * 128;
        float4 gw = *(const float4*)(gnw + g * 4);
        float4 gb = *(const float4*)(gnb + g * 4);
        ushort4 o;
        o.x = f2bf(((v[j * 4 + 0] - mu) * rstd * gw.x + gb.x) * 0.2f);
        o.y = f2bf(((v[j * 4 + 1] - mu) * rstd * gw.y + gb.y) * 0.2f);
        o.z = f2bf(((v[j * 4 + 2] - mu) * rstd * gw.z + gb.z) * 0.2f);
        o.w = f2bf(((v[j * 4 + 3] - mu) * rstd * gw.w + gb.w) * 0.2f);
        *(ushort4*)(p + g * 4) = o;
    }
}

// ---------------------------------------------------------------------------
// launch
// ---------------------------------------------------------------------------
extern "C" void kernel_launch(void* const* d_in, const int* in_sizes, int n_in,
                              void* d_out, int out_size, void* d_ws, size_t ws_size,
                              hipStream_t stream)
{
    const float* x   = (const float*)d_in[0];
    const float* Wq1 = (const float*)d_in[1];
    const float* Wk1 = (const float*)d_in[2];
    const float* Wq2 = (const float*)d_in[3];
    const float* Wk2 = (const float*)d_in[4];
    const float* Wv  = (const float*)d_in[5];
    const float* lq1 = (const float*)d_in[6];
    const float* lk1 = (const float*)d_in[7];
    const float* lq2 = (const float*)d_in[8];
    const float* lk2 = (const float*)d_in[9];
    const float* gnw = (const float*)d_in[10];
    const float* gnb = (const float*)d_in[11];
    const float* Wp  = (const float*)d_in[12];
    const float* bp  = (const float*)d_in[13];
    const int*   lidx = (const int*)d_in[14];
    float* out = (float*)d_out;

    // workspace layout (bytes):
    // WcatT bf16 [4608][768]:  7,077,888 @ 0
    // Xb    bf16 [4096][768]:  6,291,456 @ 7,077,888
    // Y     bf16 [4096][3072]: 25,165,824 @ 13,369,344
    // Vt    bf16 [48][128][1024]: 12,582,912 @ 38,535,168
    // attn  bf16 [4096][1536]: 12,582,912 @ 51,118,080
    // Wpb   bf16 [768][1536]:   2,359,296 @ 63,700,992
    // lam   f32 [12]                       @ 66,060,288
    char* w = (char*)d_ws;
    unsigned short* WcatT = (unsigned short*)(w);
    unsigned short* Xb    = (unsigned short*)(w + 7077888);
    unsigned short* Y     = (unsigned short*)(w + 13369344);
    unsigned short* VtW   = (unsigned short*)(w + 38535168);
    unsigned short* attn  = (unsigned short*)(w + 51118080);
    unsigned short* Wpb   = (unsigned short*)(w + 63700992);
    float* lam            = (float*)(w + 66060288);

    cast_bf16<<<dim3(NROWS * Cc / 1024), 256, 0, stream>>>(x, Xb);
    cast_bf16<<<dim3(Cc * HVD / 1024), 256, 0, stream>>>(Wp, Wpb);
    trans_w<<<dim3(72 * 12), 256, 0, stream>>>(Wq1, Wk1, Wq2, Wk2, Wv, WcatT);
    lambda_kernel<<<dim3(Hc), 64, 0, stream>>>(lq1, lk1, lq2, lk2, lidx, lam);
    // QKV: [4096,768] x [768,4608]; Q/K -> Y (LD 3072), V -> Vt transposed
    gemm_mfma<4, 768, YLD, false, true><<<dim3(NQKV / 128, NROWS / 128), 256, 0, stream>>>(
        Xb, WcatT, Y, nullptr, nullptr, VtW);
    // bh fastest (XCD pin); y -> QT = 31-y, longest-first; 1536 blocks x 4 waves,
    // intra-block split-KV (s=0/1 halves combined through LDS)
    diff_attn_mfma<<<dim3(Bc * Hc, 32), 256, 0, stream>>>(Y, VtW, lam, attn);
    ln_inplace<<<dim3(NROWS), 128, 0, stream>>>(attn, gnw, gnb);
    // OUT: [4096,1536] x [1536,768] -> out fp32 (+bias)
    gemm_mfma<2, HVD, Cc, true, false><<<dim3(Cc / 64, NROWS / 128), 256, 0, stream>>>(
        attn, Wpb, nullptr, out, bp, nullptr);
}

// Round 2
// 296.851 us; speedup vs baseline: 1.6256x; 1.6256x over previous
//
#include <hip/hip_runtime.h>
#include <hip/hip_bf16.h>

// Problem constants
#define Bc   4
#define Tc   1024
#define Cc   768
#define Hc   12
#define HSc  64
#define VDc  128
#define NQKV 4608   // gemm N for qkv (4*768 Q/K + 1536 V)
#define YLD  3072   // Y row stride: Q/K only (V goes to Vt)
#define NROWS 4096  // B*T
#define HVD  1536   // H*VD

// Y (qk) column offsets
#define Q1OFF 0
#define K1OFF 768
#define Q2OFF 1536
#define K2OFF 2304

typedef __bf16 bf16x8 __attribute__((ext_vector_type(8)));
typedef float f32x4 __attribute__((ext_vector_type(4)));

#define PW_S 36   // P row stride in dwords: 144B rows, 16B aligned, <=2-way banks
// exp(s*0.125) == exp2(s * 0.125*log2(e))
#define EXP2SCALE 0.18033688011112042f

static __device__ __forceinline__ float bf2f(unsigned short s) {
    return __uint_as_float(((unsigned int)s) << 16);
}
static __device__ __forceinline__ unsigned short f2bf(float f) {
    unsigned int u = __float_as_uint(f);
    unsigned int r = (u + 0x7FFFu + ((u >> 16) & 1u)) >> 16;  // round-nearest-even
    return (unsigned short)r;
}
static __device__ __forceinline__ unsigned int pack2bf(float lo, float hi) {
    // bf16(lo) | bf16(hi)<<16, half-up rounding (values >= 0)
    unsigned int a = (__float_as_uint(lo) + 0x8000u) >> 16;
    unsigned int b = (__float_as_uint(hi) + 0x8000u) & 0xFFFF0000u;
    return a | b;
}

// async global->LDS 16B per lane; lds base must be wave-uniform
static __device__ __forceinline__ void load16_lds(const void* g, void* l) {
    __builtin_amdgcn_global_load_lds(
        (const __attribute__((address_space(1))) void*)g,
        (__attribute__((address_space(3))) void*)l, 16, 0, 0);
}

// ---------------------------------------------------------------------------
// cast fp32 -> bf16, 4 elts/thread
// ---------------------------------------------------------------------------
__global__ __launch_bounds__(256) void cast_bf16(
    const float* __restrict__ src, unsigned short* __restrict__ dst)
{
    int i = blockIdx.x * 256 + threadIdx.x;
    float4 v = *(const float4*)(src + (size_t)i * 4);
    ushort4 u;
    u.x = f2bf(v.x); u.y = f2bf(v.y); u.z = f2bf(v.z); u.w = f2bf(v.w);
    *(ushort4*)(dst + (size_t)i * 4) = u;
}

// ---------------------------------------------------------------------------
// Transpose-repack the 5 projection weights into WcatT[n][k] bf16, k-contig.
// ---------------------------------------------------------------------------
__global__ __launch_bounds__(256) void trans_w(
    const float* __restrict__ Wq1, const float* __restrict__ Wk1,
    const float* __restrict__ Wq2, const float* __restrict__ Wk2,
    const float* __restrict__ Wv, unsigned short* __restrict__ WcatT)
{
    __shared__ float tile[64][65];
    int tid = threadIdx.x;
    int t = blockIdx.x;
    int kt = t % 12, nt = t / 12;
    int k0 = kt * 64, n0 = nt * 64;
    const float* src;
    int stride;
    if (n0 < 3072) {
        int which = n0 / 768, m = n0 - which * 768, h = m >> 6;
        const float* W = (which == 0) ? Wq1 : (which == 1) ? Wk1 : (which == 2) ? Wq2 : Wk2;
        src = W + ((size_t)h * 768 + k0) * 64;
        stride = 64;
    } else {
        int rel = n0 - 3072, h = rel >> 7, e0 = rel & 127;
        src = Wv + ((size_t)h * 768 + k0) * 128 + e0;
        stride = 128;
    }
    for (int i = tid; i < 4096; i += 256) {
        int kl = i >> 6, dl = i & 63;
        tile[dl][kl] = src[(size_t)kl * stride + dl];
    }
    __syncthreads();
    for (int i = tid; i < 4096; i += 256) {
        int nl = i >> 6, kl = i & 63;
        WcatT[(size_t)(n0 + nl) * 768 + k0 + kl] = f2bf(tile[nl][kl]);
    }
}

// ---------------------------------------------------------------------------
// lambda per head
// ---------------------------------------------------------------------------
__global__ __launch_bounds__(64) void lambda_kernel(
    const float* __restrict__ lq1, const float* __restrict__ lk1,
    const float* __restrict__ lq2, const float* __restrict__ lk2,
    const int* __restrict__ layer_idx, float* __restrict__ lam)
{
    int h = blockIdx.x, l = threadIdx.x;
    float li = (float)layer_idx[0];
    float dyn = 0.8f - 0.6f * expf(-0.3f * (li - 1.0f));
    int i = h * HSc + l;
    float v = expf(lq1[i] * lk1[i]) - expf(lq2[i] * lk2[i]) + dyn;
    #pragma unroll
    for (int off = 32; off; off >>= 1) v += __shfl_xor(v, off);
    if (l == 0) lam[h] = v * (1.0f / 64.0f);
}

// ---------------------------------------------------------------------------
// MFMA GEMM (m97 structure): C[M][LDC] = A[M][KD] * Bt[N][KD]^T, bf16 inputs.
// SPLITV: cols >= 3072 (V projection) -> written transposed to VtOut[bh][e][t].
// ---------------------------------------------------------------------------
template<int TN, int KD, int LDC, bool OUT_BIAS, bool SPLITV>
__global__ __launch_bounds__(256) void gemm_mfma(
    const unsigned short* __restrict__ A, const unsigned short* __restrict__ Bt,
    unsigned short* __restrict__ Cb, float* __restrict__ Cf,
    const float* __restrict__ bias, unsigned short* __restrict__ VtOut)
{
    constexpr int BN = TN * 32;
    constexpr int JB = TN / 2;
    __shared__ unsigned short As[128 * 32];
    __shared__ unsigned short Bs[BN * 32];
    int tid = threadIdx.x, lane = tid & 63, w = tid >> 6;
    int wm = w >> 1, wn = w & 1;
    int m0 = blockIdx.y * 128, n0 = blockIdx.x * BN;

    int lr = lane >> 2, lq = lane & 3;
    const unsigned short* gA[2];
    const unsigned short* gB[JB];
    #pragma unroll
    for (int j = 0; j < 2; ++j) {
        int row = w * 32 + j * 16 + lr;
        int qg = lq ^ ((row >> 1) & 3);
        gA[j] = A + (size_t)(m0 + row) * KD + qg * 8;
    }
    #pragma unroll
    for (int j = 0; j < JB; ++j) {
        int row = w * (JB * 16) + j * 16 + lr;
        int qg = lq ^ ((row >> 1) & 3);
        gB[j] = Bt + (size_t)(n0 + row) * KD + qg * 8;
    }

    int rr = lane & 15, qd = lane >> 4;
    const unsigned short* aAddr[4];
    const unsigned short* bAddr[TN];
    #pragma unroll
    for (int i = 0; i < 4; ++i) {
        int row = wm * 64 + i * 16 + rr;
        int qs = qd ^ ((row >> 1) & 3);
        aAddr[i] = As + row * 32 + qs * 8;
    }
    #pragma unroll
    for (int t = 0; t < TN; ++t) {
        int row = wn * (TN * 16) + t * 16 + rr;
        int qs = qd ^ ((row >> 1) & 3);
        bAddr[t] = Bs + row * 32 + qs * 8;
    }

    f32x4 acc[4][TN];
    #pragma unroll
    for (int i = 0; i < 4; ++i)
        #pragma unroll
        for (int t = 0; t < TN; ++t) acc[i][t] = {0.f, 0.f, 0.f, 0.f};

    for (int k = 0; k < KD / 32; ++k) {
        __syncthreads();
        load16_lds(gA[0], As + (w * 2 + 0) * 512);
        load16_lds(gA[1], As + (w * 2 + 1) * 512);
        #pragma unroll
        for (int j = 0; j < JB; ++j)
            load16_lds(gB[j], Bs + (w * JB + j) * 512);
        gA[0] += 32; gA[1] += 32;
        #pragma unroll
        for (int j = 0; j < JB; ++j) gB[j] += 32;
        __syncthreads();

        bf16x8 af[4], bfr[TN];
        #pragma unroll
        for (int i = 0; i < 4; ++i) af[i] = *(const bf16x8*)aAddr[i];
        #pragma unroll
        for (int t = 0; t < TN; ++t) bfr[t] = *(const bf16x8*)bAddr[t];
        #pragma unroll
        for (int i = 0; i < 4; ++i)
            #pragma unroll
            for (int t = 0; t < TN; ++t)
                acc[i][t] = __builtin_amdgcn_mfma_f32_16x16x32_bf16(af[i], bfr[t], acc[i][t], 0, 0, 0);
    }

    #pragma unroll
    for (int t = 0; t < TN; ++t) {
        int col = n0 + wn * (TN * 16) + t * 16 + rr;
        if (SPLITV && col >= 3072) {
            int rel = col - 3072, hh = rel >> 7, e = rel & 127;
            #pragma unroll
            for (int i = 0; i < 4; ++i) {
                int row0 = m0 + wm * 64 + i * 16 + qd * 4;
                int b = row0 >> 10, tt = row0 & 1023;
                ushort4 pk;
                pk.x = f2bf(acc[i][t][0]); pk.y = f2bf(acc[i][t][1]);
                pk.z = f2bf(acc[i][t][2]); pk.w = f2bf(acc[i][t][3]);
                *(ushort4*)&VtOut[(size_t)((b * Hc + hh) * 128 + e) * 1024 + tt] = pk;
            }
        } else {
            float bv = OUT_BIAS ? bias[col] : 0.f;
            #pragma unroll
            for (int i = 0; i < 4; ++i) {
                #pragma unroll
                for (int r = 0; r < 4; ++r) {
                    int row = m0 + wm * 64 + i * 16 + qd * 4 + r;
                    if (OUT_BIAS)
                        Cf[(size_t)row * LDC + col] = acc[i][t][r] + bv;
                    else
                        Cb[(size_t)row * LDC + col] = f2bf(acc[i][t][r]);
                }
            }
        }
    }
}

// ---------------------------------------------------------------------------
// MFMA differential flash attention — R10: intra-block split-KV, FIXED VGPR
// budget. R9's __launch_bounds__(256,4) capped unified VGPR+AGPR at 128/wave
// -> the ~230-reg wave state (Q 16 + K dbuf 64 + V dbuf 64 + O acc 64 + addr)
// spilled to scratch: WRITE_SIZE 825 MB, MfmaUtil 2.7%, 295 us. (256,2)
// restores a 256-reg cap: no spill, 2 blocks/CU resident (8 waves/CU), 6
// blocks/CU queued.
// grid (48, 32): x = bh (XCD-pinned KV), y -> QT = 31 - y (longest first).
// block 256 = 4 waves: wave (rg, s): rg = wv&1 (16-row group), s = wv>>1
// (KV half: s=0 -> [0, ceil(n/2)), s=1 -> rest, n = QT+1). Halves the
// critical path of long blocks at zero extra HBM traffic (partials additive,
// no online max in this exp formulation); combine via ~20 KB LDS f32.
// ---------------------------------------------------------------------------
__global__ __launch_bounds__(256, 2) void diff_attn_mfma(
    const unsigned short* __restrict__ Y, const unsigned short* __restrict__ Vt,
    const float* __restrict__ lam_buf, unsigned short* __restrict__ attn)
{
    __shared__ __align__(16) unsigned int PL32[4][16 * PW_S]; // per-wave packed P
    __shared__ __align__(16) float Oex[2][128][20];           // [rg][e][row(16)+pad4]
    __shared__ float lex[2][16][2];                           // [rg][row][l1,l2]

    int bh = blockIdx.x;                          // fastest dim -> XCD-pinned
    int b = bh / Hc, h = bh - b * Hc;
    int QT = 31 - (int)blockIdx.y;                // longest first
    int tid = threadIdx.x, lane = tid & 63, wv = tid >> 6;
    int rg = wv & 1;                              // row-group: rows rg*16..rg*16+15
    int sh = wv >> 1;                             // KV half
    int cl = lane & 15, qd = lane >> 4;
    float lamv = lam_buf[h];
    size_t rowbase = (size_t)(b * Tc) * YLD;
    const int hq = h * HSc;
    unsigned int* Pw = PL32[wv];
    const unsigned short* VtB = Vt + ((size_t)bh << 17);   // bh*128*1024
    const f32x4 zero4 = {0.f, 0.f, 0.f, 0.f};

    bf16x8 ka[2][4], kb[2][4], va[8], vb2[8];

    auto loadK = [&](int kt, bf16x8 kf[2][4]) {
        #pragma unroll
        for (int c = 0; c < 2; ++c) {
            size_t koff = rowbase + (size_t)(kt * 32 + c * 16 + cl) * YLD;
            kf[c][0] = *(const bf16x8*)(Y + koff + K1OFF + hq + qd * 8);
            kf[c][1] = *(const bf16x8*)(Y + koff + K1OFF + hq + 32 + qd * 8);
            kf[c][2] = *(const bf16x8*)(Y + koff + K2OFF + hq + qd * 8);
            kf[c][3] = *(const bf16x8*)(Y + koff + K2OFF + hq + 32 + qd * 8);
        }
    };
    auto loadV = [&](int kt, bf16x8 vf[8]) {
        #pragma unroll
        for (int ec = 0; ec < 8; ++ec)
            vf[ec] = *(const bf16x8*)(VtB + (((ec * 16 + cl) << 10) + kt * 32 + qd * 8));
    };

    int qrow = QT * 32 + rg * 16;

    size_t qoff = rowbase + (size_t)(qrow + cl) * YLD;
    bf16x8 q1a = *(const bf16x8*)(Y + qoff + Q1OFF + hq + qd * 8);
    bf16x8 q1b = *(const bf16x8*)(Y + qoff + Q1OFF + hq + 32 + qd * 8);
    bf16x8 q2a = *(const bf16x8*)(Y + qoff + Q2OFF + hq + qd * 8);
    bf16x8 q2b = *(const bf16x8*)(Y + qoff + Q2OFF + hq + 32 + qd * 8);

    f32x4 O1[8], O2[8];
    #pragma unroll
    for (int ec = 0; ec < 8; ++ec) { O1[ec] = zero4; O2[ec] = zero4; }
    float l1[4] = {0.f, 0.f, 0.f, 0.f}, l2[4] = {0.f, 0.f, 0.f, 0.f};

    auto tile = [&](int kt, bf16x8 kf[2][4], bf16x8 vf[8], bool diag) {
        f32x4 S1[2], S2[2];
        #pragma unroll
        for (int c = 0; c < 2; ++c) { S1[c] = zero4; S2[c] = zero4; }
        #pragma unroll
        for (int c = 0; c < 2; ++c) {
            S1[c] = __builtin_amdgcn_mfma_f32_16x16x32_bf16(q1a, kf[c][0], S1[c], 0, 0, 0);
            S1[c] = __builtin_amdgcn_mfma_f32_16x16x32_bf16(q1b, kf[c][1], S1[c], 0, 0, 0);
            S2[c] = __builtin_amdgcn_mfma_f32_16x16x32_bf16(q2a, kf[c][2], S2[c], 0, 0, 0);
            S2[c] = __builtin_amdgcn_mfma_f32_16x16x32_bf16(q2b, kf[c][3], S2[c], 0, 0, 0);
        }
        if (diag) {
            #pragma unroll
            for (int c = 0; c < 2; ++c) {
                int key_local = c * 16 + cl;
                #pragma unroll
                for (int r = 0; r < 4; ++r) {
                    int row_local = rg * 16 + qd * 4 + r;
                    if (key_local > row_local) { S1[c][r] = -1e30f; S2[c][r] = -1e30f; }
                }
            }
        }
        // p = exp(s/8) = exp2(s * 0.125*log2e): one v_mul + one v_exp each
        #pragma unroll
        for (int r = 0; r < 4; ++r) {
            float p10 = exp2f(S1[0][r] * EXP2SCALE);
            float p11 = exp2f(S1[1][r] * EXP2SCALE);
            float p20 = exp2f(S2[0][r] * EXP2SCALE);
            float p21 = exp2f(S2[1][r] * EXP2SCALE);
            l1[r] += p10 + p11;
            l2[r] += p20 + p21;
            int row = (qd << 2) + r;
            Pw[row * PW_S + cl]      = pack2bf(p10, p20);   // key = cl
            Pw[row * PW_S + cl + 16] = pack2bf(p11, p21);   // key = cl+16
        }
        // read back as A-operand fragments: row = cl, keys qd*8..qd*8+7
        const unsigned int* rp = Pw + cl * PW_S + qd * 8;
        uint4 L0 = *(const uint4*)(rp);
        uint4 L1 = *(const uint4*)(rp + 4);
        uint4 u1, u2;
        u1.x = __builtin_amdgcn_perm(L0.y, L0.x, 0x05040100u);
        u1.y = __builtin_amdgcn_perm(L0.w, L0.z, 0x05040100u);
        u1.z = __builtin_amdgcn_perm(L1.y, L1.x, 0x05040100u);
        u1.w = __builtin_amdgcn_perm(L1.w, L1.z, 0x05040100u);
        u2.x = __builtin_amdgcn_perm(L0.y, L0.x, 0x07060302u);
        u2.y = __builtin_amdgcn_perm(L0.w, L0.z, 0x07060302u);
        u2.z = __builtin_amdgcn_perm(L1.y, L1.x, 0x07060302u);
        u2.w = __builtin_amdgcn_perm(L1.w, L1.z, 0x07060302u);
        bf16x8 pa1 = __builtin_bit_cast(bf16x8, u1);
        bf16x8 pa2 = __builtin_bit_cast(bf16x8, u2);
        #pragma unroll
        for (int ec = 0; ec < 8; ++ec) {
            O1[ec] = __builtin_amdgcn_mfma_f32_16x16x32_bf16(pa1, vf[ec], O1[ec], 0, 0, 0);
            O2[ec] = __builtin_amdgcn_mfma_f32_16x16x32_bf16(pa2, vf[ec], O2[ec], 0, 0, 0);
        }
    };

    // KV range for this wave: s=0 -> [0, nh), s=1 -> [nh, n)
    int n = QT + 1;
    int nh = (n + 1) >> 1;
    int lo = sh ? nh : 0;
    int hi = sh ? n : nh;

    if (lo < hi) { loadK(lo, ka); loadV(lo, va); }
    for (int kt = lo; kt < hi; kt += 2) {
        if (kt + 1 < hi) { loadK(kt + 1, kb); loadV(kt + 1, vb2); }
        tile(kt, ka, va, kt == QT);
        if (kt + 1 < hi) {
            if (kt + 2 < hi) { loadK(kt + 2, ka); loadV(kt + 2, va); }
            tile(kt + 1, kb, vb2, kt + 1 == QT);
        }
    }

    // reduce partial l across the 16 column-lanes
    float la1[4], la2[4];
    #pragma unroll
    for (int r = 0; r < 4; ++r) {
        float a = l1[r], c = l2[r];
        a += __shfl_xor(a, 1); a += __shfl_xor(a, 2);
        a += __shfl_xor(a, 4); a += __shfl_xor(a, 8);
        c += __shfl_xor(c, 1); c += __shfl_xor(c, 2);
        c += __shfl_xor(c, 4); c += __shfl_xor(c, 8);
        la1[r] = a; la2[r] = c;
    }

    // --- combine the two KV halves through LDS (f32, 2 phases) ---
    if (sh == 1) {
        #pragma unroll
        for (int ec = 0; ec < 8; ++ec)
            *(f32x4*)&Oex[rg][ec * 16 + cl][qd * 4] = O1[ec];
        if (cl == 0) {
            #pragma unroll
            for (int r = 0; r < 4; ++r) {
                lex[rg][qd * 4 + r][0] = la1[r];
                lex[rg][qd * 4 + r][1] = la2[r];
            }
        }
    }
    __syncthreads();
    if (sh == 0) {
        #pragma unroll
        for (int ec = 0; ec < 8; ++ec)
            O1[ec] += *(const f32x4*)&Oex[rg][ec * 16 + cl][qd * 4];
        #pragma unroll
        for (int r = 0; r < 4; ++r) {
            la1[r] += lex[rg][qd * 4 + r][0];
            la2[r] += lex[rg][qd * 4 + r][1];
        }
    }
    __syncthreads();
    if (sh == 1) {
        #pragma unroll
        for (int ec = 0; ec < 8; ++ec)
            *(f32x4*)&Oex[rg][ec * 16 + cl][qd * 4] = O2[ec];
    }
    __syncthreads();
    if (sh == 0) {
        #pragma unroll
        for (int ec = 0; ec < 8; ++ec)
            O2[ec] += *(const f32x4*)&Oex[rg][ec * 16 + cl][qd * 4];

        float w1[4], w2[4];
        #pragma unroll
        for (int r = 0; r < 4; ++r) {
            w1[r] = 1.0f / la1[r];
            w2[r] = lamv / la2[r];
        }
        #pragma unroll
        for (int ec = 0; ec < 8; ++ec) {
            #pragma unroll
            for (int r = 0; r < 4; ++r) {
                size_t row = (size_t)(b * Tc + qrow + qd * 4 + r);
                attn[row * HVD + h * VDc + ec * 16 + cl] =
                    f2bf(O1[ec][r] * w1[r] - O2[ec][r] * w2[r]);
            }
        }
    }
}

// ---------------------------------------------------------------------------
// Fused row-stats + LayerNorm*0.2, in-place on bf16 attn. 128 thr/row.
// ---------------------------------------------------------------------------
__global__ __launch_bounds__(128) void ln_inplace(
    unsigned short* __restrict__ attn,
    const float* __restrict__ gnw, const float* __restrict__ gnb)
{
    int row = blockIdx.x, tid = threadIdx.x;
    unsigned short* p = attn + (size_t)row * HVD;
    float v[12];
    float s = 0.f, sq = 0.f;
    #pragma unroll
    for (int j = 0; j < 3; ++j) {
        int g = tid + j * 128;
        ushort4 u = *(const ushort4*)(p + g * 4);
        float x0 = bf2f(u.x), x1 = bf2f(u.y), x2 = bf2f(u.z), x3 = bf2f(u.w);
        v[j * 4 + 0] = x0; v[j * 4 + 1] = x1; v[j * 4 + 2] = x2; v[j * 4 + 3] = x3;
        s += x0 + x1 + x2 + x3;
        sq = fmaf(x0, x0, sq); sq = fmaf(x1, x1, sq);
        sq = fmaf(x2, x2, sq); sq = fmaf(x3, x3, sq);
    }
    #pragma unroll
    for (int off = 32; off; off >>= 1) { s += __shfl_xor(s, off); sq += __shfl_xor(sq, off); }
    __shared__ float ss[2], sqs[2];
    if ((tid & 63) == 0) { ss[tid >> 6] = s; sqs[tid >> 6] = sq; }
    __syncthreads();
    float S = ss[0] + ss[1], Q = sqs[0] + sqs[1];
    float mu = S * (1.0f / HVD);
    float rstd = rsqrtf(Q * (1.0f / HVD) - mu * mu + 1e-5f);
    #pragma unroll
    for (int j = 0; j < 3; ++j) {
        int g = tid + j * 128;
        float4 gw = *(const float4*)(gnw + g * 4);
        float4 gb = *(const float4*)(gnb + g * 4);
        ushort4 o;
        o.x = f2bf(((v[j * 4 + 0] - mu) * rstd * gw.x + gb.x) * 0.2f);
        o.y = f2bf(((v[j * 4 + 1] - mu) * rstd * gw.y + gb.y) * 0.2f);
        o.z = f2bf(((v[j * 4 + 2] - mu) * rstd * gw.z + gb.z) * 0.2f);
        o.w = f2bf(((v[j * 4 + 3] - mu) * rstd * gw.w + gb.w) * 0.2f);
        *(ushort4*)(p + g * 4) = o;
    }
}

// ---------------------------------------------------------------------------
// launch
// ---------------------------------------------------------------------------
extern "C" void kernel_launch(void* const* d_in, const int* in_sizes, int n_in,
                              void* d_out, int out_size, void* d_ws, size_t ws_size,
                              hipStream_t stream)
{
    const float* x   = (const float*)d_in[0];
    const float* Wq1 = (const float*)d_in[1];
    const float* Wk1 = (const float*)d_in[2];
    const float* Wq2 = (const float*)d_in[3];
    const float* Wk2 = (const float*)d_in[4];
    const float* Wv  = (const float*)d_in[5];
    const float* lq1 = (const float*)d_in[6];
    const float* lk1 = (const float*)d_in[7];
    const float* lq2 = (const float*)d_in[8];
    const float* lk2 = (const float*)d_in[9];
    const float* gnw = (const float*)d_in[10];
    const float* gnb = (const float*)d_in[11];
    const float* Wp  = (const float*)d_in[12];
    const float* bp  = (const float*)d_in[13];
    const int*   lidx = (const int*)d_in[14];
    float* out = (float*)d_out;

    // workspace layout (bytes):
    // WcatT bf16 [4608][768]:  7,077,888 @ 0
    // Xb    bf16 [4096][768]:  6,291,456 @ 7,077,888
    // Y     bf16 [4096][3072]: 25,165,824 @ 13,369,344
    // Vt    bf16 [48][128][1024]: 12,582,912 @ 38,535,168
    // attn  bf16 [4096][1536]: 12,582,912 @ 51,118,080
    // Wpb   bf16 [768][1536]:   2,359,296 @ 63,700,992
    // lam   f32 [12]                       @ 66,060,288
    char* w = (char*)d_ws;
    unsigned short* WcatT = (unsigned short*)(w);
    unsigned short* Xb    = (unsigned short*)(w + 7077888);
    unsigned short* Y     = (unsigned short*)(w + 13369344);
    unsigned short* VtW   = (unsigned short*)(w + 38535168);
    unsigned short* attn  = (unsigned short*)(w + 51118080);
    unsigned short* Wpb   = (unsigned short*)(w + 63700992);
    float* lam            = (float*)(w + 66060288);

    cast_bf16<<<dim3(NROWS * Cc / 1024), 256, 0, stream>>>(x, Xb);
    cast_bf16<<<dim3(Cc * HVD / 1024), 256, 0, stream>>>(Wp, Wpb);
    trans_w<<<dim3(72 * 12), 256, 0, stream>>>(Wq1, Wk1, Wq2, Wk2, Wv, WcatT);
    lambda_kernel<<<dim3(Hc), 64, 0, stream>>>(lq1, lk1, lq2, lk2, lidx, lam);
    // QKV: [4096,768] x [768,4608]; Q/K -> Y (LD 3072), V -> Vt transposed
    gemm_mfma<4, 768, YLD, false, true><<<dim3(NQKV / 128, NROWS / 128), 256, 0, stream>>>(
        Xb, WcatT, Y, nullptr, nullptr, VtW);
    // bh fastest (XCD pin); y -> QT = 31-y, longest-first; 1536 blocks x 4 waves,
    // intra-block split-KV (s=0/1 halves combined through LDS)
    diff_attn_mfma<<<dim3(Bc * Hc, 32), 256, 0, stream>>>(Y, VtW, lam, attn);
    ln_inplace<<<dim3(NROWS), 128, 0, stream>>>(attn, gnw, gnb);
    // OUT: [4096,1536] x [1536,768] -> out fp32 (+bias)
    gemm_mfma<2, HVD, Cc, true, false><<<dim3(Cc / 64, NROWS / 128), 256, 0, stream>>>(
        attn, Wpb, nullptr, out, bp, nullptr);
}

// Round 4
// 284.179 us; speedup vs baseline: 1.6981x; 1.0446x over previous
//
#include <hip/hip_runtime.h>
#include <hip/hip_bf16.h>

// Problem constants
#define Bc   4
#define Tc   1024
#define Cc   768
#define Hc   12
#define HSc  64
#define VDc  128
#define NQKV 4608   // gemm N for qkv (4*768 Q/K + 1536 V)
#define YLD  3072   // Y row stride: Q/K only (V goes to Vt)
#define NROWS 4096  // B*T
#define HVD  1536   // H*VD

// Y (qk) column offsets
#define Q1OFF 0
#define K1OFF 768
#define Q2OFF 1536
#define K2OFF 2304

typedef __bf16 bf16x8 __attribute__((ext_vector_type(8)));
typedef float f32x4 __attribute__((ext_vector_type(4)));

#define PW_S 36   // P row stride in dwords: 144B rows, 16B aligned, <=2-way banks
// exp(s*0.125) == exp2(s * 0.125*log2(e))
#define EXP2SCALE 0.18033688011112042f

static __device__ __forceinline__ float bf2f(unsigned short s) {
    return __uint_as_float(((unsigned int)s) << 16);
}
static __device__ __forceinline__ unsigned short f2bf(float f) {
    unsigned int u = __float_as_uint(f);
    unsigned int r = (u + 0x7FFFu + ((u >> 16) & 1u)) >> 16;  // round-nearest-even
    return (unsigned short)r;
}
static __device__ __forceinline__ unsigned int pack2bf(float lo, float hi) {
    // bf16(lo) | bf16(hi)<<16, half-up rounding (values >= 0)
    unsigned int a = (__float_as_uint(lo) + 0x8000u) >> 16;
    unsigned int b = (__float_as_uint(hi) + 0x8000u) & 0xFFFF0000u;
    return a | b;
}

// async global->LDS 16B per lane; lds base must be wave-uniform
static __device__ __forceinline__ void load16_lds(const void* g, void* l) {
    __builtin_amdgcn_global_load_lds(
        (const __attribute__((address_space(1))) void*)g,
        (__attribute__((address_space(3))) void*)l, 16, 0, 0);
}

// ---------------------------------------------------------------------------
// cast fp32 -> bf16, 4 elts/thread
// ---------------------------------------------------------------------------
__global__ __launch_bounds__(256) void cast_bf16(
    const float* __restrict__ src, unsigned short* __restrict__ dst)
{
    int i = blockIdx.x * 256 + threadIdx.x;
    float4 v = *(const float4*)(src + (size_t)i * 4);
    ushort4 u;
    u.x = f2bf(v.x); u.y = f2bf(v.y); u.z = f2bf(v.z); u.w = f2bf(v.w);
    *(ushort4*)(dst + (size_t)i * 4) = u;
}

// ---------------------------------------------------------------------------
// Transpose-repack the 5 projection weights into WcatT[n][k] bf16, k-contig.
// ---------------------------------------------------------------------------
__global__ __launch_bounds__(256) void trans_w(
    const float* __restrict__ Wq1, const float* __restrict__ Wk1,
    const float* __restrict__ Wq2, const float* __restrict__ Wk2,
    const float* __restrict__ Wv, unsigned short* __restrict__ WcatT)
{
    __shared__ float tile[64][65];
    int tid = threadIdx.x;
    int t = blockIdx.x;
    int kt = t % 12, nt = t / 12;
    int k0 = kt * 64, n0 = nt * 64;
    const float* src;
    int stride;
    if (n0 < 3072) {
        int which = n0 / 768, m = n0 - which * 768, h = m >> 6;
        const float* W = (which == 0) ? Wq1 : (which == 1) ? Wk1 : (which == 2) ? Wq2 : Wk2;
        src = W + ((size_t)h * 768 + k0) * 64;
        stride = 64;
    } else {
        int rel = n0 - 3072, h = rel >> 7, e0 = rel & 127;
        src = Wv + ((size_t)h * 768 + k0) * 128 + e0;
        stride = 128;
    }
    for (int i = tid; i < 4096; i += 256) {
        int kl = i >> 6, dl = i & 63;
        tile[dl][kl] = src[(size_t)kl * stride + dl];
    }
    __syncthreads();
    for (int i = tid; i < 4096; i += 256) {
        int nl = i >> 6, kl = i & 63;
        WcatT[(size_t)(n0 + nl) * 768 + k0 + kl] = f2bf(tile[nl][kl]);
    }
}

// ---------------------------------------------------------------------------
// lambda per head
// ---------------------------------------------------------------------------
__global__ __launch_bounds__(64) void lambda_kernel(
    const float* __restrict__ lq1, const float* __restrict__ lk1,
    const float* __restrict__ lq2, const float* __restrict__ lk2,
    const int* __restrict__ layer_idx, float* __restrict__ lam)
{
    int h = blockIdx.x, l = threadIdx.x;
    float li = (float)layer_idx[0];
    float dyn = 0.8f - 0.6f * expf(-0.3f * (li - 1.0f));
    int i = h * HSc + l;
    float v = expf(lq1[i] * lk1[i]) - expf(lq2[i] * lk2[i]) + dyn;
    #pragma unroll
    for (int off = 32; off; off >>= 1) v += __shfl_xor(v, off);
    if (l == 0) lam[h] = v * (1.0f / 64.0f);
}

// ---------------------------------------------------------------------------
// MFMA GEMM (m97 structure): C[M][LDC] = A[M][KD] * Bt[N][KD]^T, bf16 inputs.
// SPLITV: cols >= 3072 (V projection) -> written transposed to VtOut[bh][e][t].
// ---------------------------------------------------------------------------
template<int TN, int KD, int LDC, bool OUT_BIAS, bool SPLITV>
__global__ __launch_bounds__(256) void gemm_mfma(
    const unsigned short* __restrict__ A, const unsigned short* __restrict__ Bt,
    unsigned short* __restrict__ Cb, float* __restrict__ Cf,
    const float* __restrict__ bias, unsigned short* __restrict__ VtOut)
{
    constexpr int BN = TN * 32;
    constexpr int JB = TN / 2;
    __shared__ unsigned short As[128 * 32];
    __shared__ unsigned short Bs[BN * 32];
    int tid = threadIdx.x, lane = tid & 63, w = tid >> 6;
    int wm = w >> 1, wn = w & 1;
    int m0 = blockIdx.y * 128, n0 = blockIdx.x * BN;

    int lr = lane >> 2, lq = lane & 3;
    const unsigned short* gA[2];
    const unsigned short* gB[JB];
    #pragma unroll
    for (int j = 0; j < 2; ++j) {
        int row = w * 32 + j * 16 + lr;
        int qg = lq ^ ((row >> 1) & 3);
        gA[j] = A + (size_t)(m0 + row) * KD + qg * 8;
    }
    #pragma unroll
    for (int j = 0; j < JB; ++j) {
        int row = w * (JB * 16) + j * 16 + lr;
        int qg = lq ^ ((row >> 1) & 3);
        gB[j] = Bt + (size_t)(n0 + row) * KD + qg * 8;
    }

    int rr = lane & 15, qd = lane >> 4;
    const unsigned short* aAddr[4];
    const unsigned short* bAddr[TN];
    #pragma unroll
    for (int i = 0; i < 4; ++i) {
        int row = wm * 64 + i * 16 + rr;
        int qs = qd ^ ((row >> 1) & 3);
        aAddr[i] = As + row * 32 + qs * 8;
    }
    #pragma unroll
    for (int t = 0; t < TN; ++t) {
        int row = wn * (TN * 16) + t * 16 + rr;
        int qs = qd ^ ((row >> 1) & 3);
        bAddr[t] = Bs + row * 32 + qs * 8;
    }

    f32x4 acc[4][TN];
    #pragma unroll
    for (int i = 0; i < 4; ++i)
        #pragma unroll
        for (int t = 0; t < TN; ++t) acc[i][t] = {0.f, 0.f, 0.f, 0.f};

    for (int k = 0; k < KD / 32; ++k) {
        __syncthreads();
        load16_lds(gA[0], As + (w * 2 + 0) * 512);
        load16_lds(gA[1], As + (w * 2 + 1) * 512);
        #pragma unroll
        for (int j = 0; j < JB; ++j)
            load16_lds(gB[j], Bs + (w * JB + j) * 512);
        gA[0] += 32; gA[1] += 32;
        #pragma unroll
        for (int j = 0; j < JB; ++j) gB[j] += 32;
        __syncthreads();

        bf16x8 af[4], bfr[TN];
        #pragma unroll
        for (int i = 0; i < 4; ++i) af[i] = *(const bf16x8*)aAddr[i];
        #pragma unroll
        for (int t = 0; t < TN; ++t) bfr[t] = *(const bf16x8*)bAddr[t];
        #pragma unroll
        for (int i = 0; i < 4; ++i)
            #pragma unroll
            for (int t = 0; t < TN; ++t)
                acc[i][t] = __builtin_amdgcn_mfma_f32_16x16x32_bf16(af[i], bfr[t], acc[i][t], 0, 0, 0);
    }

    #pragma unroll
    for (int t = 0; t < TN; ++t) {
        int col = n0 + wn * (TN * 16) + t * 16 + rr;
        if (SPLITV && col >= 3072) {
            int rel = col - 3072, hh = rel >> 7, e = rel & 127;
            #pragma unroll
            for (int i = 0; i < 4; ++i) {
                int row0 = m0 + wm * 64 + i * 16 + qd * 4;
                int b = row0 >> 10, tt = row0 & 1023;
                ushort4 pk;
                pk.x = f2bf(acc[i][t][0]); pk.y = f2bf(acc[i][t][1]);
                pk.z = f2bf(acc[i][t][2]); pk.w = f2bf(acc[i][t][3]);
                *(ushort4*)&VtOut[(size_t)((b * Hc + hh) * 128 + e) * 1024 + tt] = pk;
            }
        } else {
            float bv = OUT_BIAS ? bias[col] : 0.f;
            #pragma unroll
            for (int i = 0; i < 4; ++i) {
                #pragma unroll
                for (int r = 0; r < 4; ++r) {
                    int row = m0 + wm * 64 + i * 16 + qd * 4 + r;
                    if (OUT_BIAS)
                        Cf[(size_t)row * LDC + col] = acc[i][t][r] + bv;
                    else
                        Cb[(size_t)row * LDC + col] = f2bf(acc[i][t][r]);
                }
            }
        }
    }
}

// ---------------------------------------------------------------------------
// MFMA differential flash attention — R12: LDS-staged shared K/V.
// (R11 intent; fixed: (a) no constant-initialized array of LDS pointers —
// gfx950 rejects the addrspacecast static initializer, index KV[cur] at use;
// (b) diag trigger kt*32+31 > qrow (qrow+15 missed the partial tile for
// odd 16-row waves).)
// R8 vs R10 showed per-CU tile throughput invariant to wave count -> per-CU
// memory-system (L1/TCP line) saturation: each wave independently loaded
// K/V, 256 distinct cachelines per wave-tile, duplicated across waves.
// Fix: 64 Q-rows per block (4 waves x 16 rows, all distinct -> no cross-wave
// combine), K1/K2 (8KB) + V (8KB) per K-tile staged ONCE per block into
// double-buffered LDS via global_load_lds (waves 0/1 stage K, waves 2/3
// stage V; inverse-XOR-swizzled global source, XOR-swizzled ds_read_b128).
// ~3.9x fewer L1 lines; one barrier per tile; stage(kt+1) issued before
// compute(kt) so the vmcnt-drain at __syncthreads overlaps with compute.
// grid (48, 16): x = bh (XCD-pinned: 48%8==0), y -> g = 15-y (longest
// first); block g covers Q-rows 64g..64g+63, K-tiles 0..2g+1.
// LDS: 2x16KB KV dbuf + 4x2.25KB P = 41984 B -> 3 blocks/CU.
// ---------------------------------------------------------------------------
__global__ __launch_bounds__(256) void diff_attn_mfma(
    const unsigned short* __restrict__ Y, const unsigned short* __restrict__ Vt,
    const float* __restrict__ lam_buf, unsigned short* __restrict__ attn)
{
    // KV[buf] byte layout: K1 [0,4096), K2 [4096,8192), V [8192,16384)
    __shared__ __align__(16) unsigned short KV[2][8192];
    __shared__ __align__(16) unsigned int PL32[4][16 * PW_S]; // per-wave packed P

    int bh = blockIdx.x;                          // fastest dim -> XCD-pinned
    int b = bh / Hc, h = bh - b * Hc;
    int g = 15 - (int)blockIdx.y;                 // longest first
    int tid = threadIdx.x, lane = tid & 63, wv = tid >> 6;
    int cl = lane & 15, qd = lane >> 4;
    float lamv = lam_buf[h];
    size_t rowbase = (size_t)(b * Tc) * YLD;
    const int hq = h * HSc;
    unsigned int* Pw = PL32[wv];
    const unsigned short* VtB = Vt + ((size_t)bh << 17);   // bh*128*1024
    const f32x4 zero4 = {0.f, 0.f, 0.f, 0.f};

    // ---- staging lane->global mappings (kt-independent parts) ----
    // K (waves 0,1): seg r8 holds rows r8*8..r8*8+7, 8 chunks of 16B per row.
    // LDS slot: row = r8*8 + lane>>3, lds chunk = lane&7;
    // stored global chunk = (lane&7) ^ (row&7)  [inverse of read swizzle]
    int ksrow = lane >> 3;                 // row within seg
    int ksch  = (lane & 7) ^ ksrow;        // global chunk
    int offk[4];
    {
        int mat = wv & 1;                  // wave0 -> K1, wave1 -> K2
        int moff = mat ? K2OFF : K1OFF;
        #pragma unroll
        for (int r8 = 0; r8 < 4; ++r8)
            offk[r8] = (r8 * 8 + ksrow) * YLD + moff + hq + ksch * 8;
    }
    // V (waves 2,3): seg sv holds e-rows sv*16..sv*16+15, 4 chunks of 16B.
    // LDS slot: e = sv*16 + lane>>2, lds chunk = lane&3;
    // stored global chunk = (lane&3) ^ (e&3)
    int vsel = lane >> 2;                  // e within seg
    int vsch = (lane & 3) ^ (vsel & 3);
    int offv[4];
    {
        int sv0 = (wv & 1) * 4;            // wave2 -> sv 0..3, wave3 -> sv 4..7
        #pragma unroll
        for (int i = 0; i < 4; ++i)
            offv[i] = ((sv0 + i) * 16 + vsel) * 1024 + vsch * 8;
    }

    auto stage = [&](int kt, int cur) {
        char* base = (char*)KV[cur] + wv * 4096;
        if (wv < 2) {
            const unsigned short* g0 = Y + rowbase + (size_t)(kt * 32) * YLD;
            #pragma unroll
            for (int r8 = 0; r8 < 4; ++r8)
                load16_lds(g0 + offk[r8], base + r8 * 1024);
        } else {
            const unsigned short* g0 = VtB + kt * 32;
            #pragma unroll
            for (int i = 0; i < 4; ++i)
                load16_lds(g0 + offv[i], base + i * 1024);
        }
    };

    // ---- fragment LDS byte offsets (swizzled reads) ----
    int kfo[2][4], vfo[8];
    #pragma unroll
    for (int c = 0; c < 2; ++c) {
        int row = c * 16 + cl;
        #pragma unroll
        for (int j = 0; j < 4; ++j)
            kfo[c][j] = (j >> 1) * 4096 + row * 128 +
                        ((((j & 1) * 4 + qd) ^ (row & 7)) << 4);
    }
    #pragma unroll
    for (int ec = 0; ec < 8; ++ec) {
        int e = ec * 16 + cl;
        vfo[ec] = 8192 + e * 64 + ((qd ^ (e & 3)) << 4);
    }

    int qrow = g * 64 + wv * 16;

    size_t qoff = rowbase + (size_t)(qrow + cl) * YLD;
    bf16x8 q1a = *(const bf16x8*)(Y + qoff + Q1OFF + hq + qd * 8);
    bf16x8 q1b = *(const bf16x8*)(Y + qoff + Q1OFF + hq + 32 + qd * 8);
    bf16x8 q2a = *(const bf16x8*)(Y + qoff + Q2OFF + hq + qd * 8);
    bf16x8 q2b = *(const bf16x8*)(Y + qoff + Q2OFF + hq + 32 + qd * 8);

    f32x4 O1[8], O2[8];
    #pragma unroll
    for (int ec = 0; ec < 8; ++ec) { O1[ec] = zero4; O2[ec] = zero4; }
    float l1[4] = {0.f, 0.f, 0.f, 0.f}, l2[4] = {0.f, 0.f, 0.f, 0.f};

    auto tile = [&](int cur, int kt, bool diag) {
        const char* kb = (const char*)KV[cur];
        bf16x8 kf[2][4];
        #pragma unroll
        for (int c = 0; c < 2; ++c)
            #pragma unroll
            for (int j = 0; j < 4; ++j)
                kf[c][j] = *(const bf16x8*)(kb + kfo[c][j]);

        f32x4 S1[2], S2[2];
        #pragma unroll
        for (int c = 0; c < 2; ++c) { S1[c] = zero4; S2[c] = zero4; }
        #pragma unroll
        for (int c = 0; c < 2; ++c) {
            S1[c] = __builtin_amdgcn_mfma_f32_16x16x32_bf16(q1a, kf[c][0], S1[c], 0, 0, 0);
            S1[c] = __builtin_amdgcn_mfma_f32_16x16x32_bf16(q1b, kf[c][1], S1[c], 0, 0, 0);
            S2[c] = __builtin_amdgcn_mfma_f32_16x16x32_bf16(q2a, kf[c][2], S2[c], 0, 0, 0);
            S2[c] = __builtin_amdgcn_mfma_f32_16x16x32_bf16(q2b, kf[c][3], S2[c], 0, 0, 0);
        }
        if (diag) {
            #pragma unroll
            for (int c = 0; c < 2; ++c) {
                // mask if global key > global row
                int kq = kt * 32 + c * 16 + cl - qrow - qd * 4;
                #pragma unroll
                for (int r = 0; r < 4; ++r) {
                    if (kq > r) { S1[c][r] = -1e30f; S2[c][r] = -1e30f; }
                }
            }
        }
        // V fragments (issued before the P phase; ds in-order per wave)
        bf16x8 vf[8];
        #pragma unroll
        for (int ec = 0; ec < 8; ++ec)
            vf[ec] = *(const bf16x8*)(kb + vfo[ec]);

        // p = exp(s/8) = exp2(s * 0.125*log2e): one v_mul + one v_exp each
        #pragma unroll
        for (int r = 0; r < 4; ++r) {
            float p10 = exp2f(S1[0][r] * EXP2SCALE);
            float p11 = exp2f(S1[1][r] * EXP2SCALE);
            float p20 = exp2f(S2[0][r] * EXP2SCALE);
            float p21 = exp2f(S2[1][r] * EXP2SCALE);
            l1[r] += p10 + p11;
            l2[r] += p20 + p21;
            int row = (qd << 2) + r;
            Pw[row * PW_S + cl]      = pack2bf(p10, p20);   // key = cl
            Pw[row * PW_S + cl + 16] = pack2bf(p11, p21);   // key = cl+16
        }
        // read back as A-operand fragments: row = cl, keys qd*8..qd*8+7
        const unsigned int* rp = Pw + cl * PW_S + qd * 8;
        uint4 L0 = *(const uint4*)(rp);
        uint4 L1 = *(const uint4*)(rp + 4);
        uint4 u1, u2;
        u1.x = __builtin_amdgcn_perm(L0.y, L0.x, 0x05040100u);
        u1.y = __builtin_amdgcn_perm(L0.w, L0.z, 0x05040100u);
        u1.z = __builtin_amdgcn_perm(L1.y, L1.x, 0x05040100u);
        u1.w = __builtin_amdgcn_perm(L1.w, L1.z, 0x05040100u);
        u2.x = __builtin_amdgcn_perm(L0.y, L0.x, 0x07060302u);
        u2.y = __builtin_amdgcn_perm(L0.w, L0.z, 0x07060302u);
        u2.z = __builtin_amdgcn_perm(L1.y, L1.x, 0x07060302u);
        u2.w = __builtin_amdgcn_perm(L1.w, L1.z, 0x07060302u);
        bf16x8 pa1 = __builtin_bit_cast(bf16x8, u1);
        bf16x8 pa2 = __builtin_bit_cast(bf16x8, u2);
        #pragma unroll
        for (int ec = 0; ec < 8; ++ec) {
            O1[ec] = __builtin_amdgcn_mfma_f32_16x16x32_bf16(pa1, vf[ec], O1[ec], 0, 0, 0);
            O2[ec] = __builtin_amdgcn_mfma_f32_16x16x32_bf16(pa2, vf[ec], O2[ec], 0, 0, 0);
        }
    };

    int NT = 2 * g + 2;
    int ktmax = 2 * g + (wv >> 1);   // waves 0,1 skip the fully-masked last tile

    stage(0, 0);
    __syncthreads();                 // implicit vmcnt(0) drain
    for (int kt = 0; kt < NT; ++kt) {
        int cur = kt & 1;
        if (kt + 1 < NT) stage(kt + 1, cur ^ 1);
        if (kt <= ktmax) {
            bool diag = (kt * 32 + 31 > qrow);
            tile(cur, kt, diag);
        }
        __syncthreads();             // drains stage loads + LDS reads, then barrier
    }

    // reduce l across the 16 column-lanes
    float w1[4], w2[4];
    #pragma unroll
    for (int r = 0; r < 4; ++r) {
        float a = l1[r], c = l2[r];
        a += __shfl_xor(a, 1); a += __shfl_xor(a, 2);
        a += __shfl_xor(a, 4); a += __shfl_xor(a, 8);
        c += __shfl_xor(c, 1); c += __shfl_xor(c, 2);
        c += __shfl_xor(c, 4); c += __shfl_xor(c, 8);
        w1[r] = 1.0f / a;
        w2[r] = lamv / c;
    }
    #pragma unroll
    for (int ec = 0; ec < 8; ++ec) {
        #pragma unroll
        for (int r = 0; r < 4; ++r) {
            size_t row = (size_t)(b * Tc + qrow + qd * 4 + r);
            attn[row * HVD + h * VDc + ec * 16 + cl] =
                f2bf(O1[ec][r] * w1[r] - O2[ec][r] * w2[r]);
        }
    }
}

// ---------------------------------------------------------------------------
// Fused row-stats + LayerNorm*0.2, in-place on bf16 attn. 128 thr/row.
// ---------------------------------------------------------------------------
__global__ __launch_bounds__(128) void ln_inplace(
    unsigned short* __restrict__ attn,
    const float* __restrict__ gnw, const float* __restrict__ gnb)
{
    int row = blockIdx.x, tid = threadIdx.x;
    unsigned short* p = attn + (size_t)row * HVD;
    float v[12];
    float s = 0.f, sq = 0.f;
    #pragma unroll
    for (int j = 0; j < 3; ++j) {
        int g = tid + j * 128;
        ushort4 u = *(const ushort4*)(p + g * 4);
        float x0 = bf2f(u.x), x1 = bf2f(u.y), x2 = bf2f(u.z), x3 = bf2f(u.w);
        v[j * 4 + 0] = x0; v[j * 4 + 1] = x1; v[j * 4 + 2] = x2; v[j * 4 + 3] = x3;
        s += x0 + x1 + x2 + x3;
        sq = fmaf(x0, x0, sq); sq = fmaf(x1, x1, sq);
        sq = fmaf(x2, x2, sq); sq = fmaf(x3, x3, sq);
    }
    #pragma unroll
    for (int off = 32; off; off >>= 1) { s += __shfl_xor(s, off); sq += __shfl_xor(sq, off); }
    __shared__ float ss[2], sqs[2];
    if ((tid & 63) == 0) { ss[tid >> 6] = s; sqs[tid >> 6] = sq; }
    __syncthreads();
    float S = ss[0] + ss[1], Q = sqs[0] + sqs[1];
    float mu = S * (1.0f / HVD);
    float rstd = rsqrtf(Q * (1.0f / HVD) - mu * mu + 1e-5f);
    #pragma unroll
    for (int j = 0; j < 3; ++j) {
        int g = tid + j * 128;
        float4 gw = *(const float4*)(gnw + g * 4);
        float4 gb = *(const float4*)(gnb + g * 4);
        ushort4 o;
        o.x = f2bf(((v[j * 4 + 0] - mu) * rstd * gw.x + gb.x) * 0.2f);
        o.y = f2bf(((v[j * 4 + 1] - mu) * rstd * gw.y + gb.y) * 0.2f);
        o.z = f2bf(((v[j * 4 + 2] - mu) * rstd * gw.z + gb.z) * 0.2f);
        o.w = f2bf(((v[j * 4 + 3] - mu) * rstd * gw.w + gb.w) * 0.2f);
        *(ushort4*)(p + g * 4) = o;
    }
}

// ---------------------------------------------------------------------------
// launch
// ---------------------------------------------------------------------------
extern "C" void kernel_launch(void* const* d_in, const int* in_sizes, int n_in,
                              void* d_out, int out_size, void* d_ws, size_t ws_size,
                              hipStream_t stream)
{
    const float* x   = (const float*)d_in[0];
    const float* Wq1 = (const float*)d_in[1];
    const float* Wk1 = (const float*)d_in[2];
    const float* Wq2 = (const float*)d_in[3];
    const float* Wk2 = (const float*)d_in[4];
    const float* Wv  = (const float*)d_in[5];
    const float* lq1 = (const float*)d_in[6];
    const float* lk1 = (const float*)d_in[7];
    const float* lq2 = (const float*)d_in[8];
    const float* lk2 = (const float*)d_in[9];
    const float* gnw = (const float*)d_in[10];
    const float* gnb = (const float*)d_in[11];
    const float* Wp  = (const float*)d_in[12];
    const float* bp  = (const float*)d_in[13];
    const int*   lidx = (const int*)d_in[14];
    float* out = (float*)d_out;

    // workspace layout (bytes):
    // WcatT bf16 [4608][768]:  7,077,888 @ 0
    // Xb    bf16 [4096][768]:  6,291,456 @ 7,077,888
    // Y     bf16 [4096][3072]: 25,165,824 @ 13,369,344
    // Vt    bf16 [48][128][1024]: 12,582,912 @ 38,535,168
    // attn  bf16 [4096][1536]: 12,582,912 @ 51,118,080
    // Wpb   bf16 [768][1536]:   2,359,296 @ 63,700,992
    // lam   f32 [12]                       @ 66,060,288
    char* w = (char*)d_ws;
    unsigned short* WcatT = (unsigned short*)(w);
    unsigned short* Xb    = (unsigned short*)(w + 7077888);
    unsigned short* Y     = (unsigned short*)(w + 13369344);
    unsigned short* VtW   = (unsigned short*)(w + 38535168);
    unsigned short* attn  = (unsigned short*)(w + 51118080);
    unsigned short* Wpb   = (unsigned short*)(w + 63700992);
    float* lam            = (float*)(w + 66060288);

    cast_bf16<<<dim3(NROWS * Cc / 1024), 256, 0, stream>>>(x, Xb);
    cast_bf16<<<dim3(Cc * HVD / 1024), 256, 0, stream>>>(Wp, Wpb);
    trans_w<<<dim3(72 * 12), 256, 0, stream>>>(Wq1, Wk1, Wq2, Wk2, Wv, WcatT);
    lambda_kernel<<<dim3(Hc), 64, 0, stream>>>(lq1, lk1, lq2, lk2, lidx, lam);
    // QKV: [4096,768] x [768,4608]; Q/K -> Y (LD 3072), V -> Vt transposed
    gemm_mfma<4, 768, YLD, false, true><<<dim3(NQKV / 128, NROWS / 128), 256, 0, stream>>>(
        Xb, WcatT, Y, nullptr, nullptr, VtW);
    // bh fastest (XCD pin); y -> g = 15-y, longest-first; 768 blocks x 4 waves,
    // 64 Q-rows per block, K/V staged once per block in dbuf LDS
    diff_attn_mfma<<<dim3(Bc * Hc, 16), 256, 0, stream>>>(Y, VtW, lam, attn);
    ln_inplace<<<dim3(NROWS), 128, 0, stream>>>(attn, gnw, gnb);
    // OUT: [4096,1536] x [1536,768] -> out fp32 (+bias)
    gemm_mfma<2, HVD, Cc, true, false><<<dim3(Cc / 64, NROWS / 128), 256, 0, stream>>>(
        attn, Wpb, nullptr, out, bp, nullptr);
}

// Round 5
// 280.075 us; speedup vs baseline: 1.7230x; 1.0147x over previous
//
#include <hip/hip_runtime.h>
#include <hip/hip_bf16.h>

// Problem constants
#define Bc   4
#define Tc   1024
#define Cc   768
#define Hc   12
#define HSc  64
#define VDc  128
#define NQKV 4608   // gemm N for qkv (4*768 Q/K + 1536 V)
#define YLD  3072   // Y row stride: Q/K only (V goes to Vt)
#define NROWS 4096  // B*T
#define HVD  1536   // H*VD

// Y (qk) column offsets
#define Q1OFF 0
#define K1OFF 768
#define Q2OFF 1536
#define K2OFF 2304

typedef __bf16 bf16x8 __attribute__((ext_vector_type(8)));
typedef float f32x4 __attribute__((ext_vector_type(4)));
typedef unsigned int u32x4 __attribute__((ext_vector_type(4)));

#define PW_S 36   // P row stride in dwords: 144B rows, 16B aligned, <=2-way banks
// exp(s*0.125) == exp2(s * 0.125*log2(e))
#define EXP2SCALE 0.18033688011112042f

static __device__ __forceinline__ float bf2f(unsigned short s) {
    return __uint_as_float(((unsigned int)s) << 16);
}
static __device__ __forceinline__ unsigned short f2bf(float f) {
    unsigned int u = __float_as_uint(f);
    unsigned int r = (u + 0x7FFFu + ((u >> 16) & 1u)) >> 16;  // round-nearest-even
    return (unsigned short)r;
}
static __device__ __forceinline__ unsigned int pack2bf(float lo, float hi) {
    // bf16(lo) | bf16(hi)<<16, half-up rounding (values >= 0)
    unsigned int a = (__float_as_uint(lo) + 0x8000u) >> 16;
    unsigned int b = (__float_as_uint(hi) + 0x8000u) & 0xFFFF0000u;
    return a | b;
}
// raw v_exp_f32: 2^x without libm denorm guards (inputs bounded here)
static __device__ __forceinline__ float fast_exp2(float x) {
    float r;
    asm("v_exp_f32 %0, %1" : "=v"(r) : "v"(x));
    return r;
}

// async global->LDS 16B per lane; lds base must be wave-uniform
static __device__ __forceinline__ void load16_lds(const void* g, void* l) {
    __builtin_amdgcn_global_load_lds(
        (const __attribute__((address_space(1))) void*)g,
        (__attribute__((address_space(3))) void*)l, 16, 0, 0);
}

// ---------------------------------------------------------------------------
// cast fp32 -> bf16, 4 elts/thread
// ---------------------------------------------------------------------------
__global__ __launch_bounds__(256) void cast_bf16(
    const float* __restrict__ src, unsigned short* __restrict__ dst)
{
    int i = blockIdx.x * 256 + threadIdx.x;
    float4 v = *(const float4*)(src + (size_t)i * 4);
    ushort4 u;
    u.x = f2bf(v.x); u.y = f2bf(v.y); u.z = f2bf(v.z); u.w = f2bf(v.w);
    *(ushort4*)(dst + (size_t)i * 4) = u;
}

// ---------------------------------------------------------------------------
// Transpose-repack the 5 projection weights into WcatT[n][k] bf16, k-contig.
// ---------------------------------------------------------------------------
__global__ __launch_bounds__(256) void trans_w(
    const float* __restrict__ Wq1, const float* __restrict__ Wk1,
    const float* __restrict__ Wq2, const float* __restrict__ Wk2,
    const float* __restrict__ Wv, unsigned short* __restrict__ WcatT)
{
    __shared__ float tile[64][65];
    int tid = threadIdx.x;
    int t = blockIdx.x;
    int kt = t % 12, nt = t / 12;
    int k0 = kt * 64, n0 = nt * 64;
    const float* src;
    int stride;
    if (n0 < 3072) {
        int which = n0 / 768, m = n0 - which * 768, h = m >> 6;
        const float* W = (which == 0) ? Wq1 : (which == 1) ? Wk1 : (which == 2) ? Wq2 : Wk2;
        src = W + ((size_t)h * 768 + k0) * 64;
        stride = 64;
    } else {
        int rel = n0 - 3072, h = rel >> 7, e0 = rel & 127;
        src = Wv + ((size_t)h * 768 + k0) * 128 + e0;
        stride = 128;
    }
    for (int i = tid; i < 4096; i += 256) {
        int kl = i >> 6, dl = i & 63;
        tile[dl][kl] = src[(size_t)kl * stride + dl];
    }
    __syncthreads();
    for (int i = tid; i < 4096; i += 256) {
        int nl = i >> 6, kl = i & 63;
        WcatT[(size_t)(n0 + nl) * 768 + k0 + kl] = f2bf(tile[nl][kl]);
    }
}

// ---------------------------------------------------------------------------
// lambda per head
// ---------------------------------------------------------------------------
__global__ __launch_bounds__(64) void lambda_kernel(
    const float* __restrict__ lq1, const float* __restrict__ lk1,
    const float* __restrict__ lq2, const float* __restrict__ lk2,
    const int* __restrict__ layer_idx, float* __restrict__ lam)
{
    int h = blockIdx.x, l = threadIdx.x;
    float li = (float)layer_idx[0];
    float dyn = 0.8f - 0.6f * expf(-0.3f * (li - 1.0f));
    int i = h * HSc + l;
    float v = expf(lq1[i] * lk1[i]) - expf(lq2[i] * lk2[i]) + dyn;
    #pragma unroll
    for (int off = 32; off; off >>= 1) v += __shfl_xor(v, off);
    if (l == 0) lam[h] = v * (1.0f / 64.0f);
}

// ---------------------------------------------------------------------------
// MFMA GEMM (m97 structure): C[M][LDC] = A[M][KD] * Bt[N][KD]^T, bf16 inputs.
// SPLITV: cols >= 3072 (V projection) -> written transposed to VtOut[bh][e][t].
// ---------------------------------------------------------------------------
template<int TN, int KD, int LDC, bool OUT_BIAS, bool SPLITV>
__global__ __launch_bounds__(256) void gemm_mfma(
    const unsigned short* __restrict__ A, const unsigned short* __restrict__ Bt,
    unsigned short* __restrict__ Cb, float* __restrict__ Cf,
    const float* __restrict__ bias, unsigned short* __restrict__ VtOut)
{
    constexpr int BN = TN * 32;
    constexpr int JB = TN / 2;
    __shared__ unsigned short As[128 * 32];
    __shared__ unsigned short Bs[BN * 32];
    int tid = threadIdx.x, lane = tid & 63, w = tid >> 6;
    int wm = w >> 1, wn = w & 1;
    int m0 = blockIdx.y * 128, n0 = blockIdx.x * BN;

    int lr = lane >> 2, lq = lane & 3;
    const unsigned short* gA[2];
    const unsigned short* gB[JB];
    #pragma unroll
    for (int j = 0; j < 2; ++j) {
        int row = w * 32 + j * 16 + lr;
        int qg = lq ^ ((row >> 1) & 3);
        gA[j] = A + (size_t)(m0 + row) * KD + qg * 8;
    }
    #pragma unroll
    for (int j = 0; j < JB; ++j) {
        int row = w * (JB * 16) + j * 16 + lr;
        int qg = lq ^ ((row >> 1) & 3);
        gB[j] = Bt + (size_t)(n0 + row) * KD + qg * 8;
    }

    int rr = lane & 15, qd = lane >> 4;
    const unsigned short* aAddr[4];
    const unsigned short* bAddr[TN];
    #pragma unroll
    for (int i = 0; i < 4; ++i) {
        int row = wm * 64 + i * 16 + rr;
        int qs = qd ^ ((row >> 1) & 3);
        aAddr[i] = As + row * 32 + qs * 8;
    }
    #pragma unroll
    for (int t = 0; t < TN; ++t) {
        int row = wn * (TN * 16) + t * 16 + rr;
        int qs = qd ^ ((row >> 1) & 3);
        bAddr[t] = Bs + row * 32 + qs * 8;
    }

    f32x4 acc[4][TN];
    #pragma unroll
    for (int i = 0; i < 4; ++i)
        #pragma unroll
        for (int t = 0; t < TN; ++t) acc[i][t] = {0.f, 0.f, 0.f, 0.f};

    for (int k = 0; k < KD / 32; ++k) {
        __syncthreads();
        load16_lds(gA[0], As + (w * 2 + 0) * 512);
        load16_lds(gA[1], As + (w * 2 + 1) * 512);
        #pragma unroll
        for (int j = 0; j < JB; ++j)
            load16_lds(gB[j], Bs + (w * JB + j) * 512);
        gA[0] += 32; gA[1] += 32;
        #pragma unroll
        for (int j = 0; j < JB; ++j) gB[j] += 32;
        __syncthreads();

        bf16x8 af[4], bfr[TN];
        #pragma unroll
        for (int i = 0; i < 4; ++i) af[i] = *(const bf16x8*)aAddr[i];
        #pragma unroll
        for (int t = 0; t < TN; ++t) bfr[t] = *(const bf16x8*)bAddr[t];
        #pragma unroll
        for (int i = 0; i < 4; ++i)
            #pragma unroll
            for (int t = 0; t < TN; ++t)
                acc[i][t] = __builtin_amdgcn_mfma_f32_16x16x32_bf16(af[i], bfr[t], acc[i][t], 0, 0, 0);
    }

    #pragma unroll
    for (int t = 0; t < TN; ++t) {
        int col = n0 + wn * (TN * 16) + t * 16 + rr;
        if (SPLITV && col >= 3072) {
            int rel = col - 3072, hh = rel >> 7, e = rel & 127;
            #pragma unroll
            for (int i = 0; i < 4; ++i) {
                int row0 = m0 + wm * 64 + i * 16 + qd * 4;
                int b = row0 >> 10, tt = row0 & 1023;
                ushort4 pk;
                pk.x = f2bf(acc[i][t][0]); pk.y = f2bf(acc[i][t][1]);
                pk.z = f2bf(acc[i][t][2]); pk.w = f2bf(acc[i][t][3]);
                *(ushort4*)&VtOut[(size_t)((b * Hc + hh) * 128 + e) * 1024 + tt] = pk;
            }
        } else {
            float bv = OUT_BIAS ? bias[col] : 0.f;
            #pragma unroll
            for (int i = 0; i < 4; ++i) {
                #pragma unroll
                for (int r = 0; r < 4; ++r) {
                    int row = m0 + wm * 64 + i * 16 + qd * 4 + r;
                    if (OUT_BIAS)
                        Cf[(size_t)row * LDC + col] = acc[i][t][r] + bv;
                    else
                        Cb[(size_t)row * LDC + col] = f2bf(acc[i][t][r]);
                }
            }
        }
    }
}

// ---------------------------------------------------------------------------
// MFMA differential flash attention — R13: counted-vmcnt pipeline (T3/T4).
// R12 measured: 4470 cyc/block-tile with only 35% VALU + 8% MFMA busy — the
// per-tile __syncthreads (full vmcnt(0)+lgkmcnt(0) drain) exposed the whole
// stage latency + convoyed all 4 waves every tile. R13: raw s_barrier with
// COUNTED vmcnt (never 0 in the main loop), 3-slot LDS ring, 2-tile-deep
// prefetch:
//   iter kt: s_waitcnt vmcnt(4)   (own stage(kt) done; stage(kt+1) in
//            flight) ; s_barrier  (all waves' stage(kt) done)
//            ds_read K/V[slot kt%3] ; issue stage(kt+2 -> slot (kt+2)%3)
//            (= slot of tile kt-1, all waves past it per barrier) ; compute.
// Q fragments detached from their loads via "+v" asm + pre-loop vmcnt(0) so
// in-loop vmem ops are EXACTLY the 4 stage loads/wave/tile. P round-trip is
// wave-private (DS ops in-order per wave -> no barrier needed).
// V swizzle (e>>1)&3 (was e&3): V ds_read 4-way -> 2-way banks.
// exp2f -> raw v_exp_f32.
// LDS: 3x16KB ring + 9KB P = 58368 B -> 2 blocks/CU.
// grid (48,16): x = bh (XCD-pinned), y -> g = 15-y longest-first;
// block g: Q-rows 64g..64g+63 (4 waves x 16), K-tiles 0..2g+1.
// ---------------------------------------------------------------------------
__global__ __launch_bounds__(256) void diff_attn_mfma(
    const unsigned short* __restrict__ Y, const unsigned short* __restrict__ Vt,
    const float* __restrict__ lam_buf, unsigned short* __restrict__ attn)
{
    // ring slot byte layout: K1 [0,4096), K2 [4096,8192), V [8192,16384)
    __shared__ __align__(16) unsigned short KVring[3 * 8192];
    __shared__ __align__(16) unsigned int PL32[4][16 * PW_S]; // per-wave packed P

    int bh = blockIdx.x;                          // fastest dim -> XCD-pinned
    int b = bh / Hc, h = bh - b * Hc;
    int g = 15 - (int)blockIdx.y;                 // longest first
    int tid = threadIdx.x, lane = tid & 63, wv = tid >> 6;
    int cl = lane & 15, qd = lane >> 4;
    float lamv = lam_buf[h];
    size_t rowbase = (size_t)(b * Tc) * YLD;
    const int hq = h * HSc;
    unsigned int* Pw = PL32[wv];
    const unsigned short* VtB = Vt + ((size_t)bh << 17);   // bh*128*1024
    const f32x4 zero4 = {0.f, 0.f, 0.f, 0.f};

    // ---- staging lane->global mappings (kt-independent parts) ----
    // K (waves 0,1): seg r8 holds rows r8*8..r8*8+7, 8 chunks of 16B per row.
    // LDS slot: row = r8*8 + lane>>3, lds chunk = lane&7;
    // stored global chunk = (lane&7) ^ (row&7)  [inverse of read swizzle]
    int ksrow = lane >> 3;                 // row within seg
    int ksch  = (lane & 7) ^ ksrow;        // global chunk
    int offk[4];
    {
        int mat = wv & 1;                  // wave0 -> K1, wave1 -> K2
        int moff = mat ? K2OFF : K1OFF;
        #pragma unroll
        for (int r8 = 0; r8 < 4; ++r8)
            offk[r8] = (r8 * 8 + ksrow) * YLD + moff + hq + ksch * 8;
    }
    // V (waves 2,3): seg sv holds e-rows sv*16..sv*16+15, 4 chunks of 16B.
    // LDS slot: e = sv*16 + lane>>2, lds chunk = lane&3;
    // stored global chunk = (lane&3) ^ ((e>>1)&3)   [2-way banks on read]
    int vsel = lane >> 2;                  // e within seg
    int vsch = (lane & 3) ^ ((vsel >> 1) & 3);
    int offv[4];
    {
        int sv0 = (wv & 1) * 4;            // wave2 -> sv 0..3, wave3 -> sv 4..7
        #pragma unroll
        for (int i = 0; i < 4; ++i)
            offv[i] = ((sv0 + i) * 16 + vsel) * 1024 + vsch * 8;
    }

    auto stage = [&](int kt, int slot) {
        char* base = (char*)KVring + slot * 16384 + wv * 4096;
        if (wv < 2) {
            const unsigned short* g0 = Y + rowbase + (size_t)(kt * 32) * YLD;
            #pragma unroll
            for (int r8 = 0; r8 < 4; ++r8)
                load16_lds(g0 + offk[r8], base + r8 * 1024);
        } else {
            const unsigned short* g0 = VtB + kt * 32;
            #pragma unroll
            for (int i = 0; i < 4; ++i)
                load16_lds(g0 + offv[i], base + i * 1024);
        }
    };

    // ---- fragment LDS byte offsets within a slot (swizzled reads) ----
    int kfo[2][4], vfo[8];
    #pragma unroll
    for (int c = 0; c < 2; ++c) {
        int row = c * 16 + cl;
        #pragma unroll
        for (int j = 0; j < 4; ++j)
            kfo[c][j] = (j >> 1) * 4096 + row * 128 +
                        ((((j & 1) * 4 + qd) ^ (row & 7)) << 4);
    }
    #pragma unroll
    for (int ec = 0; ec < 8; ++ec) {
        int e = ec * 16 + cl;
        vfo[ec] = 8192 + e * 64 + ((qd ^ ((e >> 1) & 3)) << 4);
    }

    int qrow = g * 64 + wv * 16;

    // Q loads as u32x4, detached from vmcnt tracking via "+v" pass-through
    size_t qoff = rowbase + (size_t)(qrow + cl) * YLD;
    u32x4 uq1a = *(const u32x4*)(Y + qoff + Q1OFF + hq + qd * 8);
    u32x4 uq1b = *(const u32x4*)(Y + qoff + Q1OFF + hq + 32 + qd * 8);
    u32x4 uq2a = *(const u32x4*)(Y + qoff + Q2OFF + hq + qd * 8);
    u32x4 uq2b = *(const u32x4*)(Y + qoff + Q2OFF + hq + 32 + qd * 8);
    asm volatile("" : "+v"(uq1a), "+v"(uq1b), "+v"(uq2a), "+v"(uq2b));
    asm volatile("" : "+v"(lamv));
    asm volatile("s_waitcnt vmcnt(0)" ::: "memory");
    bf16x8 q1a = __builtin_bit_cast(bf16x8, uq1a);
    bf16x8 q1b = __builtin_bit_cast(bf16x8, uq1b);
    bf16x8 q2a = __builtin_bit_cast(bf16x8, uq2a);
    bf16x8 q2b = __builtin_bit_cast(bf16x8, uq2b);

    f32x4 O1[8], O2[8];
    #pragma unroll
    for (int ec = 0; ec < 8; ++ec) { O1[ec] = zero4; O2[ec] = zero4; }
    float l1[4] = {0.f, 0.f, 0.f, 0.f}, l2[4] = {0.f, 0.f, 0.f, 0.f};

    int NT = 2 * g + 2;
    int ktmax = 2 * g + (wv >> 1);   // waves 0,1 skip the fully-masked last tile

    stage(0, 0);
    stage(1, 1);

    int cur = 0;
    for (int kt = 0; kt < NT; ++kt) {
        // counted wait: stage(kt) complete (4 newer = stage(kt+1) may fly);
        // last iteration has nothing newer -> 0. Then barrier: all waves'
        // stage(kt) writes visible.
        if (kt < NT - 1) {
            asm volatile("s_waitcnt vmcnt(4)\n\ts_barrier" ::: "memory");
        } else {
            asm volatile("s_waitcnt vmcnt(0)\n\ts_barrier" ::: "memory");
        }
        const char* kb = (const char*)KVring + cur * 16384;

        // issue ds reads first (compiler-counted lgkm waits before MFMA use)
        bf16x8 kf[2][4];
        #pragma unroll
        for (int c = 0; c < 2; ++c)
            #pragma unroll
            for (int j = 0; j < 4; ++j)
                kf[c][j] = *(const bf16x8*)(kb + kfo[c][j]);
        bf16x8 vf[8];
        #pragma unroll
        for (int ec = 0; ec < 8; ++ec)
            vf[ec] = *(const bf16x8*)(kb + vfo[ec]);

        // prefetch 2 ahead into the slot all waves finished reading at kt-1
        if (kt + 2 < NT) {
            int st = cur + 2; if (st >= 3) st -= 3;
            stage(kt + 2, st);
        }

        if (kt <= ktmax) {
            f32x4 S1[2], S2[2];
            #pragma unroll
            for (int c = 0; c < 2; ++c) { S1[c] = zero4; S2[c] = zero4; }
            #pragma unroll
            for (int c = 0; c < 2; ++c) {
                S1[c] = __builtin_amdgcn_mfma_f32_16x16x32_bf16(q1a, kf[c][0], S1[c], 0, 0, 0);
                S1[c] = __builtin_amdgcn_mfma_f32_16x16x32_bf16(q1b, kf[c][1], S1[c], 0, 0, 0);
                S2[c] = __builtin_amdgcn_mfma_f32_16x16x32_bf16(q2a, kf[c][2], S2[c], 0, 0, 0);
                S2[c] = __builtin_amdgcn_mfma_f32_16x16x32_bf16(q2b, kf[c][3], S2[c], 0, 0, 0);
            }
            if (kt * 32 + 31 > qrow) {
                #pragma unroll
                for (int c = 0; c < 2; ++c) {
                    int kq = kt * 32 + c * 16 + cl - qrow - qd * 4;
                    #pragma unroll
                    for (int r = 0; r < 4; ++r) {
                        if (kq > r) { S1[c][r] = -1e30f; S2[c][r] = -1e30f; }
                    }
                }
            }
            // p = exp2(s * 0.125*log2e)
            #pragma unroll
            for (int r = 0; r < 4; ++r) {
                float p10 = fast_exp2(S1[0][r] * EXP2SCALE);
                float p11 = fast_exp2(S1[1][r] * EXP2SCALE);
                float p20 = fast_exp2(S2[0][r] * EXP2SCALE);
                float p21 = fast_exp2(S2[1][r] * EXP2SCALE);
                l1[r] += p10 + p11;
                l2[r] += p20 + p21;
                int row = (qd << 2) + r;
                Pw[row * PW_S + cl]      = pack2bf(p10, p20);   // key = cl
                Pw[row * PW_S + cl + 16] = pack2bf(p11, p21);   // key = cl+16
            }
            // read back as A-operand fragments: row = cl, keys qd*8..qd*8+7
            // (wave-private; DS ops are in-order per wave -> no barrier)
            const unsigned int* rp = Pw + cl * PW_S + qd * 8;
            uint4 L0 = *(const uint4*)(rp);
            uint4 L1 = *(const uint4*)(rp + 4);
            uint4 u1, u2;
            u1.x = __builtin_amdgcn_perm(L0.y, L0.x, 0x05040100u);
            u1.y = __builtin_amdgcn_perm(L0.w, L0.z, 0x05040100u);
            u1.z = __builtin_amdgcn_perm(L1.y, L1.x, 0x05040100u);
            u1.w = __builtin_amdgcn_perm(L1.w, L1.z, 0x05040100u);
            u2.x = __builtin_amdgcn_perm(L0.y, L0.x, 0x07060302u);
            u2.y = __builtin_amdgcn_perm(L0.w, L0.z, 0x07060302u);
            u2.z = __builtin_amdgcn_perm(L1.y, L1.x, 0x07060302u);
            u2.w = __builtin_amdgcn_perm(L1.w, L1.z, 0x07060302u);
            bf16x8 pa1 = __builtin_bit_cast(bf16x8, u1);
            bf16x8 pa2 = __builtin_bit_cast(bf16x8, u2);
            #pragma unroll
            for (int ec = 0; ec < 8; ++ec) {
                O1[ec] = __builtin_amdgcn_mfma_f32_16x16x32_bf16(pa1, vf[ec], O1[ec], 0, 0, 0);
                O2[ec] = __builtin_amdgcn_mfma_f32_16x16x32_bf16(pa2, vf[ec], O2[ec], 0, 0, 0);
            }
        }
        cur = (cur == 2) ? 0 : cur + 1;
    }

    // reduce l across the 16 column-lanes
    float w1[4], w2[4];
    #pragma unroll
    for (int r = 0; r < 4; ++r) {
        float a = l1[r], c = l2[r];
        a += __shfl_xor(a, 1); a += __shfl_xor(a, 2);
        a += __shfl_xor(a, 4); a += __shfl_xor(a, 8);
        c += __shfl_xor(c, 1); c += __shfl_xor(c, 2);
        c += __shfl_xor(c, 4); c += __shfl_xor(c, 8);
        w1[r] = 1.0f / a;
        w2[r] = lamv / c;
    }
    #pragma unroll
    for (int ec = 0; ec < 8; ++ec) {
        #pragma unroll
        for (int r = 0; r < 4; ++r) {
            size_t row = (size_t)(b * Tc + qrow + qd * 4 + r);
            attn[row * HVD + h * VDc + ec * 16 + cl] =
                f2bf(O1[ec][r] * w1[r] - O2[ec][r] * w2[r]);
        }
    }
}

// ---------------------------------------------------------------------------
// Fused row-stats + LayerNorm*0.2, in-place on bf16 attn. 128 thr/row.
// ---------------------------------------------------------------------------
__global__ __launch_bounds__(128) void ln_inplace(
    unsigned short* __restrict__ attn,
    const float* __restrict__ gnw, const float* __restrict__ gnb)
{
    int row = blockIdx.x, tid = threadIdx.x;
    unsigned short* p = attn + (size_t)row * HVD;
    float v[12];
    float s = 0.f, sq = 0.f;
    #pragma unroll
    for (int j = 0; j < 3; ++j) {
        int g = tid + j * 128;
        ushort4 u = *(const ushort4*)(p + g * 4);
        float x0 = bf2f(u.x), x1 = bf2f(u.y), x2 = bf2f(u.z), x3 = bf2f(u.w);
        v[j * 4 + 0] = x0; v[j * 4 + 1] = x1; v[j * 4 + 2] = x2; v[j * 4 + 3] = x3;
        s += x0 + x1 + x2 + x3;
        sq = fmaf(x0, x0, sq); sq = fmaf(x1, x1, sq);
        sq = fmaf(x2, x2, sq); sq = fmaf(x3, x3, sq);
    }
    #pragma unroll
    for (int off = 32; off; off >>= 1) { s += __shfl_xor(s, off); sq += __shfl_xor(sq, off); }
    __shared__ float ss[2], sqs[2];
    if ((tid & 63) == 0) { ss[tid >> 6] = s; sqs[tid >> 6] = sq; }
    __syncthreads();
    float S = ss[0] + ss[1], Q = sqs[0] + sqs[1];
    float mu = S * (1.0f / HVD);
    float rstd = rsqrtf(Q * (1.0f / HVD) - mu * mu + 1e-5f);
    #pragma unroll
    for (int j = 0; j < 3; ++j) {
        int g = tid + j * 128;
        float4 gw = *(const float4*)(gnw + g * 4);
        float4 gb = *(const float4*)(gnb + g * 4);
        ushort4 o;
        o.x = f2bf(((v[j * 4 + 0] - mu) * rstd * gw.x + gb.x) * 0.2f);
        o.y = f2bf(((v[j * 4 + 1] - mu) * rstd * gw.y + gb.y) * 0.2f);
        o.z = f2bf(((v[j * 4 + 2] - mu) * rstd * gw.z + gb.z) * 0.2f);
        o.w = f2bf(((v[j * 4 + 3] - mu) * rstd * gw.w + gb.w) * 0.2f);
        *(ushort4*)(p + g * 4) = o;
    }
}

// ---------------------------------------------------------------------------
// launch
// ---------------------------------------------------------------------------
extern "C" void kernel_launch(void* const* d_in, const int* in_sizes, int n_in,
                              void* d_out, int out_size, void* d_ws, size_t ws_size,
                              hipStream_t stream)
{
    const float* x   = (const float*)d_in[0];
    const float* Wq1 = (const float*)d_in[1];
    const float* Wk1 = (const float*)d_in[2];
    const float* Wq2 = (const float*)d_in[3];
    const float* Wk2 = (const float*)d_in[4];
    const float* Wv  = (const float*)d_in[5];
    const float* lq1 = (const float*)d_in[6];
    const float* lk1 = (const float*)d_in[7];
    const float* lq2 = (const float*)d_in[8];
    const float* lk2 = (const float*)d_in[9];
    const float* gnw = (const float*)d_in[10];
    const float* gnb = (const float*)d_in[11];
    const float* Wp  = (const float*)d_in[12];
    const float* bp  = (const float*)d_in[13];
    const int*   lidx = (const int*)d_in[14];
    float* out = (float*)d_out;

    // workspace layout (bytes):
    // WcatT bf16 [4608][768]:  7,077,888 @ 0
    // Xb    bf16 [4096][768]:  6,291,456 @ 7,077,888
    // Y     bf16 [4096][3072]: 25,165,824 @ 13,369,344
    // Vt    bf16 [48][128][1024]: 12,582,912 @ 38,535,168
    // attn  bf16 [4096][1536]: 12,582,912 @ 51,118,080
    // Wpb   bf16 [768][1536]:   2,359,296 @ 63,700,992
    // lam   f32 [12]                       @ 66,060,288
    char* w = (char*)d_ws;
    unsigned short* WcatT = (unsigned short*)(w);
    unsigned short* Xb    = (unsigned short*)(w + 7077888);
    unsigned short* Y     = (unsigned short*)(w + 13369344);
    unsigned short* VtW   = (unsigned short*)(w + 38535168);
    unsigned short* attn  = (unsigned short*)(w + 51118080);
    unsigned short* Wpb   = (unsigned short*)(w + 63700992);
    float* lam            = (float*)(w + 66060288);

    cast_bf16<<<dim3(NROWS * Cc / 1024), 256, 0, stream>>>(x, Xb);
    cast_bf16<<<dim3(Cc * HVD / 1024), 256, 0, stream>>>(Wp, Wpb);
    trans_w<<<dim3(72 * 12), 256, 0, stream>>>(Wq1, Wk1, Wq2, Wk2, Wv, WcatT);
    lambda_kernel<<<dim3(Hc), 64, 0, stream>>>(lq1, lk1, lq2, lk2, lidx, lam);
    // QKV: [4096,768] x [768,4608]; Q/K -> Y (LD 3072), V -> Vt transposed
    gemm_mfma<4, 768, YLD, false, true><<<dim3(NQKV / 128, NROWS / 128), 256, 0, stream>>>(
        Xb, WcatT, Y, nullptr, nullptr, VtW);
    // bh fastest (XCD pin); y -> g = 15-y, longest-first; 768 blocks x 4 waves,
    // 64 Q-rows per block, K/V staged in 3-slot LDS ring, counted-vmcnt barriers
    diff_attn_mfma<<<dim3(Bc * Hc, 16), 256, 0, stream>>>(Y, VtW, lam, attn);
    ln_inplace<<<dim3(NROWS), 128, 0, stream>>>(attn, gnw, gnb);
    // OUT: [4096,1536] x [1536,768] -> out fp32 (+bias)
    gemm_mfma<2, HVD, Cc, true, false><<<dim3(Cc / 64, NROWS / 128), 256, 0, stream>>>(
        attn, Wpb, nullptr, out, bp, nullptr);
}

// Round 6
// 274.409 us; speedup vs baseline: 1.7585x; 1.0206x over previous
//
#include <hip/hip_runtime.h>
#include <hip/hip_bf16.h>

// Problem constants
#define Bc   4
#define Tc   1024
#define Cc   768
#define Hc   12
#define HSc  64
#define VDc  128
#define NQKV 4608   // gemm N for qkv (4*768 Q/K + 1536 V)
#define YLD  3072   // Y row stride: Q/K only (V goes to Vt)
#define NROWS 4096  // B*T
#define HVD  1536   // H*VD

// Y (qk) column offsets
#define Q1OFF 0
#define K1OFF 768
#define Q2OFF 1536
#define K2OFF 2304

typedef __bf16 bf16x8 __attribute__((ext_vector_type(8)));
typedef float f32x4 __attribute__((ext_vector_type(4)));
typedef unsigned int u32x4 __attribute__((ext_vector_type(4)));

// exp(s*0.125) == exp2(s * 0.125*log2(e))
#define EXP2SCALE 0.18033688011112042f

static __device__ __forceinline__ float bf2f(unsigned short s) {
    return __uint_as_float(((unsigned int)s) << 16);
}
static __device__ __forceinline__ unsigned short f2bf(float f) {
    unsigned int u = __float_as_uint(f);
    unsigned int r = (u + 0x7FFFu + ((u >> 16) & 1u)) >> 16;  // round-nearest-even
    return (unsigned short)r;
}
static __device__ __forceinline__ unsigned int pack2bf(float lo, float hi) {
    // bf16(lo) | bf16(hi)<<16, half-up rounding (values >= 0)
    unsigned int a = (__float_as_uint(lo) + 0x8000u) >> 16;
    unsigned int b = (__float_as_uint(hi) + 0x8000u) & 0xFFFF0000u;
    return a | b;
}
// raw v_exp_f32: 2^x without libm denorm guards (inputs bounded here)
static __device__ __forceinline__ float fast_exp2(float x) {
    float r;
    asm("v_exp_f32 %0, %1" : "=v"(r) : "v"(x));
    return r;
}

// async global->LDS 16B per lane; lds base must be wave-uniform
static __device__ __forceinline__ void load16_lds(const void* g, void* l) {
    __builtin_amdgcn_global_load_lds(
        (const __attribute__((address_space(1))) void*)g,
        (__attribute__((address_space(3))) void*)l, 16, 0, 0);
}

// ---------------------------------------------------------------------------
// cast fp32 -> bf16, 4 elts/thread
// ---------------------------------------------------------------------------
__global__ __launch_bounds__(256) void cast_bf16(
    const float* __restrict__ src, unsigned short* __restrict__ dst)
{
    int i = blockIdx.x * 256 + threadIdx.x;
    float4 v = *(const float4*)(src + (size_t)i * 4);
    ushort4 u;
    u.x = f2bf(v.x); u.y = f2bf(v.y); u.z = f2bf(v.z); u.w = f2bf(v.w);
    *(ushort4*)(dst + (size_t)i * 4) = u;
}

// ---------------------------------------------------------------------------
// Transpose-repack the 5 projection weights into WcatT[n][k] bf16, k-contig.
// ---------------------------------------------------------------------------
__global__ __launch_bounds__(256) void trans_w(
    const float* __restrict__ Wq1, const float* __restrict__ Wk1,
    const float* __restrict__ Wq2, const float* __restrict__ Wk2,
    const float* __restrict__ Wv, unsigned short* __restrict__ WcatT)
{
    __shared__ float tile[64][65];
    int tid = threadIdx.x;
    int t = blockIdx.x;
    int kt = t % 12, nt = t / 12;
    int k0 = kt * 64, n0 = nt * 64;
    const float* src;
    int stride;
    if (n0 < 3072) {
        int which = n0 / 768, m = n0 - which * 768, h = m >> 6;
        const float* W = (which == 0) ? Wq1 : (which == 1) ? Wk1 : (which == 2) ? Wq2 : Wk2;
        src = W + ((size_t)h * 768 + k0) * 64;
        stride = 64;
    } else {
        int rel = n0 - 3072, h = rel >> 7, e0 = rel & 127;
        src = Wv + ((size_t)h * 768 + k0) * 128 + e0;
        stride = 128;
    }
    for (int i = tid; i < 4096; i += 256) {
        int kl = i >> 6, dl = i & 63;
        tile[dl][kl] = src[(size_t)kl * stride + dl];
    }
    __syncthreads();
    for (int i = tid; i < 4096; i += 256) {
        int nl = i >> 6, kl = i & 63;
        WcatT[(size_t)(n0 + nl) * 768 + k0 + kl] = f2bf(tile[nl][kl]);
    }
}

// ---------------------------------------------------------------------------
// lambda per head
// ---------------------------------------------------------------------------
__global__ __launch_bounds__(64) void lambda_kernel(
    const float* __restrict__ lq1, const float* __restrict__ lk1,
    const float* __restrict__ lq2, const float* __restrict__ lk2,
    const int* __restrict__ layer_idx, float* __restrict__ lam)
{
    int h = blockIdx.x, l = threadIdx.x;
    float li = (float)layer_idx[0];
    float dyn = 0.8f - 0.6f * expf(-0.3f * (li - 1.0f));
    int i = h * HSc + l;
    float v = expf(lq1[i] * lk1[i]) - expf(lq2[i] * lk2[i]) + dyn;
    #pragma unroll
    for (int off = 32; off; off >>= 1) v += __shfl_xor(v, off);
    if (l == 0) lam[h] = v * (1.0f / 64.0f);
}

// ---------------------------------------------------------------------------
// MFMA GEMM (m97 structure): C[M][LDC] = A[M][KD] * Bt[N][KD]^T, bf16 inputs.
// SPLITV: cols >= 3072 (V projection) -> written transposed to VtOut[bh][e][t].
// ---------------------------------------------------------------------------
template<int TN, int KD, int LDC, bool OUT_BIAS, bool SPLITV>
__global__ __launch_bounds__(256) void gemm_mfma(
    const unsigned short* __restrict__ A, const unsigned short* __restrict__ Bt,
    unsigned short* __restrict__ Cb, float* __restrict__ Cf,
    const float* __restrict__ bias, unsigned short* __restrict__ VtOut)
{
    constexpr int BN = TN * 32;
    constexpr int JB = TN / 2;
    __shared__ unsigned short As[128 * 32];
    __shared__ unsigned short Bs[BN * 32];
    int tid = threadIdx.x, lane = tid & 63, w = tid >> 6;
    int wm = w >> 1, wn = w & 1;
    int m0 = blockIdx.y * 128, n0 = blockIdx.x * BN;

    int lr = lane >> 2, lq = lane & 3;
    const unsigned short* gA[2];
    const unsigned short* gB[JB];
    #pragma unroll
    for (int j = 0; j < 2; ++j) {
        int row = w * 32 + j * 16 + lr;
        int qg = lq ^ ((row >> 1) & 3);
        gA[j] = A + (size_t)(m0 + row) * KD + qg * 8;
    }
    #pragma unroll
    for (int j = 0; j < JB; ++j) {
        int row = w * (JB * 16) + j * 16 + lr;
        int qg = lq ^ ((row >> 1) & 3);
        gB[j] = Bt + (size_t)(n0 + row) * KD + qg * 8;
    }

    int rr = lane & 15, qd = lane >> 4;
    const unsigned short* aAddr[4];
    const unsigned short* bAddr[TN];
    #pragma unroll
    for (int i = 0; i < 4; ++i) {
        int row = wm * 64 + i * 16 + rr;
        int qs = qd ^ ((row >> 1) & 3);
        aAddr[i] = As + row * 32 + qs * 8;
    }
    #pragma unroll
    for (int t = 0; t < TN; ++t) {
        int row = wn * (TN * 16) + t * 16 + rr;
        int qs = qd ^ ((row >> 1) & 3);
        bAddr[t] = Bs + row * 32 + qs * 8;
    }

    f32x4 acc[4][TN];
    #pragma unroll
    for (int i = 0; i < 4; ++i)
        #pragma unroll
        for (int t = 0; t < TN; ++t) acc[i][t] = {0.f, 0.f, 0.f, 0.f};

    for (int k = 0; k < KD / 32; ++k) {
        __syncthreads();
        load16_lds(gA[0], As + (w * 2 + 0) * 512);
        load16_lds(gA[1], As + (w * 2 + 1) * 512);
        #pragma unroll
        for (int j = 0; j < JB; ++j)
            load16_lds(gB[j], Bs + (w * JB + j) * 512);
        gA[0] += 32; gA[1] += 32;
        #pragma unroll
        for (int j = 0; j < JB; ++j) gB[j] += 32;
        __syncthreads();

        bf16x8 af[4], bfr[TN];
        #pragma unroll
        for (int i = 0; i < 4; ++i) af[i] = *(const bf16x8*)aAddr[i];
        #pragma unroll
        for (int t = 0; t < TN; ++t) bfr[t] = *(const bf16x8*)bAddr[t];
        #pragma unroll
        for (int i = 0; i < 4; ++i)
            #pragma unroll
            for (int t = 0; t < TN; ++t)
                acc[i][t] = __builtin_amdgcn_mfma_f32_16x16x32_bf16(af[i], bfr[t], acc[i][t], 0, 0, 0);
    }

    #pragma unroll
    for (int t = 0; t < TN; ++t) {
        int col = n0 + wn * (TN * 16) + t * 16 + rr;
        if (SPLITV && col >= 3072) {
            int rel = col - 3072, hh = rel >> 7, e = rel & 127;
            #pragma unroll
            for (int i = 0; i < 4; ++i) {
                int row0 = m0 + wm * 64 + i * 16 + qd * 4;
                int b = row0 >> 10, tt = row0 & 1023;
                ushort4 pk;
                pk.x = f2bf(acc[i][t][0]); pk.y = f2bf(acc[i][t][1]);
                pk.z = f2bf(acc[i][t][2]); pk.w = f2bf(acc[i][t][3]);
                *(ushort4*)&VtOut[(size_t)((b * Hc + hh) * 128 + e) * 1024 + tt] = pk;
            }
        } else {
            float bv = OUT_BIAS ? bias[col] : 0.f;
            #pragma unroll
            for (int i = 0; i < 4; ++i) {
                #pragma unroll
                for (int r = 0; r < 4; ++r) {
                    int row = m0 + wm * 64 + i * 16 + qd * 4 + r;
                    if (OUT_BIAS)
                        Cf[(size_t)row * LDC + col] = acc[i][t][r] + bv;
                    else
                        Cb[(size_t)row * LDC + col] = f2bf(acc[i][t][r]);
                }
            }
        }
    }
}

// ---------------------------------------------------------------------------
// MFMA differential flash attention — R14: swapped QK^T, no P LDS round-trip.
// R13 measured ~4300 cyc/block-tile with MFMA 8% / VALU 29% / all pipes idle:
// the per-tile serial chain (~2200 cyc/wave) is the limiter, and its largest
// segment was the P transpose through LDS (8 ds_write -> lgkmcnt(0) -> 2
// ds_read_b128 -> lgkmcnt -> 8 perms ~ 350-400 cyc). Fix: compute S^T via
// mfma(K, Q) (A/B operands have identical lane maps, so swapping args
// transposes the output): lane (cl,qd) holds keys c*16+qd*4+r for Q-row cl.
// PV's A-fragment (row cl, keys qd*8..+7) is then reached by a fixed 16-lane
// group permutation: 16 ds_bpermute + 8 cndmask on packed bf16 key-pairs —
// no LDS buffer, no lgkmcnt(0) round-trip. l-sums become per-lane over keys;
// reduced once at the end (2 shfl_xor + 4 shfl). Frees the 9KB P buffer:
// LDS 49152 B -> 3 blocks/CU (12 waves, 3/SIMD) matching the 768-block grid
// (3/CU) exactly.
// Pipeline (unchanged from R13): 3-slot LDS ring, counted vmcnt(4) + raw
// s_barrier per tile, stage(kt+2) issued after the ds_reads of kt.
// grid (48,16): x = bh (XCD-pinned), y -> g = 15-y longest-first;
// block g: Q-rows 64g..64g+63 (4 waves x 16), K-tiles 0..2g+1.
// ---------------------------------------------------------------------------
__global__ __launch_bounds__(256) void diff_attn_mfma(
    const unsigned short* __restrict__ Y, const unsigned short* __restrict__ Vt,
    const float* __restrict__ lam_buf, unsigned short* __restrict__ attn)
{
    // ring slot byte layout: K1 [0,4096), K2 [4096,8192), V [8192,16384)
    __shared__ __align__(16) unsigned short KVring[3 * 8192];

    int bh = blockIdx.x;                          // fastest dim -> XCD-pinned
    int b = bh / Hc, h = bh - b * Hc;
    int g = 15 - (int)blockIdx.y;                 // longest first
    int tid = threadIdx.x, lane = tid & 63, wv = tid >> 6;
    int cl = lane & 15, qd = lane >> 4;
    float lamv = lam_buf[h];
    size_t rowbase = (size_t)(b * Tc) * YLD;
    const int hq = h * HSc;
    const unsigned short* VtB = Vt + ((size_t)bh << 17);   // bh*128*1024
    const f32x4 zero4 = {0.f, 0.f, 0.f, 0.f};

    // ---- staging lane->global mappings (kt-independent parts) ----
    // K (waves 0,1): seg r8 holds rows r8*8..r8*8+7, 8 chunks of 16B per row.
    // LDS slot: row = r8*8 + lane>>3, lds chunk = lane&7;
    // stored global chunk = (lane&7) ^ (row&7)  [inverse of read swizzle]
    int ksrow = lane >> 3;                 // row within seg
    int ksch  = (lane & 7) ^ ksrow;        // global chunk
    int offk[4];
    {
        int mat = wv & 1;                  // wave0 -> K1, wave1 -> K2
        int moff = mat ? K2OFF : K1OFF;
        #pragma unroll
        for (int r8 = 0; r8 < 4; ++r8)
            offk[r8] = (r8 * 8 + ksrow) * YLD + moff + hq + ksch * 8;
    }
    // V (waves 2,3): seg sv holds e-rows sv*16..sv*16+15, 4 chunks of 16B.
    // LDS slot: e = sv*16 + lane>>2, lds chunk = lane&3;
    // stored global chunk = (lane&3) ^ ((e>>1)&3)   [2-way banks on read]
    int vsel = lane >> 2;                  // e within seg
    int vsch = (lane & 3) ^ ((vsel >> 1) & 3);
    int offv[4];
    {
        int sv0 = (wv & 1) * 4;            // wave2 -> sv 0..3, wave3 -> sv 4..7
        #pragma unroll
        for (int i = 0; i < 4; ++i)
            offv[i] = ((sv0 + i) * 16 + vsel) * 1024 + vsch * 8;
    }

    auto stage = [&](int kt, int slot) {
        char* base = (char*)KVring + slot * 16384 + wv * 4096;
        if (wv < 2) {
            const unsigned short* g0 = Y + rowbase + (size_t)(kt * 32) * YLD;
            #pragma unroll
            for (int r8 = 0; r8 < 4; ++r8)
                load16_lds(g0 + offk[r8], base + r8 * 1024);
        } else {
            const unsigned short* g0 = VtB + kt * 32;
            #pragma unroll
            for (int i = 0; i < 4; ++i)
                load16_lds(g0 + offv[i], base + i * 1024);
        }
    };

    // ---- fragment LDS byte offsets within a slot (swizzled reads) ----
    int kfo[2][4], vfo[8];
    #pragma unroll
    for (int c = 0; c < 2; ++c) {
        int row = c * 16 + cl;
        #pragma unroll
        for (int j = 0; j < 4; ++j)
            kfo[c][j] = (j >> 1) * 4096 + row * 128 +
                        ((((j & 1) * 4 + qd) ^ (row & 7)) << 4);
    }
    #pragma unroll
    for (int ec = 0; ec < 8; ++ec) {
        int e = ec * 16 + cl;
        vfo[ec] = 8192 + e * 64 + ((qd ^ ((e >> 1) & 3)) << 4);
    }

    // P-transform bpermute indices (byte = srclane*4):
    //   target lane (cl,qd) pulls key-pairs from source lanes
    //   qd_srcA = 2*(qd&1), qd_srcB = qd_srcA+1 (c selected by qd>>1)
    int idxA = ((32 * (qd & 1)) + cl) * 4;
    int idxB = idxA + 64;
    bool loHalf = (qd < 2);

    int qrow = g * 64 + wv * 16;

    // Q loads as u32x4, detached from vmcnt tracking via "+v" pass-through
    size_t qoff = rowbase + (size_t)(qrow + cl) * YLD;
    u32x4 uq1a = *(const u32x4*)(Y + qoff + Q1OFF + hq + qd * 8);
    u32x4 uq1b = *(const u32x4*)(Y + qoff + Q1OFF + hq + 32 + qd * 8);
    u32x4 uq2a = *(const u32x4*)(Y + qoff + Q2OFF + hq + qd * 8);
    u32x4 uq2b = *(const u32x4*)(Y + qoff + Q2OFF + hq + 32 + qd * 8);
    asm volatile("" : "+v"(uq1a), "+v"(uq1b), "+v"(uq2a), "+v"(uq2b));
    asm volatile("" : "+v"(lamv));
    asm volatile("s_waitcnt vmcnt(0)" ::: "memory");
    bf16x8 q1a = __builtin_bit_cast(bf16x8, uq1a);
    bf16x8 q1b = __builtin_bit_cast(bf16x8, uq1b);
    bf16x8 q2a = __builtin_bit_cast(bf16x8, uq2a);
    bf16x8 q2b = __builtin_bit_cast(bf16x8, uq2b);

    f32x4 O1[8], O2[8];
    #pragma unroll
    for (int ec = 0; ec < 8; ++ec) { O1[ec] = zero4; O2[ec] = zero4; }
    float l1s = 0.f, l2s = 0.f;

    int NT = 2 * g + 2;
    int ktmax = 2 * g + (wv >> 1);   // waves 0,1 skip the fully-masked last tile

    stage(0, 0);
    stage(1, 1);

    int cur = 0;
    for (int kt = 0; kt < NT; ++kt) {
        // counted wait: stage(kt) complete (4 newer = stage(kt+1) may fly).
        if (kt < NT - 1) {
            asm volatile("s_waitcnt vmcnt(4)\n\ts_barrier" ::: "memory");
        } else {
            asm volatile("s_waitcnt vmcnt(0)\n\ts_barrier" ::: "memory");
        }
        const char* kb = (const char*)KVring + cur * 16384;

        // issue ds reads first (compiler-counted lgkm waits before MFMA use)
        bf16x8 kf[2][4];
        #pragma unroll
        for (int c = 0; c < 2; ++c)
            #pragma unroll
            for (int j = 0; j < 4; ++j)
                kf[c][j] = *(const bf16x8*)(kb + kfo[c][j]);
        bf16x8 vf[8];
        #pragma unroll
        for (int ec = 0; ec < 8; ++ec)
            vf[ec] = *(const bf16x8*)(kb + vfo[ec]);

        // prefetch 2 ahead into the slot all waves finished reading at kt-1
        if (kt + 2 < NT) {
            int st = cur + 2; if (st >= 3) st -= 3;
            stage(kt + 2, st);
        }

        if (kt <= ktmax) {
            // swapped: S^T[key][qrow] = mfma(K, Q): lane holds qrow=cl,
            // keys c*16 + qd*4 + r
            f32x4 S1[2], S2[2];
            #pragma unroll
            for (int c = 0; c < 2; ++c) { S1[c] = zero4; S2[c] = zero4; }
            #pragma unroll
            for (int c = 0; c < 2; ++c) {
                S1[c] = __builtin_amdgcn_mfma_f32_16x16x32_bf16(kf[c][0], q1a, S1[c], 0, 0, 0);
                S1[c] = __builtin_amdgcn_mfma_f32_16x16x32_bf16(kf[c][1], q1b, S1[c], 0, 0, 0);
                S2[c] = __builtin_amdgcn_mfma_f32_16x16x32_bf16(kf[c][2], q2a, S2[c], 0, 0, 0);
                S2[c] = __builtin_amdgcn_mfma_f32_16x16x32_bf16(kf[c][3], q2b, S2[c], 0, 0, 0);
            }
            if (kt * 32 + 31 > qrow) {
                #pragma unroll
                for (int c = 0; c < 2; ++c) {
                    // mask key > row: key = kt*32+c*16+qd*4+r, row = qrow+cl
                    int lim = qrow + cl - kt * 32 - c * 16 - qd * 4;
                    #pragma unroll
                    for (int r = 0; r < 4; ++r) {
                        if (r > lim) { S1[c][r] = -1e30f; S2[c][r] = -1e30f; }
                    }
                }
            }
            // p = exp2(s * 0.125*log2e), per-lane l accumulation (row = cl)
            float p1v[2][4], p2v[2][4];
            #pragma unroll
            for (int c = 0; c < 2; ++c) {
                #pragma unroll
                for (int r = 0; r < 4; ++r) {
                    p1v[c][r] = fast_exp2(S1[c][r] * EXP2SCALE);
                    p2v[c][r] = fast_exp2(S2[c][r] * EXP2SCALE);
                    l1s += p1v[c][r];
                    l2s += p2v[c][r];
                }
            }
            // pack key-pairs per matrix: sm[c][m] = keys (c*16+qd*4+2m, +1)
            unsigned int s1m[2][2], s2m[2][2];
            #pragma unroll
            for (int c = 0; c < 2; ++c) {
                s1m[c][0] = pack2bf(p1v[c][0], p1v[c][1]);
                s1m[c][1] = pack2bf(p1v[c][2], p1v[c][3]);
                s2m[c][0] = pack2bf(p2v[c][0], p2v[c][1]);
                s2m[c][1] = pack2bf(p2v[c][2], p2v[c][3]);
            }
            // cross-lane gather into A-operand order: keys 8qd..8qd+7, row cl
            u32x4 U1, U2;
            {
                int a00 = __builtin_amdgcn_ds_bpermute(idxA, (int)s1m[0][0]);
                int a10 = __builtin_amdgcn_ds_bpermute(idxA, (int)s1m[1][0]);
                int a01 = __builtin_amdgcn_ds_bpermute(idxA, (int)s1m[0][1]);
                int a11 = __builtin_amdgcn_ds_bpermute(idxA, (int)s1m[1][1]);
                int b00 = __builtin_amdgcn_ds_bpermute(idxB, (int)s1m[0][0]);
                int b10 = __builtin_amdgcn_ds_bpermute(idxB, (int)s1m[1][0]);
                int b01 = __builtin_amdgcn_ds_bpermute(idxB, (int)s1m[0][1]);
                int b11 = __builtin_amdgcn_ds_bpermute(idxB, (int)s1m[1][1]);
                U1[0] = (unsigned)(loHalf ? a00 : a10);
                U1[1] = (unsigned)(loHalf ? a01 : a11);
                U1[2] = (unsigned)(loHalf ? b00 : b10);
                U1[3] = (unsigned)(loHalf ? b01 : b11);
            }
            {
                int a00 = __builtin_amdgcn_ds_bpermute(idxA, (int)s2m[0][0]);
                int a10 = __builtin_amdgcn_ds_bpermute(idxA, (int)s2m[1][0]);
                int a01 = __builtin_amdgcn_ds_bpermute(idxA, (int)s2m[0][1]);
                int a11 = __builtin_amdgcn_ds_bpermute(idxA, (int)s2m[1][1]);
                int b00 = __builtin_amdgcn_ds_bpermute(idxB, (int)s2m[0][0]);
                int b10 = __builtin_amdgcn_ds_bpermute(idxB, (int)s2m[1][0]);
                int b01 = __builtin_amdgcn_ds_bpermute(idxB, (int)s2m[0][1]);
                int b11 = __builtin_amdgcn_ds_bpermute(idxB, (int)s2m[1][1]);
                U2[0] = (unsigned)(loHalf ? a00 : a10);
                U2[1] = (unsigned)(loHalf ? a01 : a11);
                U2[2] = (unsigned)(loHalf ? b00 : b10);
                U2[3] = (unsigned)(loHalf ? b01 : b11);
            }
            bf16x8 pa1 = __builtin_bit_cast(bf16x8, U1);
            bf16x8 pa2 = __builtin_bit_cast(bf16x8, U2);
            #pragma unroll
            for (int ec = 0; ec < 8; ++ec) {
                O1[ec] = __builtin_amdgcn_mfma_f32_16x16x32_bf16(pa1, vf[ec], O1[ec], 0, 0, 0);
                O2[ec] = __builtin_amdgcn_mfma_f32_16x16x32_bf16(pa2, vf[ec], O2[ec], 0, 0, 0);
            }
        }
        cur = (cur == 2) ? 0 : cur + 1;
    }

    // l sums: lane holds partial for row cl over its key-groups; reduce
    // across the 4 qd groups, then redistribute to output rows qd*4+r.
    l1s += __shfl_xor(l1s, 16); l1s += __shfl_xor(l1s, 32);
    l2s += __shfl_xor(l2s, 16); l2s += __shfl_xor(l2s, 32);
    float w1[4], w2[4];
    #pragma unroll
    for (int r = 0; r < 4; ++r) {
        float d1 = __shfl(l1s, qd * 4 + r);   // lane qd*4+r has row qd*4+r
        float d2 = __shfl(l2s, qd * 4 + r);
        w1[r] = 1.0f / d1;
        w2[r] = lamv / d2;
    }
    #pragma unroll
    for (int ec = 0; ec < 8; ++ec) {
        #pragma unroll
        for (int r = 0; r < 4; ++r) {
            size_t row = (size_t)(b * Tc + qrow + qd * 4 + r);
            attn[row * HVD + h * VDc + ec * 16 + cl] =
                f2bf(O1[ec][r] * w1[r] - O2[ec][r] * w2[r]);
        }
    }
}

// ---------------------------------------------------------------------------
// Fused row-stats + LayerNorm*0.2, in-place on bf16 attn. 128 thr/row.
// ---------------------------------------------------------------------------
__global__ __launch_bounds__(128) void ln_inplace(
    unsigned short* __restrict__ attn,
    const float* __restrict__ gnw, const float* __restrict__ gnb)
{
    int row = blockIdx.x, tid = threadIdx.x;
    unsigned short* p = attn + (size_t)row * HVD;
    float v[12];
    float s = 0.f, sq = 0.f;
    #pragma unroll
    for (int j = 0; j < 3; ++j) {
        int g = tid + j * 128;
        ushort4 u = *(const ushort4*)(p + g * 4);
        float x0 = bf2f(u.x), x1 = bf2f(u.y), x2 = bf2f(u.z), x3 = bf2f(u.w);
        v[j * 4 + 0] = x0; v[j * 4 + 1] = x1; v[j * 4 + 2] = x2; v[j * 4 + 3] = x3;
        s += x0 + x1 + x2 + x3;
        sq = fmaf(x0, x0, sq); sq = fmaf(x1, x1, sq);
        sq = fmaf(x2, x2, sq); sq = fmaf(x3, x3, sq);
    }
    #pragma unroll
    for (int off = 32; off; off >>= 1) { s += __shfl_xor(s, off); sq += __shfl_xor(sq, off); }
    __shared__ float ss[2], sqs[2];
    if ((tid & 63) == 0) { ss[tid >> 6] = s; sqs[tid >> 6] = sq; }
    __syncthreads();
    float S = ss[0] + ss[1], Q = sqs[0] + sqs[1];
    float mu = S * (1.0f / HVD);
    float rstd = rsqrtf(Q * (1.0f / HVD) - mu * mu + 1e-5f);
    #pragma unroll
    for (int j = 0; j < 3; ++j) {
        int g = tid + j * 128;
        float4 gw = *(const float4*)(gnw + g * 4);
        float4 gb = *(const float4*)(gnb + g * 4);
        ushort4 o;
        o.x = f2bf(((v[j * 4 + 0] - mu) * rstd * gw.x + gb.x) * 0.2f);
        o.y = f2bf(((v[j * 4 + 1] - mu) * rstd * gw.y + gb.y) * 0.2f);
        o.z = f2bf(((v[j * 4 + 2] - mu) * rstd * gw.z + gb.z) * 0.2f);
        o.w = f2bf(((v[j * 4 + 3] - mu) * rstd * gw.w + gb.w) * 0.2f);
        *(ushort4*)(p + g * 4) = o;
    }
}

// ---------------------------------------------------------------------------
// launch
// ---------------------------------------------------------------------------
extern "C" void kernel_launch(void* const* d_in, const int* in_sizes, int n_in,
                              void* d_out, int out_size, void* d_ws, size_t ws_size,
                              hipStream_t stream)
{
    const float* x   = (const float*)d_in[0];
    const float* Wq1 = (const float*)d_in[1];
    const float* Wk1 = (const float*)d_in[2];
    const float* Wq2 = (const float*)d_in[3];
    const float* Wk2 = (const float*)d_in[4];
    const float* Wv  = (const float*)d_in[5];
    const float* lq1 = (const float*)d_in[6];
    const float* lk1 = (const float*)d_in[7];
    const float* lq2 = (const float*)d_in[8];
    const float* lk2 = (const float*)d_in[9];
    const float* gnw = (const float*)d_in[10];
    const float* gnb = (const float*)d_in[11];
    const float* Wp  = (const float*)d_in[12];
    const float* bp  = (const float*)d_in[13];
    const int*   lidx = (const int*)d_in[14];
    float* out = (float*)d_out;

    // workspace layout (bytes):
    // WcatT bf16 [4608][768]:  7,077,888 @ 0
    // Xb    bf16 [4096][768]:  6,291,456 @ 7,077,888
    // Y     bf16 [4096][3072]: 25,165,824 @ 13,369,344
    // Vt    bf16 [48][128][1024]: 12,582,912 @ 38,535,168
    // attn  bf16 [4096][1536]: 12,582,912 @ 51,118,080
    // Wpb   bf16 [768][1536]:   2,359,296 @ 63,700,992
    // lam   f32 [12]                       @ 66,060,288
    char* w = (char*)d_ws;
    unsigned short* WcatT = (unsigned short*)(w);
    unsigned short* Xb    = (unsigned short*)(w + 7077888);
    unsigned short* Y     = (unsigned short*)(w + 13369344);
    unsigned short* VtW   = (unsigned short*)(w + 38535168);
    unsigned short* attn  = (unsigned short*)(w + 51118080);
    unsigned short* Wpb   = (unsigned short*)(w + 63700992);
    float* lam            = (float*)(w + 66060288);

    cast_bf16<<<dim3(NROWS * Cc / 1024), 256, 0, stream>>>(x, Xb);
    cast_bf16<<<dim3(Cc * HVD / 1024), 256, 0, stream>>>(Wp, Wpb);
    trans_w<<<dim3(72 * 12), 256, 0, stream>>>(Wq1, Wk1, Wq2, Wk2, Wv, WcatT);
    lambda_kernel<<<dim3(Hc), 64, 0, stream>>>(lq1, lk1, lq2, lk2, lidx, lam);
    // QKV: [4096,768] x [768,4608]; Q/K -> Y (LD 3072), V -> Vt transposed
    gemm_mfma<4, 768, YLD, false, true><<<dim3(NQKV / 128, NROWS / 128), 256, 0, stream>>>(
        Xb, WcatT, Y, nullptr, nullptr, VtW);
    // bh fastest (XCD pin); y -> g = 15-y, longest-first; 768 blocks x 4 waves,
    // 64 Q-rows per block, K/V staged in 3-slot LDS ring, counted-vmcnt barriers,
    // swapped-QK^T + bpermute P-transform (no P LDS)
    diff_attn_mfma<<<dim3(Bc * Hc, 16), 256, 0, stream>>>(Y, VtW, lam, attn);
    ln_inplace<<<dim3(NROWS), 128, 0, stream>>>(attn, gnw, gnb);
    // OUT: [4096,1536] x [1536,768] -> out fp32 (+bias)
    gemm_mfma<2, HVD, Cc, true, false><<<dim3(Cc / 64, NROWS / 128), 256, 0, stream>>>(
        attn, Wpb, nullptr, out, bp, nullptr);
}

// Round 7
// 250.862 us; speedup vs baseline: 1.9236x; 1.0939x over previous
//
#include <hip/hip_runtime.h>
#include <hip/hip_bf16.h>

// Problem constants
#define Bc   4
#define Tc   1024
#define Cc   768
#define Hc   12
#define HSc  64
#define VDc  128
#define NQKV 4608   // gemm N for qkv (4*768 Q/K + 1536 V)
#define YLD  3072   // Y row stride: Q/K only (V goes to Vt)
#define NROWS 4096  // B*T
#define HVD  1536   // H*VD

// Y (qk) column offsets
#define Q1OFF 0
#define K1OFF 768
#define Q2OFF 1536
#define K2OFF 2304

typedef __bf16 bf16x8 __attribute__((ext_vector_type(8)));
typedef float f32x4 __attribute__((ext_vector_type(4)));
typedef unsigned int u32x4 __attribute__((ext_vector_type(4)));

// exp(s*0.125) == exp2(s * 0.125*log2(e))
#define EXP2SCALE 0.18033688011112042f

static __device__ __forceinline__ float bf2f(unsigned short s) {
    return __uint_as_float(((unsigned int)s) << 16);
}
static __device__ __forceinline__ unsigned short f2bf(float f) {
    unsigned int u = __float_as_uint(f);
    unsigned int r = (u + 0x7FFFu + ((u >> 16) & 1u)) >> 16;  // round-nearest-even
    return (unsigned short)r;
}
static __device__ __forceinline__ unsigned int pack2bf(float lo, float hi) {
    // bf16(lo) | bf16(hi)<<16, half-up rounding (values >= 0)
    unsigned int a = (__float_as_uint(lo) + 0x8000u) >> 16;
    unsigned int b = (__float_as_uint(hi) + 0x8000u) & 0xFFFF0000u;
    return a | b;
}
// raw v_exp_f32: 2^x without libm denorm guards (inputs bounded here)
static __device__ __forceinline__ float fast_exp2(float x) {
    float r;
    asm("v_exp_f32 %0, %1" : "=v"(r) : "v"(x));
    return r;
}

// async global->LDS 16B per lane; lds base must be wave-uniform
static __device__ __forceinline__ void load16_lds(const void* g, void* l) {
    __builtin_amdgcn_global_load_lds(
        (const __attribute__((address_space(1))) void*)g,
        (__attribute__((address_space(3))) void*)l, 16, 0, 0);
}

// ---------------------------------------------------------------------------
// cast fp32 -> bf16, 4 elts/thread
// ---------------------------------------------------------------------------
__global__ __launch_bounds__(256) void cast_bf16(
    const float* __restrict__ src, unsigned short* __restrict__ dst)
{
    int i = blockIdx.x * 256 + threadIdx.x;
    float4 v = *(const float4*)(src + (size_t)i * 4);
    ushort4 u;
    u.x = f2bf(v.x); u.y = f2bf(v.y); u.z = f2bf(v.z); u.w = f2bf(v.w);
    *(ushort4*)(dst + (size_t)i * 4) = u;
}

// ---------------------------------------------------------------------------
// Transpose-repack the 5 projection weights into WcatT[n][k] bf16, k-contig.
// ---------------------------------------------------------------------------
__global__ __launch_bounds__(256) void trans_w(
    const float* __restrict__ Wq1, const float* __restrict__ Wk1,
    const float* __restrict__ Wq2, const float* __restrict__ Wk2,
    const float* __restrict__ Wv, unsigned short* __restrict__ WcatT)
{
    __shared__ float tile[64][65];
    int tid = threadIdx.x;
    int t = blockIdx.x;
    int kt = t % 12, nt = t / 12;
    int k0 = kt * 64, n0 = nt * 64;
    const float* src;
    int stride;
    if (n0 < 3072) {
        int which = n0 / 768, m = n0 - which * 768, h = m >> 6;
        const float* W = (which == 0) ? Wq1 : (which == 1) ? Wk1 : (which == 2) ? Wq2 : Wk2;
        src = W + ((size_t)h * 768 + k0) * 64;
        stride = 64;
    } else {
        int rel = n0 - 3072, h = rel >> 7, e0 = rel & 127;
        src = Wv + ((size_t)h * 768 + k0) * 128 + e0;
        stride = 128;
    }
    for (int i = tid; i < 4096; i += 256) {
        int kl = i >> 6, dl = i & 63;
        tile[dl][kl] = src[(size_t)kl * stride + dl];
    }
    __syncthreads();
    for (int i = tid; i < 4096; i += 256) {
        int nl = i >> 6, kl = i & 63;
        WcatT[(size_t)(n0 + nl) * 768 + k0 + kl] = f2bf(tile[nl][kl]);
    }
}

// ---------------------------------------------------------------------------
// lambda per head
// ---------------------------------------------------------------------------
__global__ __launch_bounds__(64) void lambda_kernel(
    const float* __restrict__ lq1, const float* __restrict__ lk1,
    const float* __restrict__ lq2, const float* __restrict__ lk2,
    const int* __restrict__ layer_idx, float* __restrict__ lam)
{
    int h = blockIdx.x, l = threadIdx.x;
    float li = (float)layer_idx[0];
    float dyn = 0.8f - 0.6f * expf(-0.3f * (li - 1.0f));
    int i = h * HSc + l;
    float v = expf(lq1[i] * lk1[i]) - expf(lq2[i] * lk2[i]) + dyn;
    #pragma unroll
    for (int off = 32; off; off >>= 1) v += __shfl_xor(v, off);
    if (l == 0) lam[h] = v * (1.0f / 64.0f);
}

// ---------------------------------------------------------------------------
// MFMA GEMM (m97 structure): C[M][LDC] = A[M][KD] * Bt[N][KD]^T, bf16 inputs.
// SPLITV: cols >= 3072 (V projection) -> written transposed to VtOut[bh][e][t].
// ---------------------------------------------------------------------------
template<int TN, int KD, int LDC, bool OUT_BIAS, bool SPLITV>
__global__ __launch_bounds__(256) void gemm_mfma(
    const unsigned short* __restrict__ A, const unsigned short* __restrict__ Bt,
    unsigned short* __restrict__ Cb, float* __restrict__ Cf,
    const float* __restrict__ bias, unsigned short* __restrict__ VtOut)
{
    constexpr int BN = TN * 32;
    constexpr int JB = TN / 2;
    __shared__ unsigned short As[128 * 32];
    __shared__ unsigned short Bs[BN * 32];
    int tid = threadIdx.x, lane = tid & 63, w = tid >> 6;
    int wm = w >> 1, wn = w & 1;
    int m0 = blockIdx.y * 128, n0 = blockIdx.x * BN;

    int lr = lane >> 2, lq = lane & 3;
    const unsigned short* gA[2];
    const unsigned short* gB[JB];
    #pragma unroll
    for (int j = 0; j < 2; ++j) {
        int row = w * 32 + j * 16 + lr;
        int qg = lq ^ ((row >> 1) & 3);
        gA[j] = A + (size_t)(m0 + row) * KD + qg * 8;
    }
    #pragma unroll
    for (int j = 0; j < JB; ++j) {
        int row = w * (JB * 16) + j * 16 + lr;
        int qg = lq ^ ((row >> 1) & 3);
        gB[j] = Bt + (size_t)(n0 + row) * KD + qg * 8;
    }

    int rr = lane & 15, qd = lane >> 4;
    const unsigned short* aAddr[4];
    const unsigned short* bAddr[TN];
    #pragma unroll
    for (int i = 0; i < 4; ++i) {
        int row = wm * 64 + i * 16 + rr;
        int qs = qd ^ ((row >> 1) & 3);
        aAddr[i] = As + row * 32 + qs * 8;
    }
    #pragma unroll
    for (int t = 0; t < TN; ++t) {
        int row = wn * (TN * 16) + t * 16 + rr;
        int qs = qd ^ ((row >> 1) & 3);
        bAddr[t] = Bs + row * 32 + qs * 8;
    }

    f32x4 acc[4][TN];
    #pragma unroll
    for (int i = 0; i < 4; ++i)
        #pragma unroll
        for (int t = 0; t < TN; ++t) acc[i][t] = {0.f, 0.f, 0.f, 0.f};

    for (int k = 0; k < KD / 32; ++k) {
        __syncthreads();
        load16_lds(gA[0], As + (w * 2 + 0) * 512);
        load16_lds(gA[1], As + (w * 2 + 1) * 512);
        #pragma unroll
        for (int j = 0; j < JB; ++j)
            load16_lds(gB[j], Bs + (w * JB + j) * 512);
        gA[0] += 32; gA[1] += 32;
        #pragma unroll
        for (int j = 0; j < JB; ++j) gB[j] += 32;
        __syncthreads();

        bf16x8 af[4], bfr[TN];
        #pragma unroll
        for (int i = 0; i < 4; ++i) af[i] = *(const bf16x8*)aAddr[i];
        #pragma unroll
        for (int t = 0; t < TN; ++t) bfr[t] = *(const bf16x8*)bAddr[t];
        #pragma unroll
        for (int i = 0; i < 4; ++i)
            #pragma unroll
            for (int t = 0; t < TN; ++t)
                acc[i][t] = __builtin_amdgcn_mfma_f32_16x16x32_bf16(af[i], bfr[t], acc[i][t], 0, 0, 0);
    }

    #pragma unroll
    for (int t = 0; t < TN; ++t) {
        int col = n0 + wn * (TN * 16) + t * 16 + rr;
        if (SPLITV && col >= 3072) {
            int rel = col - 3072, hh = rel >> 7, e = rel & 127;
            #pragma unroll
            for (int i = 0; i < 4; ++i) {
                int row0 = m0 + wm * 64 + i * 16 + qd * 4;
                int b = row0 >> 10, tt = row0 & 1023;
                ushort4 pk;
                pk.x = f2bf(acc[i][t][0]); pk.y = f2bf(acc[i][t][1]);
                pk.z = f2bf(acc[i][t][2]); pk.w = f2bf(acc[i][t][3]);
                *(ushort4*)&VtOut[(size_t)((b * Hc + hh) * 128 + e) * 1024 + tt] = pk;
            }
        } else {
            float bv = OUT_BIAS ? bias[col] : 0.f;
            #pragma unroll
            for (int i = 0; i < 4; ++i) {
                #pragma unroll
                for (int r = 0; r < 4; ++r) {
                    int row = m0 + wm * 64 + i * 16 + qd * 4 + r;
                    if (OUT_BIAS)
                        Cf[(size_t)row * LDC + col] = acc[i][t][r] + bv;
                    else
                        Cb[(size_t)row * LDC + col] = f2bf(acc[i][t][r]);
                }
            }
        }
    }
}

// ---------------------------------------------------------------------------
// MFMA differential flash attention — R15: 64-key iterations + LPT backfill.
// R12-R14 each shortened one chain segment and gained ~5%: per-block-tile
// cost pinned ~4200cyc, all pipes <30%, occupancy 18% (768 blocks = exactly
// resident capacity -> NO backfill; CUs decay to one 4-wave block). R15:
// (1) process K-tile PAIR (2i,2i+1) per iteration: two independent
//     QK->exp->bpermute->PV chains (2x ILP), half the barriers. Fully-masked
//     final subtiles are computed anyway (mask -> exp->0, exact) - no branch.
// (2) 2-slot x 32KB ring (64KB LDS), 1-deep prefetch issued right after the
//     barrier; vmcnt(0) wait lands a full iteration later (latency free).
// (3) 64KB LDS forces 2 blocks/CU -> 512 resident + 256 queued; dispatch is
//     longest-first so the queue holds the shortest blocks = hardware LPT.
// DS-pipe order: V-B reads issued BETWEEN bperm-A and bperm-B so they queue
// behind the data PV-A needs, not in front of it.
// grid (48,16): x = bh (XCD-pinned), y -> g = 15-y; block g: Q-rows
// 64g..64g+63 (4 waves x 16), NI = g+1 iterations of 64 keys.
// Slot layout (32KB): [A: K1 0-4K | K2 4-8K | V 8-16K][B: +16K same].
// ---------------------------------------------------------------------------
__global__ __launch_bounds__(256) void diff_attn_mfma(
    const unsigned short* __restrict__ Y, const unsigned short* __restrict__ Vt,
    const float* __restrict__ lam_buf, unsigned short* __restrict__ attn)
{
    __shared__ __align__(16) unsigned short KVring[2 * 16384];  // 64 KB

    int bh = blockIdx.x;                          // fastest dim -> XCD-pinned
    int b = bh / Hc, h = bh - b * Hc;
    int g = 15 - (int)blockIdx.y;                 // longest first
    int tid = threadIdx.x, lane = tid & 63, wv = tid >> 6;
    int cl = lane & 15, qd = lane >> 4;
    float lamv = lam_buf[h];
    size_t rowbase = (size_t)(b * Tc) * YLD;
    const int hq = h * HSc;
    const unsigned short* VtB = Vt + ((size_t)bh << 17);   // bh*128*1024
    const f32x4 zero4 = {0.f, 0.f, 0.f, 0.f};

    // ---- staging lane->global mapping (one 8-load set per wave) ----
    // wave0: K1+K2 of subtile A; wave1: K1+K2 of B; wave2: V of A; wave3: V of B
    int sub = wv & 1;
    int off8[8];
    int dstoff;
    if (wv < 2) {
        int ksrow = lane >> 3;                  // row within 8-row seg
        int ksch  = (lane & 7) ^ ksrow;         // stored global chunk (inv swizzle)
        #pragma unroll
        for (int j = 0; j < 8; ++j) {
            int moff = (j < 4) ? K1OFF : K2OFF;
            off8[j] = ((j & 3) * 8 + ksrow) * YLD + moff + hq + ksch * 8;
        }
        dstoff = 0;
    } else {
        int vsel = lane >> 2;                   // e within 16-row seg
        int vsch = (lane & 3) ^ ((vsel >> 1) & 3);
        #pragma unroll
        for (int s = 0; s < 8; ++s)
            off8[s] = (s * 16 + vsel) * 1024 + vsch * 8;
        dstoff = 8192;
    }

    auto stage = [&](int i, int slot) {
        int kt = 2 * i + sub;
        char* base = (char*)KVring + slot * 32768 + sub * 16384 + dstoff;
        const unsigned short* g0 = (wv < 2)
            ? (Y + rowbase + (size_t)(kt * 32) * YLD)
            : (VtB + kt * 32);
        #pragma unroll
        for (int j = 0; j < 8; ++j)
            load16_lds(g0 + off8[j], base + j * 1024);
    };

    // ---- fragment LDS byte offsets within a 16KB subtile (swizzled) ----
    int kfo[2][4], vfo[8];
    #pragma unroll
    for (int c = 0; c < 2; ++c) {
        int row = c * 16 + cl;
        #pragma unroll
        for (int j = 0; j < 4; ++j)
            kfo[c][j] = (j >> 1) * 4096 + row * 128 +
                        ((((j & 1) * 4 + qd) ^ (row & 7)) << 4);
    }
    #pragma unroll
    for (int ec = 0; ec < 8; ++ec) {
        int e = ec * 16 + cl;
        vfo[ec] = 8192 + e * 64 + ((qd ^ ((e >> 1) & 3)) << 4);
    }

    // P-transform bpermute indices (byte = srclane*4)
    int idxA = ((32 * (qd & 1)) + cl) * 4;
    int idxB = idxA + 64;
    bool loHalf = (qd < 2);

    int qrow = g * 64 + wv * 16;

    stage(0, 0);

    size_t qoff = rowbase + (size_t)(qrow + cl) * YLD;
    bf16x8 q1a = *(const bf16x8*)(Y + qoff + Q1OFF + hq + qd * 8);
    bf16x8 q1b = *(const bf16x8*)(Y + qoff + Q1OFF + hq + 32 + qd * 8);
    bf16x8 q2a = *(const bf16x8*)(Y + qoff + Q2OFF + hq + qd * 8);
    bf16x8 q2b = *(const bf16x8*)(Y + qoff + Q2OFF + hq + 32 + qd * 8);

    f32x4 O1[8], O2[8];
    #pragma unroll
    for (int ec = 0; ec < 8; ++ec) { O1[ec] = zero4; O2[ec] = zero4; }
    float l1s = 0.f, l2s = 0.f;

    // mask + exp + pack + cross-lane gather for one 32-key subtile
    auto transform = [&](f32x4 S1[2], f32x4 S2[2], int kt,
                         bf16x8& pa1o, bf16x8& pa2o) {
        if (kt * 32 + 31 > qrow) {
            #pragma unroll
            for (int c = 0; c < 2; ++c) {
                int lim = qrow + cl - kt * 32 - c * 16 - qd * 4;
                #pragma unroll
                for (int r = 0; r < 4; ++r) {
                    if (r > lim) { S1[c][r] = -1e30f; S2[c][r] = -1e30f; }
                }
            }
        }
        float p1v[2][4], p2v[2][4];
        #pragma unroll
        for (int c = 0; c < 2; ++c) {
            #pragma unroll
            for (int r = 0; r < 4; ++r) {
                p1v[c][r] = fast_exp2(S1[c][r] * EXP2SCALE);
                p2v[c][r] = fast_exp2(S2[c][r] * EXP2SCALE);
                l1s += p1v[c][r];
                l2s += p2v[c][r];
            }
        }
        unsigned int s1m[2][2], s2m[2][2];
        #pragma unroll
        for (int c = 0; c < 2; ++c) {
            s1m[c][0] = pack2bf(p1v[c][0], p1v[c][1]);
            s1m[c][1] = pack2bf(p1v[c][2], p1v[c][3]);
            s2m[c][0] = pack2bf(p2v[c][0], p2v[c][1]);
            s2m[c][1] = pack2bf(p2v[c][2], p2v[c][3]);
        }
        u32x4 U1, U2;
        {
            int a00 = __builtin_amdgcn_ds_bpermute(idxA, (int)s1m[0][0]);
            int a10 = __builtin_amdgcn_ds_bpermute(idxA, (int)s1m[1][0]);
            int a01 = __builtin_amdgcn_ds_bpermute(idxA, (int)s1m[0][1]);
            int a11 = __builtin_amdgcn_ds_bpermute(idxA, (int)s1m[1][1]);
            int b00 = __builtin_amdgcn_ds_bpermute(idxB, (int)s1m[0][0]);
            int b10 = __builtin_amdgcn_ds_bpermute(idxB, (int)s1m[1][0]);
            int b01 = __builtin_amdgcn_ds_bpermute(idxB, (int)s1m[0][1]);
            int b11 = __builtin_amdgcn_ds_bpermute(idxB, (int)s1m[1][1]);
            U1[0] = (unsigned)(loHalf ? a00 : a10);
            U1[1] = (unsigned)(loHalf ? a01 : a11);
            U1[2] = (unsigned)(loHalf ? b00 : b10);
            U1[3] = (unsigned)(loHalf ? b01 : b11);
        }
        {
            int a00 = __builtin_amdgcn_ds_bpermute(idxA, (int)s2m[0][0]);
            int a10 = __builtin_amdgcn_ds_bpermute(idxA, (int)s2m[1][0]);
            int a01 = __builtin_amdgcn_ds_bpermute(idxA, (int)s2m[0][1]);
            int a11 = __builtin_amdgcn_ds_bpermute(idxA, (int)s2m[1][1]);
            int b00 = __builtin_amdgcn_ds_bpermute(idxB, (int)s2m[0][0]);
            int b10 = __builtin_amdgcn_ds_bpermute(idxB, (int)s2m[1][0]);
            int b01 = __builtin_amdgcn_ds_bpermute(idxB, (int)s2m[0][1]);
            int b11 = __builtin_amdgcn_ds_bpermute(idxB, (int)s2m[1][1]);
            U2[0] = (unsigned)(loHalf ? a00 : a10);
            U2[1] = (unsigned)(loHalf ? a01 : a11);
            U2[2] = (unsigned)(loHalf ? b00 : b10);
            U2[3] = (unsigned)(loHalf ? b01 : b11);
        }
        pa1o = __builtin_bit_cast(bf16x8, U1);
        pa2o = __builtin_bit_cast(bf16x8, U2);
    };

    int NI = g + 1;
    for (int i = 0; i < NI; ++i) {
        // own stage(i) loads done, then block-wide visibility via barrier
        asm volatile("s_waitcnt vmcnt(0)\n\ts_barrier" ::: "memory");
        const char* kbA = (const char*)KVring + (i & 1) * 32768;
        const char* kbB = kbA + 16384;
        // prefetch next pair into the other slot (read 2 barriers ago)
        if (i + 1 < NI) stage(i + 1, (i + 1) & 1);

        // K reads (both subtiles) + V-A reads
        bf16x8 kfA[2][4], kfB[2][4];
        #pragma unroll
        for (int c = 0; c < 2; ++c)
            #pragma unroll
            for (int j = 0; j < 4; ++j) {
                kfA[c][j] = *(const bf16x8*)(kbA + kfo[c][j]);
                kfB[c][j] = *(const bf16x8*)(kbB + kfo[c][j]);
            }
        bf16x8 vfA[8];
        #pragma unroll
        for (int ec = 0; ec < 8; ++ec)
            vfA[ec] = *(const bf16x8*)(kbA + vfo[ec]);

        // QK^T (swapped) for both subtiles: 8 independent 2-MFMA chains
        f32x4 S1A[2], S2A[2], S1B[2], S2B[2];
        #pragma unroll
        for (int c = 0; c < 2; ++c) {
            S1A[c] = zero4; S2A[c] = zero4; S1B[c] = zero4; S2B[c] = zero4;
        }
        #pragma unroll
        for (int c = 0; c < 2; ++c) {
            S1A[c] = __builtin_amdgcn_mfma_f32_16x16x32_bf16(kfA[c][0], q1a, S1A[c], 0, 0, 0);
            S1A[c] = __builtin_amdgcn_mfma_f32_16x16x32_bf16(kfA[c][1], q1b, S1A[c], 0, 0, 0);
            S2A[c] = __builtin_amdgcn_mfma_f32_16x16x32_bf16(kfA[c][2], q2a, S2A[c], 0, 0, 0);
            S2A[c] = __builtin_amdgcn_mfma_f32_16x16x32_bf16(kfA[c][3], q2b, S2A[c], 0, 0, 0);
            S1B[c] = __builtin_amdgcn_mfma_f32_16x16x32_bf16(kfB[c][0], q1a, S1B[c], 0, 0, 0);
            S1B[c] = __builtin_amdgcn_mfma_f32_16x16x32_bf16(kfB[c][1], q1b, S1B[c], 0, 0, 0);
            S2B[c] = __builtin_amdgcn_mfma_f32_16x16x32_bf16(kfB[c][2], q2a, S2B[c], 0, 0, 0);
            S2B[c] = __builtin_amdgcn_mfma_f32_16x16x32_bf16(kfB[c][3], q2b, S2B[c], 0, 0, 0);
        }

        bf16x8 pa1A, pa2A, pa1B, pa2B;
        transform(S1A, S2A, 2 * i, pa1A, pa2A);        // bperm-A on DS pipe
        // V-B reads queue BEHIND bperm-A (PV-A not delayed), ahead of bperm-B
        bf16x8 vfB[8];
        #pragma unroll
        for (int ec = 0; ec < 8; ++ec)
            vfB[ec] = *(const bf16x8*)(kbB + vfo[ec]);
        transform(S1B, S2B, 2 * i + 1, pa1B, pa2B);

        #pragma unroll
        for (int ec = 0; ec < 8; ++ec) {
            O1[ec] = __builtin_amdgcn_mfma_f32_16x16x32_bf16(pa1A, vfA[ec], O1[ec], 0, 0, 0);
            O2[ec] = __builtin_amdgcn_mfma_f32_16x16x32_bf16(pa2A, vfA[ec], O2[ec], 0, 0, 0);
        }
        #pragma unroll
        for (int ec = 0; ec < 8; ++ec) {
            O1[ec] = __builtin_amdgcn_mfma_f32_16x16x32_bf16(pa1B, vfB[ec], O1[ec], 0, 0, 0);
            O2[ec] = __builtin_amdgcn_mfma_f32_16x16x32_bf16(pa2B, vfB[ec], O2[ec], 0, 0, 0);
        }
    }

    // l sums: lane holds partial for row cl over its key-groups; reduce
    // across qd groups, then redistribute to output rows qd*4+r.
    l1s += __shfl_xor(l1s, 16); l1s += __shfl_xor(l1s, 32);
    l2s += __shfl_xor(l2s, 16); l2s += __shfl_xor(l2s, 32);
    float w1[4], w2[4];
    #pragma unroll
    for (int r = 0; r < 4; ++r) {
        float d1 = __shfl(l1s, qd * 4 + r);
        float d2 = __shfl(l2s, qd * 4 + r);
        w1[r] = 1.0f / d1;
        w2[r] = lamv / d2;
    }
    #pragma unroll
    for (int ec = 0; ec < 8; ++ec) {
        #pragma unroll
        for (int r = 0; r < 4; ++r) {
            size_t row = (size_t)(b * Tc + qrow + qd * 4 + r);
            attn[row * HVD + h * VDc + ec * 16 + cl] =
                f2bf(O1[ec][r] * w1[r] - O2[ec][r] * w2[r]);
        }
    }
}

// ---------------------------------------------------------------------------
// Fused row-stats + LayerNorm*0.2, in-place on bf16 attn. 128 thr/row.
// ---------------------------------------------------------------------------
__global__ __launch_bounds__(128) void ln_inplace(
    unsigned short* __restrict__ attn,
    const float* __restrict__ gnw, const float* __restrict__ gnb)
{
    int row = blockIdx.x, tid = threadIdx.x;
    unsigned short* p = attn + (size_t)row * HVD;
    float v[12];
    float s = 0.f, sq = 0.f;
    #pragma unroll
    for (int j = 0; j < 3; ++j) {
        int g = tid + j * 128;
        ushort4 u = *(const ushort4*)(p + g * 4);
        float x0 = bf2f(u.x), x1 = bf2f(u.y), x2 = bf2f(u.z), x3 = bf2f(u.w);
        v[j * 4 + 0] = x0; v[j * 4 + 1] = x1; v[j * 4 + 2] = x2; v[j * 4 + 3] = x3;
        s += x0 + x1 + x2 + x3;
        sq = fmaf(x0, x0, sq); sq = fmaf(x1, x1, sq);
        sq = fmaf(x2, x2, sq); sq = fmaf(x3, x3, sq);
    }
    #pragma unroll
    for (int off = 32; off; off >>= 1) { s += __shfl_xor(s, off); sq += __shfl_xor(sq, off); }
    __shared__ float ss[2], sqs[2];
    if ((tid & 63) == 0) { ss[tid >> 6] = s; sqs[tid >> 6] = sq; }
    __syncthreads();
    float S = ss[0] + ss[1], Q = sqs[0] + sqs[1];
    float mu = S * (1.0f / HVD);
    float rstd = rsqrtf(Q * (1.0f / HVD) - mu * mu + 1e-5f);
    #pragma unroll
    for (int j = 0; j < 3; ++j) {
        int g = tid + j * 128;
        float4 gw = *(const float4*)(gnw + g * 4);
        float4 gb = *(const float4*)(gnb + g * 4);
        ushort4 o;
        o.x = f2bf(((v[j * 4 + 0] - mu) * rstd * gw.x + gb.x) * 0.2f);
        o.y = f2bf(((v[j * 4 + 1] - mu) * rstd * gw.y + gb.y) * 0.2f);
        o.z = f2bf(((v[j * 4 + 2] - mu) * rstd * gw.z + gb.z) * 0.2f);
        o.w = f2bf(((v[j * 4 + 3] - mu) * rstd * gw.w + gb.w) * 0.2f);
        *(ushort4*)(p + g * 4) = o;
    }
}

// ---------------------------------------------------------------------------
// launch
// ---------------------------------------------------------------------------
extern "C" void kernel_launch(void* const* d_in, const int* in_sizes, int n_in,
                              void* d_out, int out_size, void* d_ws, size_t ws_size,
                              hipStream_t stream)
{
    const float* x   = (const float*)d_in[0];
    const float* Wq1 = (const float*)d_in[1];
    const float* Wk1 = (const float*)d_in[2];
    const float* Wq2 = (const float*)d_in[3];
    const float* Wk2 = (const float*)d_in[4];
    const float* Wv  = (const float*)d_in[5];
    const float* lq1 = (const float*)d_in[6];
    const float* lk1 = (const float*)d_in[7];
    const float* lq2 = (const float*)d_in[8];
    const float* lk2 = (const float*)d_in[9];
    const float* gnw = (const float*)d_in[10];
    const float* gnb = (const float*)d_in[11];
    const float* Wp  = (const float*)d_in[12];
    const float* bp  = (const float*)d_in[13];
    const int*   lidx = (const int*)d_in[14];
    float* out = (float*)d_out;

    // workspace layout (bytes):
    // WcatT bf16 [4608][768]:  7,077,888 @ 0
    // Xb    bf16 [4096][768]:  6,291,456 @ 7,077,888
    // Y     bf16 [4096][3072]: 25,165,824 @ 13,369,344
    // Vt    bf16 [48][128][1024]: 12,582,912 @ 38,535,168
    // attn  bf16 [4096][1536]: 12,582,912 @ 51,118,080
    // Wpb   bf16 [768][1536]:   2,359,296 @ 63,700,992
    // lam   f32 [12]                       @ 66,060,288
    char* w = (char*)d_ws;
    unsigned short* WcatT = (unsigned short*)(w);
    unsigned short* Xb    = (unsigned short*)(w + 7077888);
    unsigned short* Y     = (unsigned short*)(w + 13369344);
    unsigned short* VtW   = (unsigned short*)(w + 38535168);
    unsigned short* attn  = (unsigned short*)(w + 51118080);
    unsigned short* Wpb   = (unsigned short*)(w + 63700992);
    float* lam            = (float*)(w + 66060288);

    cast_bf16<<<dim3(NROWS * Cc / 1024), 256, 0, stream>>>(x, Xb);
    cast_bf16<<<dim3(Cc * HVD / 1024), 256, 0, stream>>>(Wp, Wpb);
    trans_w<<<dim3(72 * 12), 256, 0, stream>>>(Wq1, Wk1, Wq2, Wk2, Wv, WcatT);
    lambda_kernel<<<dim3(Hc), 64, 0, stream>>>(lq1, lk1, lq2, lk2, lidx, lam);
    // QKV: [4096,768] x [768,4608]; Q/K -> Y (LD 3072), V -> Vt transposed
    gemm_mfma<4, 768, YLD, false, true><<<dim3(NQKV / 128, NROWS / 128), 256, 0, stream>>>(
        Xb, WcatT, Y, nullptr, nullptr, VtW);
    // bh fastest (XCD pin); y -> g = 15-y, longest-first; 768 blocks x 4 waves,
    // 64 Q-rows per block, 64-key iterations, 2-slot 64KB ring (2 blocks/CU ->
    // 256-block LPT backfill queue)
    diff_attn_mfma<<<dim3(Bc * Hc, 16), 256, 0, stream>>>(Y, VtW, lam, attn);
    ln_inplace<<<dim3(NROWS), 128, 0, stream>>>(attn, gnw, gnb);
    // OUT: [4096,1536] x [1536,768] -> out fp32 (+bias)
    gemm_mfma<2, HVD, Cc, true, false><<<dim3(Cc / 64, NROWS / 128), 256, 0, stream>>>(
        attn, Wpb, nullptr, out, bp, nullptr);
}

// Round 8
// 240.459 us; speedup vs baseline: 2.0068x; 1.0433x over previous
//
#include <hip/hip_runtime.h>
#include <hip/hip_bf16.h>

// Problem constants
#define Bc   4
#define Tc   1024
#define Cc   768
#define Hc   12
#define HSc  64
#define VDc  128
#define NQKV 4608   // gemm N for qkv (4*768 Q/K + 1536 V)
#define YLD  3072   // Y row stride: Q/K only (V goes to Vt)
#define NROWS 4096  // B*T
#define HVD  1536   // H*VD

// Y (qk) column offsets
#define Q1OFF 0
#define K1OFF 768
#define Q2OFF 1536
#define K2OFF 2304

typedef __bf16 bf16x8 __attribute__((ext_vector_type(8)));
typedef float f32x4 __attribute__((ext_vector_type(4)));
typedef unsigned int u32x4 __attribute__((ext_vector_type(4)));

// exp(s*0.125) == exp2(s * 0.125*log2(e))
#define EXP2SCALE 0.18033688011112042f

static __device__ __forceinline__ float bf2f(unsigned short s) {
    return __uint_as_float(((unsigned int)s) << 16);
}
static __device__ __forceinline__ unsigned short f2bf(float f) {
    unsigned int u = __float_as_uint(f);
    unsigned int r = (u + 0x7FFFu + ((u >> 16) & 1u)) >> 16;  // round-nearest-even
    return (unsigned short)r;
}
static __device__ __forceinline__ unsigned int pack2bf(float lo, float hi) {
    // bf16(lo) | bf16(hi)<<16, half-up rounding (values >= 0)
    unsigned int a = (__float_as_uint(lo) + 0x8000u) >> 16;
    unsigned int b = (__float_as_uint(hi) + 0x8000u) & 0xFFFF0000u;
    return a | b;
}
// raw v_exp_f32: 2^x without libm denorm guards (inputs bounded here)
static __device__ __forceinline__ float fast_exp2(float x) {
    float r;
    asm("v_exp_f32 %0, %1" : "=v"(r) : "v"(x));
    return r;
}

// async global->LDS 16B per lane; lds base must be wave-uniform
static __device__ __forceinline__ void load16_lds(const void* g, void* l) {
    __builtin_amdgcn_global_load_lds(
        (const __attribute__((address_space(1))) void*)g,
        (__attribute__((address_space(3))) void*)l, 16, 0, 0);
}

// ---------------------------------------------------------------------------
// cast fp32 -> bf16, 4 elts/thread
// ---------------------------------------------------------------------------
__global__ __launch_bounds__(256) void cast_bf16(
    const float* __restrict__ src, unsigned short* __restrict__ dst)
{
    int i = blockIdx.x * 256 + threadIdx.x;
    float4 v = *(const float4*)(src + (size_t)i * 4);
    ushort4 u;
    u.x = f2bf(v.x); u.y = f2bf(v.y); u.z = f2bf(v.z); u.w = f2bf(v.w);
    *(ushort4*)(dst + (size_t)i * 4) = u;
}

// ---------------------------------------------------------------------------
// Transpose-repack the 5 projection weights into WcatT[n][k] bf16, k-contig.
// ---------------------------------------------------------------------------
__global__ __launch_bounds__(256) void trans_w(
    const float* __restrict__ Wq1, const float* __restrict__ Wk1,
    const float* __restrict__ Wq2, const float* __restrict__ Wk2,
    const float* __restrict__ Wv, unsigned short* __restrict__ WcatT)
{
    __shared__ float tile[64][65];
    int tid = threadIdx.x;
    int t = blockIdx.x;
    int kt = t % 12, nt = t / 12;
    int k0 = kt * 64, n0 = nt * 64;
    const float* src;
    int stride;
    if (n0 < 3072) {
        int which = n0 / 768, m = n0 - which * 768, h = m >> 6;
        const float* W = (which == 0) ? Wq1 : (which == 1) ? Wk1 : (which == 2) ? Wq2 : Wk2;
        src = W + ((size_t)h * 768 + k0) * 64;
        stride = 64;
    } else {
        int rel = n0 - 3072, h = rel >> 7, e0 = rel & 127;
        src = Wv + ((size_t)h * 768 + k0) * 128 + e0;
        stride = 128;
    }
    for (int i = tid; i < 4096; i += 256) {
        int kl = i >> 6, dl = i & 63;
        tile[dl][kl] = src[(size_t)kl * stride + dl];
    }
    __syncthreads();
    for (int i = tid; i < 4096; i += 256) {
        int nl = i >> 6, kl = i & 63;
        WcatT[(size_t)(n0 + nl) * 768 + k0 + kl] = f2bf(tile[nl][kl]);
    }
}

// ---------------------------------------------------------------------------
// lambda per head
// ---------------------------------------------------------------------------
__global__ __launch_bounds__(64) void lambda_kernel(
    const float* __restrict__ lq1, const float* __restrict__ lk1,
    const float* __restrict__ lq2, const float* __restrict__ lk2,
    const int* __restrict__ layer_idx, float* __restrict__ lam)
{
    int h = blockIdx.x, l = threadIdx.x;
    float li = (float)layer_idx[0];
    float dyn = 0.8f - 0.6f * expf(-0.3f * (li - 1.0f));
    int i = h * HSc + l;
    float v = expf(lq1[i] * lk1[i]) - expf(lq2[i] * lk2[i]) + dyn;
    #pragma unroll
    for (int off = 32; off; off >>= 1) v += __shfl_xor(v, off);
    if (l == 0) lam[h] = v * (1.0f / 64.0f);
}

// ---------------------------------------------------------------------------
// MFMA GEMM — R16: BK=64 (two 32-K halves per barrier pair). The m97-style
// 2-barriers-per-32-K-step loop pays a full vmcnt(0)+lgkmcnt(0) drain per
// barrier; at K=768/1536 (24/48 steps) these drains dominate the per-block
// cost. BK=64 halves the barrier count at identical load/ds_read/MFMA
// counts and identical accumulation order (bit-identical output).
// LDS: As 16KB + Bs 8*TN KB (TN=4: 32KB, TN=2: 24KB).
// SPLITV: cols >= 3072 (V projection) -> written transposed to VtOut.
// ---------------------------------------------------------------------------
template<int TN, int KD, int LDC, bool OUT_BIAS, bool SPLITV>
__global__ __launch_bounds__(256) void gemm_mfma(
    const unsigned short* __restrict__ A, const unsigned short* __restrict__ Bt,
    unsigned short* __restrict__ Cb, float* __restrict__ Cf,
    const float* __restrict__ bias, unsigned short* __restrict__ VtOut)
{
    constexpr int BN = TN * 32;
    constexpr int JB = TN / 2;
    __shared__ unsigned short As[128 * 64];
    __shared__ unsigned short Bs[BN * 64];
    int tid = threadIdx.x, lane = tid & 63, w = tid >> 6;
    int wm = w >> 1, wn = w & 1;
    int m0 = blockIdx.y * 128, n0 = blockIdx.x * BN;

    int lr = lane >> 2, lq = lane & 3;
    const unsigned short* gA[2];
    const unsigned short* gB[JB];
    #pragma unroll
    for (int j = 0; j < 2; ++j) {
        int row = w * 32 + j * 16 + lr;
        int qg = lq ^ ((row >> 1) & 3);
        gA[j] = A + (size_t)(m0 + row) * KD + qg * 8;
    }
    #pragma unroll
    for (int j = 0; j < JB; ++j) {
        int row = w * (JB * 16) + j * 16 + lr;
        int qg = lq ^ ((row >> 1) & 3);
        gB[j] = Bt + (size_t)(n0 + row) * KD + qg * 8;
    }

    int rr = lane & 15, qd = lane >> 4;
    const unsigned short* aAddr[4];
    const unsigned short* bAddr[TN];
    #pragma unroll
    for (int i = 0; i < 4; ++i) {
        int row = wm * 64 + i * 16 + rr;
        int qs = qd ^ ((row >> 1) & 3);
        aAddr[i] = As + row * 32 + qs * 8;
    }
    #pragma unroll
    for (int t = 0; t < TN; ++t) {
        int row = wn * (TN * 16) + t * 16 + rr;
        int qs = qd ^ ((row >> 1) & 3);
        bAddr[t] = Bs + row * 32 + qs * 8;
    }

    f32x4 acc[4][TN];
    #pragma unroll
    for (int i = 0; i < 4; ++i)
        #pragma unroll
        for (int t = 0; t < TN; ++t) acc[i][t] = {0.f, 0.f, 0.f, 0.f};

    for (int k = 0; k < KD / 64; ++k) {
        __syncthreads();
        // half 0 (cols k*64 .. +31)
        load16_lds(gA[0], As + (w * 2 + 0) * 512);
        load16_lds(gA[1], As + (w * 2 + 1) * 512);
        // half 1 (cols k*64+32 .. +63) into the second 4K-ushort bank
        load16_lds(gA[0] + 32, As + 4096 + (w * 2 + 0) * 512);
        load16_lds(gA[1] + 32, As + 4096 + (w * 2 + 1) * 512);
        #pragma unroll
        for (int j = 0; j < JB; ++j) {
            load16_lds(gB[j], Bs + (w * JB + j) * 512);
            load16_lds(gB[j] + 32, Bs + BN * 32 + (w * JB + j) * 512);
        }
        gA[0] += 64; gA[1] += 64;
        #pragma unroll
        for (int j = 0; j < JB; ++j) gB[j] += 64;
        __syncthreads();

        bf16x8 af0[4], af1[4], bf0[TN], bf1[TN];
        #pragma unroll
        for (int i = 0; i < 4; ++i) {
            af0[i] = *(const bf16x8*)aAddr[i];
            af1[i] = *(const bf16x8*)(aAddr[i] + 4096);
        }
        #pragma unroll
        for (int t = 0; t < TN; ++t) {
            bf0[t] = *(const bf16x8*)bAddr[t];
            bf1[t] = *(const bf16x8*)(bAddr[t] + BN * 32);
        }
        #pragma unroll
        for (int i = 0; i < 4; ++i)
            #pragma unroll
            for (int t = 0; t < TN; ++t) {
                acc[i][t] = __builtin_amdgcn_mfma_f32_16x16x32_bf16(af0[i], bf0[t], acc[i][t], 0, 0, 0);
                acc[i][t] = __builtin_amdgcn_mfma_f32_16x16x32_bf16(af1[i], bf1[t], acc[i][t], 0, 0, 0);
            }
    }

    #pragma unroll
    for (int t = 0; t < TN; ++t) {
        int col = n0 + wn * (TN * 16) + t * 16 + rr;
        if (SPLITV && col >= 3072) {
            int rel = col - 3072, hh = rel >> 7, e = rel & 127;
            #pragma unroll
            for (int i = 0; i < 4; ++i) {
                int row0 = m0 + wm * 64 + i * 16 + qd * 4;
                int b = row0 >> 10, tt = row0 & 1023;
                ushort4 pk;
                pk.x = f2bf(acc[i][t][0]); pk.y = f2bf(acc[i][t][1]);
                pk.z = f2bf(acc[i][t][2]); pk.w = f2bf(acc[i][t][3]);
                *(ushort4*)&VtOut[(size_t)((b * Hc + hh) * 128 + e) * 1024 + tt] = pk;
            }
        } else {
            float bv = OUT_BIAS ? bias[col] : 0.f;
            #pragma unroll
            for (int i = 0; i < 4; ++i) {
                #pragma unroll
                for (int r = 0; r < 4; ++r) {
                    int row = m0 + wm * 64 + i * 16 + qd * 4 + r;
                    if (OUT_BIAS)
                        Cf[(size_t)row * LDC + col] = acc[i][t][r] + bv;
                    else
                        Cb[(size_t)row * LDC + col] = f2bf(acc[i][t][r]);
                }
            }
        }
    }
}

// ---------------------------------------------------------------------------
// MFMA differential flash attention — R15 (frozen): 64-key iterations,
// swapped QK^T + bpermute P-transform, 2-slot 64KB ring, counted barriers,
// LPT backfill. Measured 61.6 us, MfmaUtil 12.3%.
// ---------------------------------------------------------------------------
__global__ __launch_bounds__(256) void diff_attn_mfma(
    const unsigned short* __restrict__ Y, const unsigned short* __restrict__ Vt,
    const float* __restrict__ lam_buf, unsigned short* __restrict__ attn)
{
    __shared__ __align__(16) unsigned short KVring[2 * 16384];  // 64 KB

    int bh = blockIdx.x;                          // fastest dim -> XCD-pinned
    int b = bh / Hc, h = bh - b * Hc;
    int g = 15 - (int)blockIdx.y;                 // longest first
    int tid = threadIdx.x, lane = tid & 63, wv = tid >> 6;
    int cl = lane & 15, qd = lane >> 4;
    float lamv = lam_buf[h];
    size_t rowbase = (size_t)(b * Tc) * YLD;
    const int hq = h * HSc;
    const unsigned short* VtB = Vt + ((size_t)bh << 17);   // bh*128*1024
    const f32x4 zero4 = {0.f, 0.f, 0.f, 0.f};

    // ---- staging lane->global mapping (one 8-load set per wave) ----
    // wave0: K1+K2 of subtile A; wave1: K1+K2 of B; wave2: V of A; wave3: V of B
    int sub = wv & 1;
    int off8[8];
    int dstoff;
    if (wv < 2) {
        int ksrow = lane >> 3;                  // row within 8-row seg
        int ksch  = (lane & 7) ^ ksrow;         // stored global chunk (inv swizzle)
        #pragma unroll
        for (int j = 0; j < 8; ++j) {
            int moff = (j < 4) ? K1OFF : K2OFF;
            off8[j] = ((j & 3) * 8 + ksrow) * YLD + moff + hq + ksch * 8;
        }
        dstoff = 0;
    } else {
        int vsel = lane >> 2;                   // e within 16-row seg
        int vsch = (lane & 3) ^ ((vsel >> 1) & 3);
        #pragma unroll
        for (int s = 0; s < 8; ++s)
            off8[s] = (s * 16 + vsel) * 1024 + vsch * 8;
        dstoff = 8192;
    }

    auto stage = [&](int i, int slot) {
        int kt = 2 * i + sub;
        char* base = (char*)KVring + slot * 32768 + sub * 16384 + dstoff;
        const unsigned short* g0 = (wv < 2)
            ? (Y + rowbase + (size_t)(kt * 32) * YLD)
            : (VtB + kt * 32);
        #pragma unroll
        for (int j = 0; j < 8; ++j)
            load16_lds(g0 + off8[j], base + j * 1024);
    };

    // ---- fragment LDS byte offsets within a 16KB subtile (swizzled) ----
    int kfo[2][4], vfo[8];
    #pragma unroll
    for (int c = 0; c < 2; ++c) {
        int row = c * 16 + cl;
        #pragma unroll
        for (int j = 0; j < 4; ++j)
            kfo[c][j] = (j >> 1) * 4096 + row * 128 +
                        ((((j & 1) * 4 + qd) ^ (row & 7)) << 4);
    }
    #pragma unroll
    for (int ec = 0; ec < 8; ++ec) {
        int e = ec * 16 + cl;
        vfo[ec] = 8192 + e * 64 + ((qd ^ ((e >> 1) & 3)) << 4);
    }

    // P-transform bpermute indices (byte = srclane*4)
    int idxA = ((32 * (qd & 1)) + cl) * 4;
    int idxB = idxA + 64;
    bool loHalf = (qd < 2);

    int qrow = g * 64 + wv * 16;

    stage(0, 0);

    size_t qoff = rowbase + (size_t)(qrow + cl) * YLD;
    bf16x8 q1a = *(const bf16x8*)(Y + qoff + Q1OFF + hq + qd * 8);
    bf16x8 q1b = *(const bf16x8*)(Y + qoff + Q1OFF + hq + 32 + qd * 8);
    bf16x8 q2a = *(const bf16x8*)(Y + qoff + Q2OFF + hq + qd * 8);
    bf16x8 q2b = *(const bf16x8*)(Y + qoff + Q2OFF + hq + 32 + qd * 8);

    f32x4 O1[8], O2[8];
    #pragma unroll
    for (int ec = 0; ec < 8; ++ec) { O1[ec] = zero4; O2[ec] = zero4; }
    float l1s = 0.f, l2s = 0.f;

    // mask + exp + pack + cross-lane gather for one 32-key subtile
    auto transform = [&](f32x4 S1[2], f32x4 S2[2], int kt,
                         bf16x8& pa1o, bf16x8& pa2o) {
        if (kt * 32 + 31 > qrow) {
            #pragma unroll
            for (int c = 0; c < 2; ++c) {
                int lim = qrow + cl - kt * 32 - c * 16 - qd * 4;
                #pragma unroll
                for (int r = 0; r < 4; ++r) {
                    if (r > lim) { S1[c][r] = -1e30f; S2[c][r] = -1e30f; }
                }
            }
        }
        float p1v[2][4], p2v[2][4];
        #pragma unroll
        for (int c = 0; c < 2; ++c) {
            #pragma unroll
            for (int r = 0; r < 4; ++r) {
                p1v[c][r] = fast_exp2(S1[c][r] * EXP2SCALE);
                p2v[c][r] = fast_exp2(S2[c][r] * EXP2SCALE);
                l1s += p1v[c][r];
                l2s += p2v[c][r];
            }
        }
        unsigned int s1m[2][2], s2m[2][2];
        #pragma unroll
        for (int c = 0; c < 2; ++c) {
            s1m[c][0] = pack2bf(p1v[c][0], p1v[c][1]);
            s1m[c][1] = pack2bf(p1v[c][2], p1v[c][3]);
            s2m[c][0] = pack2bf(p2v[c][0], p2v[c][1]);
            s2m[c][1] = pack2bf(p2v[c][2], p2v[c][3]);
        }
        u32x4 U1, U2;
        {
            int a00 = __builtin_amdgcn_ds_bpermute(idxA, (int)s1m[0][0]);
            int a10 = __builtin_amdgcn_ds_bpermute(idxA, (int)s1m[1][0]);
            int a01 = __builtin_amdgcn_ds_bpermute(idxA, (int)s1m[0][1]);
            int a11 = __builtin_amdgcn_ds_bpermute(idxA, (int)s1m[1][1]);
            int b00 = __builtin_amdgcn_ds_bpermute(idxB, (int)s1m[0][0]);
            int b10 = __builtin_amdgcn_ds_bpermute(idxB, (int)s1m[1][0]);
            int b01 = __builtin_amdgcn_ds_bpermute(idxB, (int)s1m[0][1]);
            int b11 = __builtin_amdgcn_ds_bpermute(idxB, (int)s1m[1][1]);
            U1[0] = (unsigned)(loHalf ? a00 : a10);
            U1[1] = (unsigned)(loHalf ? a01 : a11);
            U1[2] = (unsigned)(loHalf ? b00 : b10);
            U1[3] = (unsigned)(loHalf ? b01 : b11);
        }
        {
            int a00 = __builtin_amdgcn_ds_bpermute(idxA, (int)s2m[0][0]);
            int a10 = __builtin_amdgcn_ds_bpermute(idxA, (int)s2m[1][0]);
            int a01 = __builtin_amdgcn_ds_bpermute(idxA, (int)s2m[0][1]);
            int a11 = __builtin_amdgcn_ds_bpermute(idxA, (int)s2m[1][1]);
            int b00 = __builtin_amdgcn_ds_bpermute(idxB, (int)s2m[0][0]);
            int b10 = __builtin_amdgcn_ds_bpermute(idxB, (int)s2m[1][0]);
            int b01 = __builtin_amdgcn_ds_bpermute(idxB, (int)s2m[0][1]);
            int b11 = __builtin_amdgcn_ds_bpermute(idxB, (int)s2m[1][1]);
            U2[0] = (unsigned)(loHalf ? a00 : a10);
            U2[1] = (unsigned)(loHalf ? a01 : a11);
            U2[2] = (unsigned)(loHalf ? b00 : b10);
            U2[3] = (unsigned)(loHalf ? b01 : b11);
        }
        pa1o = __builtin_bit_cast(bf16x8, U1);
        pa2o = __builtin_bit_cast(bf16x8, U2);
    };

    int NI = g + 1;
    for (int i = 0; i < NI; ++i) {
        // own stage(i) loads done, then block-wide visibility via barrier
        asm volatile("s_waitcnt vmcnt(0)\n\ts_barrier" ::: "memory");
        const char* kbA = (const char*)KVring + (i & 1) * 32768;
        const char* kbB = kbA + 16384;
        // prefetch next pair into the other slot (read 2 barriers ago)
        if (i + 1 < NI) stage(i + 1, (i + 1) & 1);

        // K reads (both subtiles) + V-A reads
        bf16x8 kfA[2][4], kfB[2][4];
        #pragma unroll
        for (int c = 0; c < 2; ++c)
            #pragma unroll
            for (int j = 0; j < 4; ++j) {
                kfA[c][j] = *(const bf16x8*)(kbA + kfo[c][j]);
                kfB[c][j] = *(const bf16x8*)(kbB + kfo[c][j]);
            }
        bf16x8 vfA[8];
        #pragma unroll
        for (int ec = 0; ec < 8; ++ec)
            vfA[ec] = *(const bf16x8*)(kbA + vfo[ec]);

        // QK^T (swapped) for both subtiles: 8 independent 2-MFMA chains
        f32x4 S1A[2], S2A[2], S1B[2], S2B[2];
        #pragma unroll
        for (int c = 0; c < 2; ++c) {
            S1A[c] = zero4; S2A[c] = zero4; S1B[c] = zero4; S2B[c] = zero4;
        }
        #pragma unroll
        for (int c = 0; c < 2; ++c) {
            S1A[c] = __builtin_amdgcn_mfma_f32_16x16x32_bf16(kfA[c][0], q1a, S1A[c], 0, 0, 0);
            S1A[c] = __builtin_amdgcn_mfma_f32_16x16x32_bf16(kfA[c][1], q1b, S1A[c], 0, 0, 0);
            S2A[c] = __builtin_amdgcn_mfma_f32_16x16x32_bf16(kfA[c][2], q2a, S2A[c], 0, 0, 0);
            S2A[c] = __builtin_amdgcn_mfma_f32_16x16x32_bf16(kfA[c][3], q2b, S2A[c], 0, 0, 0);
            S1B[c] = __builtin_amdgcn_mfma_f32_16x16x32_bf16(kfB[c][0], q1a, S1B[c], 0, 0, 0);
            S1B[c] = __builtin_amdgcn_mfma_f32_16x16x32_bf16(kfB[c][1], q1b, S1B[c], 0, 0, 0);
            S2B[c] = __builtin_amdgcn_mfma_f32_16x16x32_bf16(kfB[c][2], q2a, S2B[c], 0, 0, 0);
            S2B[c] = __builtin_amdgcn_mfma_f32_16x16x32_bf16(kfB[c][3], q2b, S2B[c], 0, 0, 0);
        }

        bf16x8 pa1A, pa2A, pa1B, pa2B;
        transform(S1A, S2A, 2 * i, pa1A, pa2A);        // bperm-A on DS pipe
        // V-B reads queue BEHIND bperm-A (PV-A not delayed), ahead of bperm-B
        bf16x8 vfB[8];
        #pragma unroll
        for (int ec = 0; ec < 8; ++ec)
            vfB[ec] = *(const bf16x8*)(kbB + vfo[ec]);
        transform(S1B, S2B, 2 * i + 1, pa1B, pa2B);

        #pragma unroll
        for (int ec = 0; ec < 8; ++ec) {
            O1[ec] = __builtin_amdgcn_mfma_f32_16x16x32_bf16(pa1A, vfA[ec], O1[ec], 0, 0, 0);
            O2[ec] = __builtin_amdgcn_mfma_f32_16x16x32_bf16(pa2A, vfA[ec], O2[ec], 0, 0, 0);
        }
        #pragma unroll
        for (int ec = 0; ec < 8; ++ec) {
            O1[ec] = __builtin_amdgcn_mfma_f32_16x16x32_bf16(pa1B, vfB[ec], O1[ec], 0, 0, 0);
            O2[ec] = __builtin_amdgcn_mfma_f32_16x16x32_bf16(pa2B, vfB[ec], O2[ec], 0, 0, 0);
        }
    }

    // l sums: lane holds partial for row cl over its key-groups; reduce
    // across qd groups, then redistribute to output rows qd*4+r.
    l1s += __shfl_xor(l1s, 16); l1s += __shfl_xor(l1s, 32);
    l2s += __shfl_xor(l2s, 16); l2s += __shfl_xor(l2s, 32);
    float w1[4], w2[4];
    #pragma unroll
    for (int r = 0; r < 4; ++r) {
        float d1 = __shfl(l1s, qd * 4 + r);
        float d2 = __shfl(l2s, qd * 4 + r);
        w1[r] = 1.0f / d1;
        w2[r] = lamv / d2;
    }
    #pragma unroll
    for (int ec = 0; ec < 8; ++ec) {
        #pragma unroll
        for (int r = 0; r < 4; ++r) {
            size_t row = (size_t)(b * Tc + qrow + qd * 4 + r);
            attn[row * HVD + h * VDc + ec * 16 + cl] =
                f2bf(O1[ec][r] * w1[r] - O2[ec][r] * w2[r]);
        }
    }
}

// ---------------------------------------------------------------------------
// Fused row-stats + LayerNorm*0.2, in-place on bf16 attn. 128 thr/row.
// ---------------------------------------------------------------------------
__global__ __launch_bounds__(128) void ln_inplace(
    unsigned short* __restrict__ attn,
    const float* __restrict__ gnw, const float* __restrict__ gnb)
{
    int row = blockIdx.x, tid = threadIdx.x;
    unsigned short* p = attn + (size_t)row * HVD;
    float v[12];
    float s = 0.f, sq = 0.f;
    #pragma unroll
    for (int j = 0; j < 3; ++j) {
        int g = tid + j * 128;
        ushort4 u = *(const ushort4*)(p + g * 4);
        float x0 = bf2f(u.x), x1 = bf2f(u.y), x2 = bf2f(u.z), x3 = bf2f(u.w);
        v[j * 4 + 0] = x0; v[j * 4 + 1] = x1; v[j * 4 + 2] = x2; v[j * 4 + 3] = x3;
        s += x0 + x1 + x2 + x3;
        sq = fmaf(x0, x0, sq); sq = fmaf(x1, x1, sq);
        sq = fmaf(x2, x2, sq); sq = fmaf(x3, x3, sq);
    }
    #pragma unroll
    for (int off = 32; off; off >>= 1) { s += __shfl_xor(s, off); sq += __shfl_xor(sq, off); }
    __shared__ float ss[2], sqs[2];
    if ((tid & 63) == 0) { ss[tid >> 6] = s; sqs[tid >> 6] = sq; }
    __syncthreads();
    float S = ss[0] + ss[1], Q = sqs[0] + sqs[1];
    float mu = S * (1.0f / HVD);
    float rstd = rsqrtf(Q * (1.0f / HVD) - mu * mu + 1e-5f);
    #pragma unroll
    for (int j = 0; j < 3; ++j) {
        int g = tid + j * 128;
        float4 gw = *(const float4*)(gnw + g * 4);
        float4 gb = *(const float4*)(gnb + g * 4);
        ushort4 o;
        o.x = f2bf(((v[j * 4 + 0] - mu) * rstd * gw.x + gb.x) * 0.2f);
        o.y = f2bf(((v[j * 4 + 1] - mu) * rstd * gw.y + gb.y) * 0.2f);
        o.z = f2bf(((v[j * 4 + 2] - mu) * rstd * gw.z + gb.z) * 0.2f);
        o.w = f2bf(((v[j * 4 + 3] - mu) * rstd * gw.w + gb.w) * 0.2f);
        *(ushort4*)(p + g * 4) = o;
    }
}

// ---------------------------------------------------------------------------
// launch
// ---------------------------------------------------------------------------
extern "C" void kernel_launch(void* const* d_in, const int* in_sizes, int n_in,
                              void* d_out, int out_size, void* d_ws, size_t ws_size,
                              hipStream_t stream)
{
    const float* x   = (const float*)d_in[0];
    const float* Wq1 = (const float*)d_in[1];
    const float* Wk1 = (const float*)d_in[2];
    const float* Wq2 = (const float*)d_in[3];
    const float* Wk2 = (const float*)d_in[4];
    const float* Wv  = (const float*)d_in[5];
    const float* lq1 = (const float*)d_in[6];
    const float* lk1 = (const float*)d_in[7];
    const float* lq2 = (const float*)d_in[8];
    const float* lk2 = (const float*)d_in[9];
    const float* gnw = (const float*)d_in[10];
    const float* gnb = (const float*)d_in[11];
    const float* Wp  = (const float*)d_in[12];
    const float* bp  = (const float*)d_in[13];
    const int*   lidx = (const int*)d_in[14];
    float* out = (float*)d_out;

    // workspace layout (bytes):
    // WcatT bf16 [4608][768]:  7,077,888 @ 0
    // Xb    bf16 [4096][768]:  6,291,456 @ 7,077,888
    // Y     bf16 [4096][3072]: 25,165,824 @ 13,369,344
    // Vt    bf16 [48][128][1024]: 12,582,912 @ 38,535,168
    // attn  bf16 [4096][1536]: 12,582,912 @ 51,118,080
    // Wpb   bf16 [768][1536]:   2,359,296 @ 63,700,992
    // lam   f32 [12]                       @ 66,060,288
    char* w = (char*)d_ws;
    unsigned short* WcatT = (unsigned short*)(w);
    unsigned short* Xb    = (unsigned short*)(w + 7077888);
    unsigned short* Y     = (unsigned short*)(w + 13369344);
    unsigned short* VtW   = (unsigned short*)(w + 38535168);
    unsigned short* attn  = (unsigned short*)(w + 51118080);
    unsigned short* Wpb   = (unsigned short*)(w + 63700992);
    float* lam            = (float*)(w + 66060288);

    cast_bf16<<<dim3(NROWS * Cc / 1024), 256, 0, stream>>>(x, Xb);
    cast_bf16<<<dim3(Cc * HVD / 1024), 256, 0, stream>>>(Wp, Wpb);
    trans_w<<<dim3(72 * 12), 256, 0, stream>>>(Wq1, Wk1, Wq2, Wk2, Wv, WcatT);
    lambda_kernel<<<dim3(Hc), 64, 0, stream>>>(lq1, lk1, lq2, lk2, lidx, lam);
    // QKV: [4096,768] x [768,4608]; Q/K -> Y (LD 3072), V -> Vt transposed
    gemm_mfma<4, 768, YLD, false, true><<<dim3(NQKV / 128, NROWS / 128), 256, 0, stream>>>(
        Xb, WcatT, Y, nullptr, nullptr, VtW);
    // bh fastest (XCD pin); y -> g = 15-y, longest-first; 768 blocks x 4 waves,
    // 64 Q-rows per block, 64-key iterations, 2-slot 64KB ring (2 blocks/CU ->
    // 256-block LPT backfill queue)
    diff_attn_mfma<<<dim3(Bc * Hc, 16), 256, 0, stream>>>(Y, VtW, lam, attn);
    ln_inplace<<<dim3(NROWS), 128, 0, stream>>>(attn, gnw, gnb);
    // OUT: [4096,1536] x [1536,768] -> out fp32 (+bias)
    gemm_mfma<2, HVD, Cc, true, false><<<dim3(Cc / 64, NROWS / 128), 256, 0, stream>>>(
        attn, Wpb, nullptr, out, bp, nullptr);
}

// Round 9
// 235.604 us; speedup vs baseline: 2.0482x; 1.0206x over previous
//
#include <hip/hip_runtime.h>
#include <hip/hip_bf16.h>

// Problem constants
#define Bc   4
#define Tc   1024
#define Cc   768
#define Hc   12
#define HSc  64
#define VDc  128
#define NQKV 4608   // gemm N for qkv (4*768 Q/K + 1536 V)
#define YLD  3072   // Y row stride: Q/K only (V goes to Vt)
#define NROWS 4096  // B*T
#define HVD  1536   // H*VD

// Y (qk) column offsets
#define Q1OFF 0
#define K1OFF 768
#define Q2OFF 1536
#define K2OFF 2304

typedef __bf16 bf16x8 __attribute__((ext_vector_type(8)));
typedef float f32x4 __attribute__((ext_vector_type(4)));
typedef unsigned int u32x4 __attribute__((ext_vector_type(4)));

// exp(s*0.125) == exp2(s * 0.125*log2(e))
#define EXP2SCALE 0.18033688011112042f

static __device__ __forceinline__ float bf2f(unsigned short s) {
    return __uint_as_float(((unsigned int)s) << 16);
}
static __device__ __forceinline__ unsigned short f2bf(float f) {
    unsigned int u = __float_as_uint(f);
    unsigned int r = (u + 0x7FFFu + ((u >> 16) & 1u)) >> 16;  // round-nearest-even
    return (unsigned short)r;
}
static __device__ __forceinline__ unsigned int pack2bf(float lo, float hi) {
    // bf16(lo) | bf16(hi)<<16, half-up rounding (values >= 0)
    unsigned int a = (__float_as_uint(lo) + 0x8000u) >> 16;
    unsigned int b = (__float_as_uint(hi) + 0x8000u) & 0xFFFF0000u;
    return a | b;
}
// raw v_exp_f32: 2^x without libm denorm guards (inputs bounded here)
static __device__ __forceinline__ float fast_exp2(float x) {
    float r;
    asm("v_exp_f32 %0, %1" : "=v"(r) : "v"(x));
    return r;
}

// async global->LDS 16B per lane; lds base must be wave-uniform
static __device__ __forceinline__ void load16_lds(const void* g, void* l) {
    __builtin_amdgcn_global_load_lds(
        (const __attribute__((address_space(1))) void*)g,
        (__attribute__((address_space(3))) void*)l, 16, 0, 0);
}

// ---------------------------------------------------------------------------
// prep: fused cast x->bf16 (blocks 0..3071), cast Wp->bf16 (3072..4223),
// lambda (4224..4235). Merging saves 2 launches.
// ---------------------------------------------------------------------------
__global__ __launch_bounds__(256) void prep(
    const float* __restrict__ x, const float* __restrict__ Wp,
    const float* __restrict__ lq1, const float* __restrict__ lk1,
    const float* __restrict__ lq2, const float* __restrict__ lk2,
    const int* __restrict__ layer_idx,
    unsigned short* __restrict__ Xb, unsigned short* __restrict__ Wpb,
    float* __restrict__ lam)
{
    int bid = blockIdx.x, tid = threadIdx.x;
    if (bid < 3072) {
        size_t i = (size_t)bid * 256 + tid;
        float4 v = *(const float4*)(x + i * 4);
        ushort4 u;
        u.x = f2bf(v.x); u.y = f2bf(v.y); u.z = f2bf(v.z); u.w = f2bf(v.w);
        *(ushort4*)(Xb + i * 4) = u;
    } else if (bid < 4224) {
        size_t i = (size_t)(bid - 3072) * 256 + tid;
        float4 v = *(const float4*)(Wp + i * 4);
        ushort4 u;
        u.x = f2bf(v.x); u.y = f2bf(v.y); u.z = f2bf(v.z); u.w = f2bf(v.w);
        *(ushort4*)(Wpb + i * 4) = u;
    } else if (tid < 64) {
        int h = bid - 4224, l = tid;
        float li = (float)layer_idx[0];
        float dyn = 0.8f - 0.6f * expf(-0.3f * (li - 1.0f));
        int i = h * HSc + l;
        float v = expf(lq1[i] * lk1[i]) - expf(lq2[i] * lk2[i]) + dyn;
        #pragma unroll
        for (int off = 32; off; off >>= 1) v += __shfl_xor(v, off);
        if (l == 0) lam[h] = v * (1.0f / 64.0f);
    }
}

// ---------------------------------------------------------------------------
// Transpose-repack the 5 projection weights into WcatT[n][k] bf16, k-contig.
// ---------------------------------------------------------------------------
__global__ __launch_bounds__(256) void trans_w(
    const float* __restrict__ Wq1, const float* __restrict__ Wk1,
    const float* __restrict__ Wq2, const float* __restrict__ Wk2,
    const float* __restrict__ Wv, unsigned short* __restrict__ WcatT)
{
    __shared__ float tile[64][65];
    int tid = threadIdx.x;
    int t = blockIdx.x;
    int kt = t % 12, nt = t / 12;
    int k0 = kt * 64, n0 = nt * 64;
    const float* src;
    int stride;
    if (n0 < 3072) {
        int which = n0 / 768, m = n0 - which * 768, h = m >> 6;
        const float* W = (which == 0) ? Wq1 : (which == 1) ? Wk1 : (which == 2) ? Wq2 : Wk2;
        src = W + ((size_t)h * 768 + k0) * 64;
        stride = 64;
    } else {
        int rel = n0 - 3072, h = rel >> 7, e0 = rel & 127;
        src = Wv + ((size_t)h * 768 + k0) * 128 + e0;
        stride = 128;
    }
    for (int i = tid; i < 4096; i += 256) {
        int kl = i >> 6, dl = i & 63;
        tile[dl][kl] = src[(size_t)kl * stride + dl];
    }
    __syncthreads();
    for (int i = tid; i < 4096; i += 256) {
        int nl = i >> 6, kl = i & 63;
        WcatT[(size_t)(n0 + nl) * 768 + k0 + kl] = f2bf(tile[nl][kl]);
    }
}

// ---------------------------------------------------------------------------
// MFMA GEMM — R17: BK=64 + XCD-chunked block swizzle. Default round-robin
// dispatch puts adjacent n-tiles (sharing an A-panel) on DIFFERENT XCDs ->
// every XCD re-fetches most of A and B (per-XCD L2 is 4MB, non-coherent).
// Swizzle: 1-D grid, xcd = bid&7 (nwg%8==0), each XCD owns 4 m-rows x all
// n-tiles; within the chunk mi varies FASTEST, so the 4 A-panels stay
// L2-resident for the whole kernel and each B-panel is fetched once and
// reused 4x. Pure block reorder -> bit-identical output.
// Requires gridM == 32 (NROWS/128) and nwg/8 == 4*NX (QKV: 1152, OUT: 384).
// SPLITV: cols >= 3072 (V projection) -> written transposed to VtOut.
// ---------------------------------------------------------------------------
template<int TN, int KD, int LDC, bool OUT_BIAS, bool SPLITV>
__global__ __launch_bounds__(256) void gemm_mfma(
    const unsigned short* __restrict__ A, const unsigned short* __restrict__ Bt,
    unsigned short* __restrict__ Cb, float* __restrict__ Cf,
    const float* __restrict__ bias, unsigned short* __restrict__ VtOut)
{
    constexpr int BN = TN * 32;
    constexpr int JB = TN / 2;
    __shared__ unsigned short As[128 * 64];
    __shared__ unsigned short Bs[BN * 64];
    int tid = threadIdx.x, lane = tid & 63, w = tid >> 6;
    int wm = w >> 1, wn = w & 1;

    // XCD-chunked swizzle: bid = xcd + 8*(mi + 4*ni)
    int bid = blockIdx.x;
    int xcd = bid & 7;
    int idx = bid >> 3;
    int mi  = idx & 3;
    int ni  = idx >> 2;
    int m0 = (xcd * 4 + mi) * 128;
    int n0 = ni * BN;

    int lr = lane >> 2, lq = lane & 3;
    const unsigned short* gA[2];
    const unsigned short* gB[JB];
    #pragma unroll
    for (int j = 0; j < 2; ++j) {
        int row = w * 32 + j * 16 + lr;
        int qg = lq ^ ((row >> 1) & 3);
        gA[j] = A + (size_t)(m0 + row) * KD + qg * 8;
    }
    #pragma unroll
    for (int j = 0; j < JB; ++j) {
        int row = w * (JB * 16) + j * 16 + lr;
        int qg = lq ^ ((row >> 1) & 3);
        gB[j] = Bt + (size_t)(n0 + row) * KD + qg * 8;
    }

    int rr = lane & 15, qd = lane >> 4;
    const unsigned short* aAddr[4];
    const unsigned short* bAddr[TN];
    #pragma unroll
    for (int i = 0; i < 4; ++i) {
        int row = wm * 64 + i * 16 + rr;
        int qs = qd ^ ((row >> 1) & 3);
        aAddr[i] = As + row * 32 + qs * 8;
    }
    #pragma unroll
    for (int t = 0; t < TN; ++t) {
        int row = wn * (TN * 16) + t * 16 + rr;
        int qs = qd ^ ((row >> 1) & 3);
        bAddr[t] = Bs + row * 32 + qs * 8;
    }

    f32x4 acc[4][TN];
    #pragma unroll
    for (int i = 0; i < 4; ++i)
        #pragma unroll
        for (int t = 0; t < TN; ++t) acc[i][t] = {0.f, 0.f, 0.f, 0.f};

    for (int k = 0; k < KD / 64; ++k) {
        __syncthreads();
        // half 0 (cols k*64 .. +31)
        load16_lds(gA[0], As + (w * 2 + 0) * 512);
        load16_lds(gA[1], As + (w * 2 + 1) * 512);
        // half 1 (cols k*64+32 .. +63) into the second 4K-ushort bank
        load16_lds(gA[0] + 32, As + 4096 + (w * 2 + 0) * 512);
        load16_lds(gA[1] + 32, As + 4096 + (w * 2 + 1) * 512);
        #pragma unroll
        for (int j = 0; j < JB; ++j) {
            load16_lds(gB[j], Bs + (w * JB + j) * 512);
            load16_lds(gB[j] + 32, Bs + BN * 32 + (w * JB + j) * 512);
        }
        gA[0] += 64; gA[1] += 64;
        #pragma unroll
        for (int j = 0; j < JB; ++j) gB[j] += 64;
        __syncthreads();

        bf16x8 af0[4], af1[4], bf0[TN], bf1[TN];
        #pragma unroll
        for (int i = 0; i < 4; ++i) {
            af0[i] = *(const bf16x8*)aAddr[i];
            af1[i] = *(const bf16x8*)(aAddr[i] + 4096);
        }
        #pragma unroll
        for (int t = 0; t < TN; ++t) {
            bf0[t] = *(const bf16x8*)bAddr[t];
            bf1[t] = *(const bf16x8*)(bAddr[t] + BN * 32);
        }
        #pragma unroll
        for (int i = 0; i < 4; ++i)
            #pragma unroll
            for (int t = 0; t < TN; ++t) {
                acc[i][t] = __builtin_amdgcn_mfma_f32_16x16x32_bf16(af0[i], bf0[t], acc[i][t], 0, 0, 0);
                acc[i][t] = __builtin_amdgcn_mfma_f32_16x16x32_bf16(af1[i], bf1[t], acc[i][t], 0, 0, 0);
            }
    }

    #pragma unroll
    for (int t = 0; t < TN; ++t) {
        int col = n0 + wn * (TN * 16) + t * 16 + rr;
        if (SPLITV && col >= 3072) {
            int rel = col - 3072, hh = rel >> 7, e = rel & 127;
            #pragma unroll
            for (int i = 0; i < 4; ++i) {
                int row0 = m0 + wm * 64 + i * 16 + qd * 4;
                int b = row0 >> 10, tt = row0 & 1023;
                ushort4 pk;
                pk.x = f2bf(acc[i][t][0]); pk.y = f2bf(acc[i][t][1]);
                pk.z = f2bf(acc[i][t][2]); pk.w = f2bf(acc[i][t][3]);
                *(ushort4*)&VtOut[(size_t)((b * Hc + hh) * 128 + e) * 1024 + tt] = pk;
            }
        } else {
            float bv = OUT_BIAS ? bias[col] : 0.f;
            #pragma unroll
            for (int i = 0; i < 4; ++i) {
                #pragma unroll
                for (int r = 0; r < 4; ++r) {
                    int row = m0 + wm * 64 + i * 16 + qd * 4 + r;
                    if (OUT_BIAS)
                        Cf[(size_t)row * LDC + col] = acc[i][t][r] + bv;
                    else
                        Cb[(size_t)row * LDC + col] = f2bf(acc[i][t][r]);
                }
            }
        }
    }
}

// ---------------------------------------------------------------------------
// MFMA differential flash attention — R15 (frozen): 64-key iterations,
// swapped QK^T + bpermute P-transform, 2-slot 64KB ring, counted barriers,
// LPT backfill. Measured 61.6 us, MfmaUtil 12.3%.
// ---------------------------------------------------------------------------
__global__ __launch_bounds__(256) void diff_attn_mfma(
    const unsigned short* __restrict__ Y, const unsigned short* __restrict__ Vt,
    const float* __restrict__ lam_buf, unsigned short* __restrict__ attn)
{
    __shared__ __align__(16) unsigned short KVring[2 * 16384];  // 64 KB

    int bh = blockIdx.x;                          // fastest dim -> XCD-pinned
    int b = bh / Hc, h = bh - b * Hc;
    int g = 15 - (int)blockIdx.y;                 // longest first
    int tid = threadIdx.x, lane = tid & 63, wv = tid >> 6;
    int cl = lane & 15, qd = lane >> 4;
    float lamv = lam_buf[h];
    size_t rowbase = (size_t)(b * Tc) * YLD;
    const int hq = h * HSc;
    const unsigned short* VtB = Vt + ((size_t)bh << 17);   // bh*128*1024
    const f32x4 zero4 = {0.f, 0.f, 0.f, 0.f};

    // ---- staging lane->global mapping (one 8-load set per wave) ----
    // wave0: K1+K2 of subtile A; wave1: K1+K2 of B; wave2: V of A; wave3: V of B
    int sub = wv & 1;
    int off8[8];
    int dstoff;
    if (wv < 2) {
        int ksrow = lane >> 3;                  // row within 8-row seg
        int ksch  = (lane & 7) ^ ksrow;         // stored global chunk (inv swizzle)
        #pragma unroll
        for (int j = 0; j < 8; ++j) {
            int moff = (j < 4) ? K1OFF : K2OFF;
            off8[j] = ((j & 3) * 8 + ksrow) * YLD + moff + hq + ksch * 8;
        }
        dstoff = 0;
    } else {
        int vsel = lane >> 2;                   // e within 16-row seg
        int vsch = (lane & 3) ^ ((vsel >> 1) & 3);
        #pragma unroll
        for (int s = 0; s < 8; ++s)
            off8[s] = (s * 16 + vsel) * 1024 + vsch * 8;
        dstoff = 8192;
    }

    auto stage = [&](int i, int slot) {
        int kt = 2 * i + sub;
        char* base = (char*)KVring + slot * 32768 + sub * 16384 + dstoff;
        const unsigned short* g0 = (wv < 2)
            ? (Y + rowbase + (size_t)(kt * 32) * YLD)
            : (VtB + kt * 32);
        #pragma unroll
        for (int j = 0; j < 8; ++j)
            load16_lds(g0 + off8[j], base + j * 1024);
    };

    // ---- fragment LDS byte offsets within a 16KB subtile (swizzled) ----
    int kfo[2][4], vfo[8];
    #pragma unroll
    for (int c = 0; c < 2; ++c) {
        int row = c * 16 + cl;
        #pragma unroll
        for (int j = 0; j < 4; ++j)
            kfo[c][j] = (j >> 1) * 4096 + row * 128 +
                        ((((j & 1) * 4 + qd) ^ (row & 7)) << 4);
    }
    #pragma unroll
    for (int ec = 0; ec < 8; ++ec) {
        int e = ec * 16 + cl;
        vfo[ec] = 8192 + e * 64 + ((qd ^ ((e >> 1) & 3)) << 4);
    }

    // P-transform bpermute indices (byte = srclane*4)
    int idxA = ((32 * (qd & 1)) + cl) * 4;
    int idxB = idxA + 64;
    bool loHalf = (qd < 2);

    int qrow = g * 64 + wv * 16;

    stage(0, 0);

    size_t qoff = rowbase + (size_t)(qrow + cl) * YLD;
    bf16x8 q1a = *(const bf16x8*)(Y + qoff + Q1OFF + hq + qd * 8);
    bf16x8 q1b = *(const bf16x8*)(Y + qoff + Q1OFF + hq + 32 + qd * 8);
    bf16x8 q2a = *(const bf16x8*)(Y + qoff + Q2OFF + hq + qd * 8);
    bf16x8 q2b = *(const bf16x8*)(Y + qoff + Q2OFF + hq + 32 + qd * 8);

    f32x4 O1[8], O2[8];
    #pragma unroll
    for (int ec = 0; ec < 8; ++ec) { O1[ec] = zero4; O2[ec] = zero4; }
    float l1s = 0.f, l2s = 0.f;

    // mask + exp + pack + cross-lane gather for one 32-key subtile
    auto transform = [&](f32x4 S1[2], f32x4 S2[2], int kt,
                         bf16x8& pa1o, bf16x8& pa2o) {
        if (kt * 32 + 31 > qrow) {
            #pragma unroll
            for (int c = 0; c < 2; ++c) {
                int lim = qrow + cl - kt * 32 - c * 16 - qd * 4;
                #pragma unroll
                for (int r = 0; r < 4; ++r) {
                    if (r > lim) { S1[c][r] = -1e30f; S2[c][r] = -1e30f; }
                }
            }
        }
        float p1v[2][4], p2v[2][4];
        #pragma unroll
        for (int c = 0; c < 2; ++c) {
            #pragma unroll
            for (int r = 0; r < 4; ++r) {
                p1v[c][r] = fast_exp2(S1[c][r] * EXP2SCALE);
                p2v[c][r] = fast_exp2(S2[c][r] * EXP2SCALE);
                l1s += p1v[c][r];
                l2s += p2v[c][r];
            }
        }
        unsigned int s1m[2][2], s2m[2][2];
        #pragma unroll
        for (int c = 0; c < 2; ++c) {
            s1m[c][0] = pack2bf(p1v[c][0], p1v[c][1]);
            s1m[c][1] = pack2bf(p1v[c][2], p1v[c][3]);
            s2m[c][0] = pack2bf(p2v[c][0], p2v[c][1]);
            s2m[c][1] = pack2bf(p2v[c][2], p2v[c][3]);
        }
        u32x4 U1, U2;
        {
            int a00 = __builtin_amdgcn_ds_bpermute(idxA, (int)s1m[0][0]);
            int a10 = __builtin_amdgcn_ds_bpermute(idxA, (int)s1m[1][0]);
            int a01 = __builtin_amdgcn_ds_bpermute(idxA, (int)s1m[0][1]);
            int a11 = __builtin_amdgcn_ds_bpermute(idxA, (int)s1m[1][1]);
            int b00 = __builtin_amdgcn_ds_bpermute(idxB, (int)s1m[0][0]);
            int b10 = __builtin_amdgcn_ds_bpermute(idxB, (int)s1m[1][0]);
            int b01 = __builtin_amdgcn_ds_bpermute(idxB, (int)s1m[0][1]);
            int b11 = __builtin_amdgcn_ds_bpermute(idxB, (int)s1m[1][1]);
            U1[0] = (unsigned)(loHalf ? a00 : a10);
            U1[1] = (unsigned)(loHalf ? a01 : a11);
            U1[2] = (unsigned)(loHalf ? b00 : b10);
            U1[3] = (unsigned)(loHalf ? b01 : b11);
        }
        {
            int a00 = __builtin_amdgcn_ds_bpermute(idxA, (int)s2m[0][0]);
            int a10 = __builtin_amdgcn_ds_bpermute(idxA, (int)s2m[1][0]);
            int a01 = __builtin_amdgcn_ds_bpermute(idxA, (int)s2m[0][1]);
            int a11 = __builtin_amdgcn_ds_bpermute(idxA, (int)s2m[1][1]);
            int b00 = __builtin_amdgcn_ds_bpermute(idxB, (int)s2m[0][0]);
            int b10 = __builtin_amdgcn_ds_bpermute(idxB, (int)s2m[1][0]);
            int b01 = __builtin_amdgcn_ds_bpermute(idxB, (int)s2m[0][1]);
            int b11 = __builtin_amdgcn_ds_bpermute(idxB, (int)s2m[1][1]);
            U2[0] = (unsigned)(loHalf ? a00 : a10);
            U2[1] = (unsigned)(loHalf ? a01 : a11);
            U2[2] = (unsigned)(loHalf ? b00 : b10);
            U2[3] = (unsigned)(loHalf ? b01 : b11);
        }
        pa1o = __builtin_bit_cast(bf16x8, U1);
        pa2o = __builtin_bit_cast(bf16x8, U2);
    };

    int NI = g + 1;
    for (int i = 0; i < NI; ++i) {
        // own stage(i) loads done, then block-wide visibility via barrier
        asm volatile("s_waitcnt vmcnt(0)\n\ts_barrier" ::: "memory");
        const char* kbA = (const char*)KVring + (i & 1) * 32768;
        const char* kbB = kbA + 16384;
        // prefetch next pair into the other slot (read 2 barriers ago)
        if (i + 1 < NI) stage(i + 1, (i + 1) & 1);

        // K reads (both subtiles) + V-A reads
        bf16x8 kfA[2][4], kfB[2][4];
        #pragma unroll
        for (int c = 0; c < 2; ++c)
            #pragma unroll
            for (int j = 0; j < 4; ++j) {
                kfA[c][j] = *(const bf16x8*)(kbA + kfo[c][j]);
                kfB[c][j] = *(const bf16x8*)(kbB + kfo[c][j]);
            }
        bf16x8 vfA[8];
        #pragma unroll
        for (int ec = 0; ec < 8; ++ec)
            vfA[ec] = *(const bf16x8*)(kbA + vfo[ec]);

        // QK^T (swapped) for both subtiles: 8 independent 2-MFMA chains
        f32x4 S1A[2], S2A[2], S1B[2], S2B[2];
        #pragma unroll
        for (int c = 0; c < 2; ++c) {
            S1A[c] = zero4; S2A[c] = zero4; S1B[c] = zero4; S2B[c] = zero4;
        }
        #pragma unroll
        for (int c = 0; c < 2; ++c) {
            S1A[c] = __builtin_amdgcn_mfma_f32_16x16x32_bf16(kfA[c][0], q1a, S1A[c], 0, 0, 0);
            S1A[c] = __builtin_amdgcn_mfma_f32_16x16x32_bf16(kfA[c][1], q1b, S1A[c], 0, 0, 0);
            S2A[c] = __builtin_amdgcn_mfma_f32_16x16x32_bf16(kfA[c][2], q2a, S2A[c], 0, 0, 0);
            S2A[c] = __builtin_amdgcn_mfma_f32_16x16x32_bf16(kfA[c][3], q2b, S2A[c], 0, 0, 0);
            S1B[c] = __builtin_amdgcn_mfma_f32_16x16x32_bf16(kfB[c][0], q1a, S1B[c], 0, 0, 0);
            S1B[c] = __builtin_amdgcn_mfma_f32_16x16x32_bf16(kfB[c][1], q1b, S1B[c], 0, 0, 0);
            S2B[c] = __builtin_amdgcn_mfma_f32_16x16x32_bf16(kfB[c][2], q2a, S2B[c], 0, 0, 0);
            S2B[c] = __builtin_amdgcn_mfma_f32_16x16x32_bf16(kfB[c][3], q2b, S2B[c], 0, 0, 0);
        }

        bf16x8 pa1A, pa2A, pa1B, pa2B;
        transform(S1A, S2A, 2 * i, pa1A, pa2A);        // bperm-A on DS pipe
        // V-B reads queue BEHIND bperm-A (PV-A not delayed), ahead of bperm-B
        bf16x8 vfB[8];
        #pragma unroll
        for (int ec = 0; ec < 8; ++ec)
            vfB[ec] = *(const bf16x8*)(kbB + vfo[ec]);
        transform(S1B, S2B, 2 * i + 1, pa1B, pa2B);

        #pragma unroll
        for (int ec = 0; ec < 8; ++ec) {
            O1[ec] = __builtin_amdgcn_mfma_f32_16x16x32_bf16(pa1A, vfA[ec], O1[ec], 0, 0, 0);
            O2[ec] = __builtin_amdgcn_mfma_f32_16x16x32_bf16(pa2A, vfA[ec], O2[ec], 0, 0, 0);
        }
        #pragma unroll
        for (int ec = 0; ec < 8; ++ec) {
            O1[ec] = __builtin_amdgcn_mfma_f32_16x16x32_bf16(pa1B, vfB[ec], O1[ec], 0, 0, 0);
            O2[ec] = __builtin_amdgcn_mfma_f32_16x16x32_bf16(pa2B, vfB[ec], O2[ec], 0, 0, 0);
        }
    }

    // l sums: lane holds partial for row cl over its key-groups; reduce
    // across qd groups, then redistribute to output rows qd*4+r.
    l1s += __shfl_xor(l1s, 16); l1s += __shfl_xor(l1s, 32);
    l2s += __shfl_xor(l2s, 16); l2s += __shfl_xor(l2s, 32);
    float w1[4], w2[4];
    #pragma unroll
    for (int r = 0; r < 4; ++r) {
        float d1 = __shfl(l1s, qd * 4 + r);
        float d2 = __shfl(l2s, qd * 4 + r);
        w1[r] = 1.0f / d1;
        w2[r] = lamv / d2;
    }
    #pragma unroll
    for (int ec = 0; ec < 8; ++ec) {
        #pragma unroll
        for (int r = 0; r < 4; ++r) {
            size_t row = (size_t)(b * Tc + qrow + qd * 4 + r);
            attn[row * HVD + h * VDc + ec * 16 + cl] =
                f2bf(O1[ec][r] * w1[r] - O2[ec][r] * w2[r]);
        }
    }
}

// ---------------------------------------------------------------------------
// Fused row-stats + LayerNorm*0.2, in-place on bf16 attn. 128 thr/row.
// ---------------------------------------------------------------------------
__global__ __launch_bounds__(128) void ln_inplace(
    unsigned short* __restrict__ attn,
    const float* __restrict__ gnw, const float* __restrict__ gnb)
{
    int row = blockIdx.x, tid = threadIdx.x;
    unsigned short* p = attn + (size_t)row * HVD;
    float v[12];
    float s = 0.f, sq = 0.f;
    #pragma unroll
    for (int j = 0; j < 3; ++j) {
        int g = tid + j * 128;
        ushort4 u = *(const ushort4*)(p + g * 4);
        float x0 = bf2f(u.x), x1 = bf2f(u.y), x2 = bf2f(u.z), x3 = bf2f(u.w);
        v[j * 4 + 0] = x0; v[j * 4 + 1] = x1; v[j * 4 + 2] = x2; v[j * 4 + 3] = x3;
        s += x0 + x1 + x2 + x3;
        sq = fmaf(x0, x0, sq); sq = fmaf(x1, x1, sq);
        sq = fmaf(x2, x2, sq); sq = fmaf(x3, x3, sq);
    }
    #pragma unroll
    for (int off = 32; off; off >>= 1) { s += __shfl_xor(s, off); sq += __shfl_xor(sq, off); }
    __shared__ float ss[2], sqs[2];
    if ((tid & 63) == 0) { ss[tid >> 6] = s; sqs[tid >> 6] = sq; }
    __syncthreads();
    float S = ss[0] + ss[1], Q = sqs[0] + sqs[1];
    float mu = S * (1.0f / HVD);
    float rstd = rsqrtf(Q * (1.0f / HVD) - mu * mu + 1e-5f);
    #pragma unroll
    for (int j = 0; j < 3; ++j) {
        int g = tid + j * 128;
        float4 gw = *(const float4*)(gnw + g * 4);
        float4 gb = *(const float4*)(gnb + g * 4);
        ushort4 o;
        o.x = f2bf(((v[j * 4 + 0] - mu) * rstd * gw.x + gb.x) * 0.2f);
        o.y = f2bf(((v[j * 4 + 1] - mu) * rstd * gw.y + gb.y) * 0.2f);
        o.z = f2bf(((v[j * 4 + 2] - mu) * rstd * gw.z + gb.z) * 0.2f);
        o.w = f2bf(((v[j * 4 + 3] - mu) * rstd * gw.w + gb.w) * 0.2f);
        *(ushort4*)(p + g * 4) = o;
    }
}

// ---------------------------------------------------------------------------
// launch
// ---------------------------------------------------------------------------
extern "C" void kernel_launch(void* const* d_in, const int* in_sizes, int n_in,
                              void* d_out, int out_size, void* d_ws, size_t ws_size,
                              hipStream_t stream)
{
    const float* x   = (const float*)d_in[0];
    const float* Wq1 = (const float*)d_in[1];
    const float* Wk1 = (const float*)d_in[2];
    const float* Wq2 = (const float*)d_in[3];
    const float* Wk2 = (const float*)d_in[4];
    const float* Wv  = (const float*)d_in[5];
    const float* lq1 = (const float*)d_in[6];
    const float* lk1 = (const float*)d_in[7];
    const float* lq2 = (const float*)d_in[8];
    const float* lk2 = (const float*)d_in[9];
    const float* gnw = (const float*)d_in[10];
    const float* gnb = (const float*)d_in[11];
    const float* Wp  = (const float*)d_in[12];
    const float* bp  = (const float*)d_in[13];
    const int*   lidx = (const int*)d_in[14];
    float* out = (float*)d_out;

    // workspace layout (bytes):
    // WcatT bf16 [4608][768]:  7,077,888 @ 0
    // Xb    bf16 [4096][768]:  6,291,456 @ 7,077,888
    // Y     bf16 [4096][3072]: 25,165,824 @ 13,369,344
    // Vt    bf16 [48][128][1024]: 12,582,912 @ 38,535,168
    // attn  bf16 [4096][1536]: 12,582,912 @ 51,118,080
    // Wpb   bf16 [768][1536]:   2,359,296 @ 63,700,992
    // lam   f32 [12]                       @ 66,060,288
    char* w = (char*)d_ws;
    unsigned short* WcatT = (unsigned short*)(w);
    unsigned short* Xb    = (unsigned short*)(w + 7077888);
    unsigned short* Y     = (unsigned short*)(w + 13369344);
    unsigned short* VtW   = (unsigned short*)(w + 38535168);
    unsigned short* attn  = (unsigned short*)(w + 51118080);
    unsigned short* Wpb   = (unsigned short*)(w + 63700992);
    float* lam            = (float*)(w + 66060288);

    // fused casts + lambda
    prep<<<dim3(4236), 256, 0, stream>>>(x, Wp, lq1, lk1, lq2, lk2, lidx,
                                         Xb, Wpb, lam);
    trans_w<<<dim3(72 * 12), 256, 0, stream>>>(Wq1, Wk1, Wq2, Wk2, Wv, WcatT);
    // QKV: [4096,768] x [768,4608]; Q/K -> Y (LD 3072), V -> Vt transposed
    // 1-D grid 1152 = 8 xcd x (4 m x 36 n), XCD-chunked swizzle in-kernel
    gemm_mfma<4, 768, YLD, false, true><<<dim3(1152), 256, 0, stream>>>(
        Xb, WcatT, Y, nullptr, nullptr, VtW);
    // bh fastest (XCD pin); y -> g = 15-y, longest-first; 768 blocks x 4 waves
    diff_attn_mfma<<<dim3(Bc * Hc, 16), 256, 0, stream>>>(Y, VtW, lam, attn);
    ln_inplace<<<dim3(NROWS), 128, 0, stream>>>(attn, gnw, gnb);
    // OUT: [4096,1536] x [1536,768] -> out fp32 (+bias)
    // 1-D grid 384 = 8 xcd x (4 m x 12 n)
    gemm_mfma<2, HVD, Cc, true, false><<<dim3(384), 256, 0, stream>>>(
        attn, Wpb, nullptr, out, bp, nullptr);
}